// Round 9
// baseline (2642.237 us; speedup 1.0000x reference)
//
#include <hip/hip_runtime.h>

// simpleKT forward on gfx950: bf16 MFMA GEMMs + flash-style causal attention
// (transposed-scores formulation; P stays in registers; coalesced O epilogue;
//  XCD-aware block swizzle for K/V L2 locality).
// R9: two changes:
//  (a) attn_k: pair q-tiles {3-p, p} per block -> every block = exactly 5
//      chunks, 1024 blocks = one residency round (4/CU), zero imbalance.
//      All staging regions are wave-private (audited) so the barrier
//      structure is unchanged; outer 2-tile loop reinits state per tile.
//      Both blocks of a (b,h) share l%8 (same XCD) for K/V L2 reuse.
//  (b) residual fused into Wo-proj & FFN-down epilogues (resid param);
//      ln_k is now single-input (32MB less read per ln dispatch; one fewer
//      bf16 rounding in the residual chain).
// History: R0 2844 (spill-bound) -> R5 2491 (spill dead, WRITE==32MB==O) ->
//  R6 2371 (cvt_pk + BK=64) -> R7 2419 (dbuf regressed; BK=64 1-buf is the
//  envelope optimum) -> R8 2349 (recombine).
// B=64 S=512 D=512 H=8 DK=64 L=4 DFF=2048 NSK=300 FC1=512 FC2=256.
// ENVELOPE RULE: kernels use <=256 threads and <=32KB static LDS; no
// dynamic-LDS opt-in, no hipFuncSetAttribute.

typedef unsigned short u16;
typedef __attribute__((ext_vector_type(8))) short short8;   // 8 bf16 - 16x16x32 A/B frag
typedef __attribute__((ext_vector_type(4))) short short4v;  // 4 bf16 - 16x16x16 A/B frag
typedef __attribute__((ext_vector_type(4))) float f32x4;    // MFMA C/D frag

#define DEV __device__ __forceinline__

DEV float bf2f(u16 u) { return __uint_as_float(((unsigned int)u) << 16); }
DEV u16 f2bf(float f) {
  unsigned int u = __float_as_uint(f);
  u += 0x7FFFu + ((u >> 16) & 1u);
  return (u16)(u >> 16);
}

// v_cvt_pk_bf16_f32: low16 = bf16(lo), high16 = bf16(hi); RNE — bit-identical
// to f2bf for finite inputs.
DEV unsigned cvt_pk_bf16(float lo, float hi) {
  unsigned r;
  asm("v_cvt_pk_bf16_f32 %0, %1, %2" : "=v"(r) : "v"(lo), "v"(hi));
  return r;
}

template <bool V> struct BoolC { static constexpr bool value = V; };

DEV void gl2l16(const void* g, void* l) {
  __builtin_amdgcn_global_load_lds(
      (__attribute__((address_space(1))) void*)g,
      (__attribute__((address_space(3))) void*)l, 16, 0, 0);
}

#define MFMA16(a, b, c) __builtin_amdgcn_mfma_f32_16x16x32_bf16(a, b, c, 0, 0, 0)

// 16x16x16 bf16 MFMA (K=16: k = (lane>>4)*4+j — matches C-layout rows)
#if defined(__has_builtin)
#if __has_builtin(__builtin_amdgcn_mfma_f32_16x16x16bf16_1k)
#define MFMA16X16(a, b, c) __builtin_amdgcn_mfma_f32_16x16x16bf16_1k(a, b, c, 0, 0, 0)
#elif __has_builtin(__builtin_amdgcn_mfma_f32_16x16x16_bf16)
#define MFMA16X16(a, b, c) __builtin_amdgcn_mfma_f32_16x16x16_bf16(a, b, c, 0, 0, 0)
#endif
#endif
#ifndef MFMA16X16
DEV f32x4 mfma_16x16x16_bf16_asm(short4v a, short4v b, f32x4 c) {
  f32x4 d;
  asm("v_mfma_f32_16x16x16_bf16 %0, %1, %2, %3\n\ts_nop 7\n\ts_nop 3"
      : "=&v"(d) : "v"(a), "v"(b), "v"(c));
  return d;
}
#define MFMA16X16(a, b, c) mfma_16x16x16_bf16_asm(a, b, c)
#endif

// ---------------------------------------------------------------------------
// Weight convert+transpose: fp32 [K,N] (batched over z) -> bf16 [N,K]
// ---------------------------------------------------------------------------
__global__ __launch_bounds__(256) void transpose_cvt(
    const float* __restrict__ src, u16* __restrict__ dst, int K, int N)
{
  src += (size_t)blockIdx.z * K * N;
  dst += (size_t)blockIdx.z * K * N;
  __shared__ alignas(16) float tile[32][33];
  const int tx = threadIdx.x & 31, ty = threadIdx.x >> 5;
  const int n0 = blockIdx.x * 32, k0 = blockIdx.y * 32;
#pragma unroll
  for (int i = 0; i < 4; ++i) {
    int k = k0 + ty + i * 8, n = n0 + tx;
    if (k < K && n < N) tile[ty + i * 8][tx] = src[(size_t)k * N + n];
  }
  __syncthreads();
#pragma unroll
  for (int i = 0; i < 4; ++i) {
    int n = n0 + ty + i * 8, k = k0 + tx;
    if (n < N && k < K) dst[(size_t)n * K + k] = f2bf(tile[tx][ty + i * 8]);
  }
}

// ---------------------------------------------------------------------------
// Embedding: x = q_emb[q_data] + pe[s]; y = qa_emb[target] + q_emb[q_data] + pe[s]
// ---------------------------------------------------------------------------
__global__ __launch_bounds__(256) void embed_k(
    const int* __restrict__ qd, const int* __restrict__ tg,
    const float* __restrict__ pe, const float* __restrict__ qe, const float* __restrict__ qa,
    u16* __restrict__ x_b, u16* __restrict__ y_b)
{
  const int row = blockIdx.x * 4 + (threadIdx.x >> 6);
  const int lane = threadIdx.x & 63;
  const int s = row & 511;
  const int idx = qd[row];
  const int tt = tg[row];
  const int c = lane * 8;
  const float* q = qe + (size_t)idx * 512 + c;
  const float* p = pe + (size_t)s * 512 + c;
  const float* a = qa + (size_t)tt * 512 + c;
  float4 q0 = *(const float4*)q, q1 = *(const float4*)(q + 4);
  float4 p0 = *(const float4*)p, p1 = *(const float4*)(p + 4);
  float4 a0 = *(const float4*)a, a1 = *(const float4*)(a + 4);
  float qv[8] = {q0.x, q0.y, q0.z, q0.w, q1.x, q1.y, q1.z, q1.w};
  float pv[8] = {p0.x, p0.y, p0.z, p0.w, p1.x, p1.y, p1.z, p1.w};
  float av[8] = {a0.x, a0.y, a0.z, a0.w, a1.x, a1.y, a1.z, a1.w};
  short8 ox, oy;
#pragma unroll
  for (int i = 0; i < 8; ++i) {
    ox[i] = (short)f2bf(qv[i] + pv[i]);
    oy[i] = (short)f2bf(qv[i] + pv[i] + av[i]);
  }
  size_t base = (size_t)row * 512 + c;
  *(short8*)(x_b + base) = ox;
  *(short8*)(y_b + base) = oy;
}

// ---------------------------------------------------------------------------
// bf16 GEMM core: C[M,N] = act((A[M,K] @ Bt[N,K]^T + bias) * oscale [+ resid])
// 128x128 tile, BK=64, 256 thr. Staging: 16 sub-tiles of (8 rows x 64 cols),
// wave w owns tb = w*4+i; slot swizzle ps = (lane&7)^(r&7) with r&7 == lane>>3
// (uniform across tb). Per K-step: 8 gl2l16, one barrier pair, 2x16 MFMA.
// OUTM: 0 = bf16 row-major, 1 = f32 row-major, 2 = bf16 scatter vT[b,h,dk,s].
// resid (nullable, OUTM=0 only): bf16 [M,N] added pre-activation — fuses the
// transformer residual so ln_k is single-input (R9).
// ---------------------------------------------------------------------------
template <int ACT, int OUTM>
DEV void gemm_core(u16* As, u16* Bs,
                   const u16* __restrict__ A, const u16* __restrict__ Bt,
                   const float* __restrict__ bias, void* __restrict__ Cv,
                   int M, int N, int K, int bx, int by, float oscale,
                   const u16* __restrict__ resid)
{
  const int lane = threadIdx.x & 63;
  const int w = threadIdx.x >> 6;
  const int wm = w >> 1, wn = w & 1;
  const int m0 = by * 128, n0 = bx * 128;

  // staging addresses: rows rs_+8i (i<4), slot ps_ (8 u16 = 16B)
  const int rs_ = w * 32 + (lane >> 3);
  const int ps_ = (lane & 7) ^ (lane >> 3);   // r&7 == lane>>3 for all tb
  const u16* pa = A + (size_t)(m0 + rs_) * K + ps_ * 8;
  const u16* pb[4];
#pragma unroll
  for (int i = 0; i < 4; ++i) {
    int rb = n0 + rs_ + i * 8;
    rb = (rb < N) ? rb : (N - 1);
    pb[i] = Bt + (size_t)rb * K + ps_ * 8;
  }
  u16* la = As + (w * 4 * 64 + lane) * 8;
  u16* lb = Bs + (w * 4 * 64 + lane) * 8;

  f32x4 acc[4][4];
#pragma unroll
  for (int a_ = 0; a_ < 4; ++a_)
#pragma unroll
    for (int b_ = 0; b_ < 4; ++b_)
#pragma unroll
      for (int i = 0; i < 4; ++i) acc[a_][b_][i] = 0.f;

  for (int k0 = 0; k0 < K; k0 += 64) {
#pragma unroll
    for (int i = 0; i < 4; ++i) gl2l16(pa + (size_t)i * 8 * K, la + i * 64 * 8);
#pragma unroll
    for (int i = 0; i < 4; ++i) gl2l16(pb[i], lb + i * 64 * 8);
    pa += 64;
#pragma unroll
    for (int i = 0; i < 4; ++i) pb[i] += 64;
    __syncthreads();
#pragma unroll
    for (int ks = 0; ks < 2; ++ks) {
      short8 af[4], bf[4];
#pragma unroll
      for (int i = 0; i < 4; ++i) {
        int r = wm * 64 + i * 16 + (lane & 15);
        af[i] = *(const short8*)(As + (r * 8 + ((ks * 4 + (lane >> 4)) ^ (r & 7))) * 8);
        int r2 = wn * 64 + i * 16 + (lane & 15);
        bf[i] = *(const short8*)(Bs + (r2 * 8 + ((ks * 4 + (lane >> 4)) ^ (r2 & 7))) * 8);
      }
#pragma unroll
      for (int mt = 0; mt < 4; ++mt)
#pragma unroll
        for (int nt = 0; nt < 4; ++nt)
          acc[mt][nt] = MFMA16(af[mt], bf[nt], acc[mt][nt]);
    }
    __syncthreads();
  }

  const int row0 = m0 + wm * 64, col0 = n0 + wn * 64;
#pragma unroll
  for (int mt = 0; mt < 4; ++mt) {
#pragma unroll
    for (int nt = 0; nt < 4; ++nt) {
      int c = col0 + nt * 16 + (lane & 15);
      int r = row0 + mt * 16 + (lane >> 4) * 4;
      if (c < N) {
        float bz = bias[c];
#pragma unroll
        for (int i = 0; i < 4; ++i) {
          float v = (acc[mt][nt][i] + bz) * oscale;
          int m = r + i;
          if (OUTM == 0 && resid) v += bf2f(resid[(size_t)m * N + c]);
          if (ACT == 1) v = fmaxf(v, 0.f);
          if (OUTM == 0) {
            ((u16*)Cv)[(size_t)m * N + c] = f2bf(v);
          } else if (OUTM == 1) {
            ((float*)Cv)[(size_t)m * N + c] = v;
          } else {  // vT[b][h][dk][s]: m=(b,s) local, c=(h,dk)
            size_t idx = ((((size_t)(m >> 9)) * 8 + (c >> 6)) * 64 + (c & 63)) * 512 + (m & 511);
            ((u16*)Cv)[idx] = f2bf(v);
          }
        }
      }
    }
  }
}

template <int ACT, int OUTM>
__global__ __launch_bounds__(256) void gemm_bt(
    const u16* __restrict__ A, const u16* __restrict__ Bt,
    const float* __restrict__ bias, void* __restrict__ Cv,
    int M, int N, int K, const u16* __restrict__ resid)
{
  __shared__ alignas(16) u16 As[128 * 64];
  __shared__ alignas(16) u16 Bs[128 * 64];
  gemm_core<ACT, OUTM>(As, Bs, A, Bt, bias, Cv, M, N, K, blockIdx.x, blockIdx.y,
                       1.f, resid);
}

// fused K/V projection: z=0 -> x@Wk (scaled by os0) -> s_kq (OUTM 0);
//                       z=1 -> y@Wv -> vT (OUTM 2)
__global__ __launch_bounds__(256) void gemm_kv(
    const u16* __restrict__ A0, const u16* __restrict__ Bt0,
    const float* __restrict__ b0, void* __restrict__ C0,
    const u16* __restrict__ A1, const u16* __restrict__ Bt1,
    const float* __restrict__ b1, void* __restrict__ C1,
    int M, int N, int K, float os0)
{
  __shared__ alignas(16) u16 As[128 * 64];
  __shared__ alignas(16) u16 Bs[128 * 64];
  if (blockIdx.z == 0)
    gemm_core<0, 0>(As, Bs, A0, Bt0, b0, C0, M, N, K, blockIdx.x, blockIdx.y,
                    os0, nullptr);
  else
    gemm_core<0, 2>(As, Bs, A1, Bt1, b1, C1, M, N, K, blockIdx.x, blockIdx.y,
                    1.f, nullptr);
}

// ---------------------------------------------------------------------------
// Flash attention, transposed scores. grid (pair=2, h=8, b=NB), 256 thr.
// R9: each block processes TWO q-tiles {3-p, p} sequentially -> uniform 5
// chunks/block, 1024 blocks = one residency round (4/CU), zero imbalance.
// Unswizzle: l = x + 2*(y+8*z); bh = (l&7)+8*(l>>4), p = (l>>3)&1 -> both
// blocks of a (b,h) share l%8 (same XCD under round-robin) for K/V L2 hits.
// Wave w owns q-cols [w*32, w*32+32). S^T = K Q^T via 16x16x32 (keys=M, q=N);
// C-layout: q = lane&15 (col), key = (lane>>4)*4+i (row). P^T stays in regs as
// 16x16x16 B-frags; O^T = V^T P^T with dk as M.
// Q/K arrive PRE-SCALED by sqrt(0.125*log2e) (gemm_kv z=0 epilogue), so QK^T
// emerges directly in the exp2 domain — no per-element scale pass (R7).
// All LDS staging regions (Q/K/V/epilogue scratch) are wave-private ranges
// [w*2048,(w+1)*2048) of Ks/Vs, so the barrier structure is unchanged by the
// outer 2-tile loop. Each chunk = two 64-key halves with their own online-
// softmax update (no spill — R5: WRITE==32MB==O). Softmax: masked = -1e30,
// plain-subtract exp2; P->bf16 via cvt_pk (R6). Epilogue bounces O^T through
// wave-private LDS (XOR swizzle) for coalesced short8 stores. LDS 32KB.
// ---------------------------------------------------------------------------
__global__ __launch_bounds__(256, 2) void attn_k(
    const u16* __restrict__ kq, const u16* __restrict__ vT, u16* __restrict__ o)
{
  __shared__ alignas(16) u16 Ks[128 * 64];
  __shared__ alignas(16) u16 Vs[64 * 128];
  const int l = blockIdx.x + 2 * (blockIdx.y + 8 * blockIdx.z);
  const int bh = (l & 7) + 8 * (l >> 4);
  const int pr = (l >> 3) & 1;
  const int h = bh & 7, b = bh >> 3;
  const int lane = threadIdx.x & 63;
  const int w = threadIdx.x >> 6;
  const size_t kq_base = ((size_t)b * 512) * 512 + h * 64;

  for (int pi = 0; pi < 2; ++pi) {
    const int t = pi ? pr : 3 - pr;   // pr=0 -> {3,0}; pr=1 -> {2,1}: 5 chunks
    const int q0 = t * 128;

    // stage Q tile [128 x 64] into Ks (wave-private region), pull B-frags
#pragma unroll
    for (int i = 0; i < 4; ++i) {
      int tb = w * 4 + i;
      int r = tb * 8 + (lane >> 3);
      int ps = (lane & 7) ^ (r & 7);
      gl2l16(kq + kq_base + (size_t)(q0 + r) * 512 + ps * 8, Ks + (tb * 64 + lane) * 8);
    }
    __syncthreads();
    short8 qf[2][2];
#pragma unroll
    for (int nt = 0; nt < 2; ++nt)
#pragma unroll
      for (int ks = 0; ks < 2; ++ks) {
        int q = w * 32 + nt * 16 + (lane & 15);
        int ch = ks * 4 + (lane >> 4);
        qf[nt][ks] = *(const short8*)(Ks + (q * 8 + (ch ^ (q & 7))) * 8);
      }

    f32x4 of[4][2];  // [dk-tile][q-tile]; col=q=lane&15, row=dk=(lane>>4)*4+i
    float m_st[2] = {-1e30f, -1e30f}, l_st[2] = {0.f, 0.f};  // exp2 domain
#pragma unroll
    for (int d = 0; d < 4; ++d)
#pragma unroll
      for (int nt = 0; nt < 2; ++nt)
#pragma unroll
        for (int i = 0; i < 4; ++i) of[d][nt][i] = 0.f;

    auto chunk = [&](int j, auto diagc) {
      constexpr bool DIAG = decltype(diagc)::value;
      // diagonal chunk: wave w needs keys < w*32+32 -> key-tiles mt < 2w+2
      const int MT = DIAG ? (2 * w + 2) : 8;
      const int k0 = j * 128;

      // two 64-key halves, each with its own online-softmax update: halves
      // the sc/pf live range -> fits the 128-reg target (R3/R5 spill fix).
#pragma unroll
      for (int hh = 0; hh < 2; ++hh) {
        if (!DIAG || MT > hh * 4) {
          const int MTl = DIAG ? ((MT - hh * 4 < 4) ? MT - hh * 4 : 4) : 4;

          // S^T = K Q^T (this half's 4 key-tiles) — already exp2-scaled
          f32x4 sc[4][2];
          __builtin_amdgcn_s_setprio(1);
#pragma unroll
          for (int mt = 0; mt < 4; ++mt)
            if (!DIAG || mt < MTl) {
#pragma unroll
              for (int nt = 0; nt < 2; ++nt)
#pragma unroll
                for (int i = 0; i < 4; ++i) sc[mt][nt][i] = 0.f;
#pragma unroll
              for (int ks = 0; ks < 2; ++ks) {
                int key = (hh * 4 + mt) * 16 + (lane & 15);
                int ch = ks * 4 + (lane >> 4);
                short8 kf = *(const short8*)(Ks + (key * 8 + (ch ^ (key & 7))) * 8);
                sc[mt][0] = MFMA16(kf, qf[0][ks], sc[mt][0]);
                sc[mt][1] = MFMA16(kf, qf[1][ks], sc[mt][1]);
              }
            }
          __builtin_amdgcn_s_setprio(0);

          // strict causal mask (diag chunk only; no scale pass needed)
          if (DIAG) {
#pragma unroll
            for (int mt = 0; mt < 4; ++mt)
              if (mt < MTl) {
#pragma unroll
                for (int nt = 0; nt < 2; ++nt) {
                  int qg = q0 + w * 32 + nt * 16 + (lane & 15);
#pragma unroll
                  for (int i = 0; i < 4; ++i) {
                    int kg = k0 + (hh * 4 + mt) * 16 + (lane >> 4) * 4 + i;
                    if (kg >= qg) sc[mt][nt][i] = -1e30f;
                  }
                }
              }
          }

          // online softmax (exp2 domain): per-lane scalar state (q=lane&15)
          short4v pf[4][2];
#pragma unroll
          for (int nt = 0; nt < 2; ++nt) {
            float mx = -1e30f;
#pragma unroll
            for (int mt = 0; mt < 4; ++mt)
              if (!DIAG || mt < MTl) {
#pragma unroll
                for (int i = 0; i < 4; ++i) mx = fmaxf(mx, sc[mt][nt][i]);
              }
            mx = fmaxf(mx, __shfl_xor(mx, 16));
            mx = fmaxf(mx, __shfl_xor(mx, 32));
            float mo = m_st[nt];
            float mn = fmaxf(mo, mx);
            float al = exp2f(mo - mn);
            float rs = 0.f;
#pragma unroll
            for (int mt = 0; mt < 4; ++mt)
              if (!DIAG || mt < MTl) {
#pragma unroll
                for (int i = 0; i < 4; ++i) {
                  float pv = exp2f(sc[mt][nt][i] - mn);
                  sc[mt][nt][i] = pv;
                  rs += pv;
                }
              }
            rs += __shfl_xor(rs, 16);
            rs += __shfl_xor(rs, 32);
            m_st[nt] = mn;
            l_st[nt] = l_st[nt] * al + rs;
#pragma unroll
            for (int d = 0; d < 4; ++d)
#pragma unroll
              for (int i = 0; i < 4; ++i) of[d][nt][i] *= al;
            // pack P^T to bf16 16x16x16 B-frags via cvt_pk
#pragma unroll
            for (int mt = 0; mt < 4; ++mt)
              if (!DIAG || mt < MTl) {
                union { unsigned u[2]; short4v s; } cv;
                cv.u[0] = cvt_pk_bf16(sc[mt][nt][0], sc[mt][nt][1]);
                cv.u[1] = cvt_pk_bf16(sc[mt][nt][2], sc[mt][nt][3]);
                pf[mt][nt] = cv.s;
              }
          }

          // O^T += V^T P^T  (A = V^T frag: m=dk, k=key; 16x16x16)
          __builtin_amdgcn_s_setprio(1);
#pragma unroll
          for (int mt = 0; mt < 4; ++mt)
            if (!DIAG || mt < MTl) {
              int key4 = (hh * 4 + mt) * 16 + (lane >> 4) * 4;
#pragma unroll
              for (int d = 0; d < 4; ++d) {
                int dk = d * 16 + (lane & 15);
                short4v vf = *(const short4v*)(
                    Vs + (dk * 16 + ((key4 >> 3) ^ (dk & 15))) * 8 + (key4 & 7));
                of[d][0] = MFMA16X16(vf, pf[mt][0], of[d][0]);
                of[d][1] = MFMA16X16(vf, pf[mt][1], of[d][1]);
              }
            }
          __builtin_amdgcn_s_setprio(0);
        }
      }
    };

    for (int j = 0; j <= t; ++j) {
      const int k0 = j * 128;
      __syncthreads();  // all waves done reading prior chunk's Ks/Vs
#pragma unroll
      for (int i = 0; i < 4; ++i) {  // K chunk [128 keys x 64]
        int tb = w * 4 + i;
        int r = tb * 8 + (lane >> 3);
        int ps = (lane & 7) ^ (r & 7);
        gl2l16(kq + kq_base + (size_t)(k0 + r) * 512 + ps * 8, Ks + (tb * 64 + lane) * 8);
      }
#pragma unroll
      for (int i = 0; i < 4; ++i) {  // V^T chunk [64 dk x 128 keys]
        int tb = w * 4 + i;
        int r = tb * 4 + (lane >> 4);
        int ps = (lane & 15) ^ (r & 15);
        gl2l16(vT + ((size_t)((b * 8 + h) * 64 + r)) * 512 + k0 + ps * 8, Vs + (tb * 64 + lane) * 8);
      }
      __syncthreads();
      if (j < t) {
        chunk(j, BoolC<false>{});
      } else {
        chunk(j, BoolC<true>{});
      }
    }

    // epilogue: O^T -> wave-private LDS (swizzled) -> coalesced stores
    __syncthreads();  // all waves done reading Ks/Vs
    u16* Ws = Ks + w * 2048;  // 32 q-rows x 64 dk per wave
#pragma unroll
    for (int nt = 0; nt < 2; ++nt) {
      int qrow = nt * 16 + (lane & 15);
      int qg = q0 + w * 32 + qrow;
      float li = l_st[nt];
      float inv = (qg > 0 && li > 0.f) ? (1.f / li) : 0.f;
      int sw = (qrow & 7) * 8;
#pragma unroll
      for (int d = 0; d < 4; ++d)
#pragma unroll
        for (int i = 0; i < 4; ++i) {
          int dk = d * 16 + (lane >> 4) * 4 + i;
          Ws[qrow * 64 + (dk ^ sw)] = f2bf(of[d][nt][i] * inv);
        }
    }
    // wave-private: no barrier needed (lgkmcnt ordering within wave)
#pragma unroll
    for (int p = 0; p < 4; ++p) {
      int qrow = p * 8 + (lane >> 3);
      int c = lane & 7;
      short8 vv = *(const short8*)(Ws + qrow * 64 + ((c ^ (qrow & 7)) * 8));
      int qg = q0 + w * 32 + qrow;
      *(short8*)(o + ((size_t)b * 512 + qg) * 512 + h * 64 + c * 8) = vv;
    }
  }
}

// ---------------------------------------------------------------------------
// LayerNorm(x) — single input (residual pre-added in GEMM epilogue, R9);
// one wave per 512-col row.
// ---------------------------------------------------------------------------
__global__ __launch_bounds__(256) void ln_k(
    const u16* __restrict__ xin,
    const float* __restrict__ gam, const float* __restrict__ bet, u16* __restrict__ xout)
{
  const int row = blockIdx.x * 4 + (threadIdx.x >> 6);
  const int lane = threadIdx.x & 63;
  const size_t base = (size_t)row * 512 + lane * 8;
  short8 xv = *(const short8*)(xin + base);
  float v[8];
  float s = 0.f, s2 = 0.f;
#pragma unroll
  for (int i = 0; i < 8; ++i) {
    float a = bf2f((u16)xv[i]);
    v[i] = a;
    s += a;
    s2 += a * a;
  }
#pragma unroll
  for (int d = 1; d < 64; d <<= 1) {
    s += __shfl_xor(s, d);
    s2 += __shfl_xor(s2, d);
  }
  float mean = s * (1.f / 512.f);
  float var = s2 * (1.f / 512.f) - mean * mean;
  float rstd = rsqrtf(var + 1e-5f);
  const int c = lane * 8;
  short8 ov;
#pragma unroll
  for (int i = 0; i < 8; ++i) {
    float ot = (v[i] - mean) * rstd * gam[c + i] + bet[c + i];
    ov[i] = (short)f2bf(ot);
  }
  *(short8*)(xout + base) = ov;
}

// ---------------------------------------------------------------------------
// concat [x, q_emb[q_data]] -> cat [rows,1024] bf16
// ---------------------------------------------------------------------------
__global__ __launch_bounds__(256) void concat2_k(
    const u16* __restrict__ x, const int* __restrict__ qd,
    const float* __restrict__ qemb, u16* __restrict__ cat)
{
  const int row = blockIdx.x * 4 + (threadIdx.x >> 6);
  const int lane = threadIdx.x & 63;
  *(short8*)(cat + (size_t)row * 1024 + lane * 8) =
      *(const short8*)(x + (size_t)row * 512 + lane * 8);
  const int idx = qd[row];
  const float* q = qemb + (size_t)idx * 512 + lane * 8;
  float4 q0 = *(const float4*)q, q1 = *(const float4*)(q + 4);
  float qv[8] = {q0.x, q0.y, q0.z, q0.w, q1.x, q1.y, q1.z, q1.w};
  short8 ov;
#pragma unroll
  for (int i = 0; i < 8; ++i) ov[i] = (short)f2bf(qv[i]);
  *(short8*)(cat + (size_t)row * 1024 + 512 + lane * 8) = ov;
}

// ---------------------------------------------------------------------------
extern "C" void kernel_launch(void* const* d_in, const int* in_sizes, int n_in,
                              void* d_out, int out_size, void* d_ws, size_t ws_size,
                              hipStream_t stream)
{
  const int* qd = (const int*)d_in[0];
  const int* tg = (const int*)d_in[1];
  const float* pe = (const float*)d_in[2];
  const float* qemb = (const float*)d_in[3];
  const float* qa = (const float*)d_in[4];
  const float* Wk = (const float*)d_in[5];
  const float* bk = (const float*)d_in[6];
  const float* Wv = (const float*)d_in[7];
  const float* bv = (const float*)d_in[8];
  const float* Wo = (const float*)d_in[9];
  const float* bo = (const float*)d_in[10];
  const float* g1 = (const float*)d_in[11];
  const float* be1 = (const float*)d_in[12];
  const float* W1 = (const float*)d_in[13];
  const float* b1 = (const float*)d_in[14];
  const float* W2 = (const float*)d_in[15];
  const float* b2 = (const float*)d_in[16];
  const float* g2 = (const float*)d_in[17];
  const float* be2 = (const float*)d_in[18];
  const float* Wo1 = (const float*)d_in[19];
  const float* bo1 = (const float*)d_in[20];
  const float* Wo2 = (const float*)d_in[21];
  const float* bo2 = (const float*)d_in[22];
  const float* Wo3 = (const float*)d_in[23];
  const float* bo3 = (const float*)d_in[24];
  float* out = (float*)d_out;

  const int BS = 64 * 512;  // 32768
  const float SQS = 0.42466089f;  // sqrt(0.125 * log2(e)) — QK pre-scale

  // batch-group chunking from ws_size (constant per process -> graph-safe)
  const size_t WU16 = 12266496ull;
  int NC = 1;
  {
    auto need = [&](int nc) -> size_t {
      size_t CMr = (size_t)BS / nc;
      size_t st = CMr < 8192 ? CMr : 8192;
      return 2ull * (WU16 + 2ull * BS * 512 + 3ull * CMr * 512 + st * 2048);
    };
    if (ws_size < need(1)) NC = 4;
    if (NC == 4 && ws_size < need(4)) NC = 8;
  }
  const int CM = BS / NC;
  const int MI = CM < 8192 ? CM : 8192;

  u16* p = (u16*)d_ws;
  u16* wkT = p;  p += 4 * 512 * 512;
  u16* wvT = p;  p += 4 * 512 * 512;
  u16* woT = p;  p += 4 * 512 * 512;
  u16* w1T = p;  p += 4 * 512 * 2048;
  u16* w2T = p;  p += 4 * 2048 * 512;
  u16* wo1T = p; p += 1024 * 512;
  u16* wo2T = p; p += 512 * 256;
  u16* wo3T = p; p += 300 * 256;
  u16* x_b = p;  p += (size_t)BS * 512;
  u16* y_b = p;  p += (size_t)BS * 512;
  u16* s_kq = p; p += (size_t)CM * 512;   // also head-cat first half
  u16* s_vT = p; p += (size_t)CM * 512;   // adjacent: cat = s_kq[CM x 1024]
  u16* s_o = p;  p += (size_t)CM * 512;
  u16* s_t = p;                            // MI x 2048 FFN / head scratch

  transpose_cvt<<<dim3(16, 16, 4), 256, 0, stream>>>(Wk, wkT, 512, 512);
  transpose_cvt<<<dim3(16, 16, 4), 256, 0, stream>>>(Wv, wvT, 512, 512);
  transpose_cvt<<<dim3(16, 16, 4), 256, 0, stream>>>(Wo, woT, 512, 512);
  transpose_cvt<<<dim3(64, 16, 4), 256, 0, stream>>>(W1, w1T, 512, 2048);
  transpose_cvt<<<dim3(16, 64, 4), 256, 0, stream>>>(W2, w2T, 2048, 512);
  transpose_cvt<<<dim3(16, 32, 1), 256, 0, stream>>>(Wo1, wo1T, 1024, 512);
  transpose_cvt<<<dim3(8, 16, 1), 256, 0, stream>>>(Wo2, wo2T, 512, 256);
  transpose_cvt<<<dim3(10, 8, 1), 256, 0, stream>>>(Wo3, wo3T, 256, 300);

  embed_k<<<BS / 4, 256, 0, stream>>>(qd, tg, pe, qemb, qa, x_b, y_b);

  for (int l = 0; l < 4; ++l) {
    const size_t lw = (size_t)l * 512 * 512;
    for (int cc = 0; cc < NC; ++cc) {
      const size_t R = (size_t)cc * CM;
      // fused q/k + v projections (kq_same=1); q/k pre-scaled for exp2 domain
      gemm_kv<<<dim3(4, CM / 128, 2), 256, 0, stream>>>(
          x_b + R * 512, wkT + lw, bk + l * 512, s_kq,
          y_b + R * 512, wvT + lw, bv + l * 512, s_vT, CM, 512, 512, SQS);
      attn_k<<<dim3(2, 8, CM / 512), 256, 0, stream>>>(s_kq, s_vT, s_o);
      // Wo-projection with fused residual (+x_b) -> s_kq holds x+attn_out
      gemm_bt<0, 0><<<dim3(4, CM / 128), 256, 0, stream>>>(
          s_o, woT + lw, bo + l * 512, s_kq, CM, 512, 512, x_b + R * 512);
      ln_k<<<CM / 4, 256, 0, stream>>>(
          s_kq, g1 + l * 512, be1 + l * 512, x_b + R * 512);
      for (int mc = 0; mc < CM; mc += MI) {
        gemm_bt<1, 0><<<dim3(16, MI / 128), 256, 0, stream>>>(
            x_b + (R + mc) * 512, w1T + (size_t)l * 512 * 2048, b1 + l * 2048,
            s_t, MI, 2048, 512, nullptr);
        // FFN-down with fused residual (+x_b) -> s_vT holds x+ffn_out
        gemm_bt<0, 0><<<dim3(4, MI / 128), 256, 0, stream>>>(
            s_t, w2T + (size_t)l * 2048 * 512, b2 + l * 512,
            s_vT + (size_t)mc * 512, MI, 512, 2048, x_b + (R + mc) * 512);
      }
      ln_k<<<CM / 4, 256, 0, stream>>>(
          s_vT, g2 + l * 512, be2 + l * 512, x_b + R * 512);
    }
  }

  for (int cc = 0; cc < NC; ++cc) {
    const size_t R = (size_t)cc * CM;
    concat2_k<<<CM / 4, 256, 0, stream>>>(x_b + R * 512, qd + R, qemb, s_kq);
    gemm_bt<1, 0><<<dim3(4, CM / 128), 256, 0, stream>>>(
        s_kq, wo1T, bo1, s_o, CM, 512, 1024, nullptr);
    gemm_bt<1, 0><<<dim3(2, CM / 128), 256, 0, stream>>>(
        s_o, wo2T, bo2, s_t, CM, 256, 512, nullptr);
    gemm_bt<0, 1><<<dim3(3, CM / 128), 256, 0, stream>>>(
        s_t, wo3T, bo3, out + R * 300, CM, 300, 256, nullptr);
  }
}

// Round 10
// 2393.474 us; speedup vs baseline: 1.1039x; 1.1039x over previous
//
#include <hip/hip_runtime.h>

// simpleKT forward on gfx950: bf16 MFMA GEMMs + flash-style causal attention
// (transposed-scores formulation; P stays in registers; coalesced O epilogue;
//  XCD-aware block swizzle for K/V L2 locality).
// R10: R8 + R9's attn pairing ONLY. R9 postmortem: (a) attn q-tile pairing
//  was a win (85->77us/dispatch despite ~28MB spill returning — uniform 5
//  chunks/block beats the imbalanced 4-round schedule); (b) residual fusion
//  into GEMM epilogues was PATHOLOGICAL (one FFN-down at 932us, MfmaUtil
//  1.7%, occupancy 2.8% — scalar strided resid reads stall-storm the
//  epilogue at 1 block/CU). So: keep (a), revert (b) -> two-input ln_res,
//  resid-free gemm_core.
// History: R0 2844 (spill-bound) -> R5 2491 (spill dead) -> R6 2371 (cvt_pk
//  + BK=64) -> R7 2419 (dbuf regr) -> R8 2349 (recombine) -> R9 2642 (resid
//  fusion regr).
// B=64 S=512 D=512 H=8 DK=64 L=4 DFF=2048 NSK=300 FC1=512 FC2=256.
// ENVELOPE RULE: kernels use <=256 threads and <=32KB static LDS; no
// dynamic-LDS opt-in, no hipFuncSetAttribute.

typedef unsigned short u16;
typedef __attribute__((ext_vector_type(8))) short short8;   // 8 bf16 - 16x16x32 A/B frag
typedef __attribute__((ext_vector_type(4))) short short4v;  // 4 bf16 - 16x16x16 A/B frag
typedef __attribute__((ext_vector_type(4))) float f32x4;    // MFMA C/D frag

#define DEV __device__ __forceinline__

DEV float bf2f(u16 u) { return __uint_as_float(((unsigned int)u) << 16); }
DEV u16 f2bf(float f) {
  unsigned int u = __float_as_uint(f);
  u += 0x7FFFu + ((u >> 16) & 1u);
  return (u16)(u >> 16);
}

// v_cvt_pk_bf16_f32: low16 = bf16(lo), high16 = bf16(hi); RNE — bit-identical
// to f2bf for finite inputs.
DEV unsigned cvt_pk_bf16(float lo, float hi) {
  unsigned r;
  asm("v_cvt_pk_bf16_f32 %0, %1, %2" : "=v"(r) : "v"(lo), "v"(hi));
  return r;
}

template <bool V> struct BoolC { static constexpr bool value = V; };

DEV void gl2l16(const void* g, void* l) {
  __builtin_amdgcn_global_load_lds(
      (__attribute__((address_space(1))) void*)g,
      (__attribute__((address_space(3))) void*)l, 16, 0, 0);
}

#define MFMA16(a, b, c) __builtin_amdgcn_mfma_f32_16x16x32_bf16(a, b, c, 0, 0, 0)

// 16x16x16 bf16 MFMA (K=16: k = (lane>>4)*4+j — matches C-layout rows)
#if defined(__has_builtin)
#if __has_builtin(__builtin_amdgcn_mfma_f32_16x16x16bf16_1k)
#define MFMA16X16(a, b, c) __builtin_amdgcn_mfma_f32_16x16x16bf16_1k(a, b, c, 0, 0, 0)
#elif __has_builtin(__builtin_amdgcn_mfma_f32_16x16x16_bf16)
#define MFMA16X16(a, b, c) __builtin_amdgcn_mfma_f32_16x16x16_bf16(a, b, c, 0, 0, 0)
#endif
#endif
#ifndef MFMA16X16
DEV f32x4 mfma_16x16x16_bf16_asm(short4v a, short4v b, f32x4 c) {
  f32x4 d;
  asm("v_mfma_f32_16x16x16_bf16 %0, %1, %2, %3\n\ts_nop 7\n\ts_nop 3"
      : "=&v"(d) : "v"(a), "v"(b), "v"(c));
  return d;
}
#define MFMA16X16(a, b, c) mfma_16x16x16_bf16_asm(a, b, c)
#endif

// ---------------------------------------------------------------------------
// Weight convert+transpose: fp32 [K,N] (batched over z) -> bf16 [N,K]
// ---------------------------------------------------------------------------
__global__ __launch_bounds__(256) void transpose_cvt(
    const float* __restrict__ src, u16* __restrict__ dst, int K, int N)
{
  src += (size_t)blockIdx.z * K * N;
  dst += (size_t)blockIdx.z * K * N;
  __shared__ alignas(16) float tile[32][33];
  const int tx = threadIdx.x & 31, ty = threadIdx.x >> 5;
  const int n0 = blockIdx.x * 32, k0 = blockIdx.y * 32;
#pragma unroll
  for (int i = 0; i < 4; ++i) {
    int k = k0 + ty + i * 8, n = n0 + tx;
    if (k < K && n < N) tile[ty + i * 8][tx] = src[(size_t)k * N + n];
  }
  __syncthreads();
#pragma unroll
  for (int i = 0; i < 4; ++i) {
    int n = n0 + ty + i * 8, k = k0 + tx;
    if (n < N && k < K) dst[(size_t)n * K + k] = f2bf(tile[tx][ty + i * 8]);
  }
}

// ---------------------------------------------------------------------------
// Embedding: x = q_emb[q_data] + pe[s]; y = qa_emb[target] + q_emb[q_data] + pe[s]
// ---------------------------------------------------------------------------
__global__ __launch_bounds__(256) void embed_k(
    const int* __restrict__ qd, const int* __restrict__ tg,
    const float* __restrict__ pe, const float* __restrict__ qe, const float* __restrict__ qa,
    u16* __restrict__ x_b, u16* __restrict__ y_b)
{
  const int row = blockIdx.x * 4 + (threadIdx.x >> 6);
  const int lane = threadIdx.x & 63;
  const int s = row & 511;
  const int idx = qd[row];
  const int tt = tg[row];
  const int c = lane * 8;
  const float* q = qe + (size_t)idx * 512 + c;
  const float* p = pe + (size_t)s * 512 + c;
  const float* a = qa + (size_t)tt * 512 + c;
  float4 q0 = *(const float4*)q, q1 = *(const float4*)(q + 4);
  float4 p0 = *(const float4*)p, p1 = *(const float4*)(p + 4);
  float4 a0 = *(const float4*)a, a1 = *(const float4*)(a + 4);
  float qv[8] = {q0.x, q0.y, q0.z, q0.w, q1.x, q1.y, q1.z, q1.w};
  float pv[8] = {p0.x, p0.y, p0.z, p0.w, p1.x, p1.y, p1.z, p1.w};
  float av[8] = {a0.x, a0.y, a0.z, a0.w, a1.x, a1.y, a1.z, a1.w};
  short8 ox, oy;
#pragma unroll
  for (int i = 0; i < 8; ++i) {
    ox[i] = (short)f2bf(qv[i] + pv[i]);
    oy[i] = (short)f2bf(qv[i] + pv[i] + av[i]);
  }
  size_t base = (size_t)row * 512 + c;
  *(short8*)(x_b + base) = ox;
  *(short8*)(y_b + base) = oy;
}

// ---------------------------------------------------------------------------
// bf16 GEMM core: C[M,N] = act((A[M,K] @ Bt[N,K]^T + bias) * oscale)
// 128x128 tile, BK=64, 256 thr. Staging: 16 sub-tiles of (8 rows x 64 cols),
// wave w owns tb = w*4+i; slot swizzle ps = (lane&7)^(r&7) with r&7 == lane>>3
// (uniform across tb). Per K-step: 8 gl2l16, one barrier pair, 2x16 MFMA.
// OUTM: 0 = bf16 row-major, 1 = f32 row-major, 2 = bf16 scatter vT[b,h,dk,s].
// ---------------------------------------------------------------------------
template <int ACT, int OUTM>
DEV void gemm_core(u16* As, u16* Bs,
                   const u16* __restrict__ A, const u16* __restrict__ Bt,
                   const float* __restrict__ bias, void* __restrict__ Cv,
                   int M, int N, int K, int bx, int by, float oscale)
{
  const int lane = threadIdx.x & 63;
  const int w = threadIdx.x >> 6;
  const int wm = w >> 1, wn = w & 1;
  const int m0 = by * 128, n0 = bx * 128;

  // staging addresses: rows rs_+8i (i<4), slot ps_ (8 u16 = 16B)
  const int rs_ = w * 32 + (lane >> 3);
  const int ps_ = (lane & 7) ^ (lane >> 3);   // r&7 == lane>>3 for all tb
  const u16* pa = A + (size_t)(m0 + rs_) * K + ps_ * 8;
  const u16* pb[4];
#pragma unroll
  for (int i = 0; i < 4; ++i) {
    int rb = n0 + rs_ + i * 8;
    rb = (rb < N) ? rb : (N - 1);
    pb[i] = Bt + (size_t)rb * K + ps_ * 8;
  }
  u16* la = As + (w * 4 * 64 + lane) * 8;
  u16* lb = Bs + (w * 4 * 64 + lane) * 8;

  f32x4 acc[4][4];
#pragma unroll
  for (int a_ = 0; a_ < 4; ++a_)
#pragma unroll
    for (int b_ = 0; b_ < 4; ++b_)
#pragma unroll
      for (int i = 0; i < 4; ++i) acc[a_][b_][i] = 0.f;

  for (int k0 = 0; k0 < K; k0 += 64) {
#pragma unroll
    for (int i = 0; i < 4; ++i) gl2l16(pa + (size_t)i * 8 * K, la + i * 64 * 8);
#pragma unroll
    for (int i = 0; i < 4; ++i) gl2l16(pb[i], lb + i * 64 * 8);
    pa += 64;
#pragma unroll
    for (int i = 0; i < 4; ++i) pb[i] += 64;
    __syncthreads();
#pragma unroll
    for (int ks = 0; ks < 2; ++ks) {
      short8 af[4], bf[4];
#pragma unroll
      for (int i = 0; i < 4; ++i) {
        int r = wm * 64 + i * 16 + (lane & 15);
        af[i] = *(const short8*)(As + (r * 8 + ((ks * 4 + (lane >> 4)) ^ (r & 7))) * 8);
        int r2 = wn * 64 + i * 16 + (lane & 15);
        bf[i] = *(const short8*)(Bs + (r2 * 8 + ((ks * 4 + (lane >> 4)) ^ (r2 & 7))) * 8);
      }
#pragma unroll
      for (int mt = 0; mt < 4; ++mt)
#pragma unroll
        for (int nt = 0; nt < 4; ++nt)
          acc[mt][nt] = MFMA16(af[mt], bf[nt], acc[mt][nt]);
    }
    __syncthreads();
  }

  const int row0 = m0 + wm * 64, col0 = n0 + wn * 64;
#pragma unroll
  for (int mt = 0; mt < 4; ++mt) {
#pragma unroll
    for (int nt = 0; nt < 4; ++nt) {
      int c = col0 + nt * 16 + (lane & 15);
      int r = row0 + mt * 16 + (lane >> 4) * 4;
      if (c < N) {
        float bz = bias[c];
#pragma unroll
        for (int i = 0; i < 4; ++i) {
          float v = (acc[mt][nt][i] + bz) * oscale;
          if (ACT == 1) v = fmaxf(v, 0.f);
          int m = r + i;
          if (OUTM == 0) {
            ((u16*)Cv)[(size_t)m * N + c] = f2bf(v);
          } else if (OUTM == 1) {
            ((float*)Cv)[(size_t)m * N + c] = v;
          } else {  // vT[b][h][dk][s]: m=(b,s) local, c=(h,dk)
            size_t idx = ((((size_t)(m >> 9)) * 8 + (c >> 6)) * 64 + (c & 63)) * 512 + (m & 511);
            ((u16*)Cv)[idx] = f2bf(v);
          }
        }
      }
    }
  }
}

template <int ACT, int OUTM>
__global__ __launch_bounds__(256) void gemm_bt(
    const u16* __restrict__ A, const u16* __restrict__ Bt,
    const float* __restrict__ bias, void* __restrict__ Cv,
    int M, int N, int K)
{
  __shared__ alignas(16) u16 As[128 * 64];
  __shared__ alignas(16) u16 Bs[128 * 64];
  gemm_core<ACT, OUTM>(As, Bs, A, Bt, bias, Cv, M, N, K, blockIdx.x, blockIdx.y, 1.f);
}

// fused K/V projection: z=0 -> x@Wk (scaled by os0) -> s_kq (OUTM 0);
//                       z=1 -> y@Wv -> vT (OUTM 2)
__global__ __launch_bounds__(256) void gemm_kv(
    const u16* __restrict__ A0, const u16* __restrict__ Bt0,
    const float* __restrict__ b0, void* __restrict__ C0,
    const u16* __restrict__ A1, const u16* __restrict__ Bt1,
    const float* __restrict__ b1, void* __restrict__ C1,
    int M, int N, int K, float os0)
{
  __shared__ alignas(16) u16 As[128 * 64];
  __shared__ alignas(16) u16 Bs[128 * 64];
  if (blockIdx.z == 0)
    gemm_core<0, 0>(As, Bs, A0, Bt0, b0, C0, M, N, K, blockIdx.x, blockIdx.y, os0);
  else
    gemm_core<0, 2>(As, Bs, A1, Bt1, b1, C1, M, N, K, blockIdx.x, blockIdx.y, 1.f);
}

// ---------------------------------------------------------------------------
// Flash attention, transposed scores. grid (pair=2, h=8, b=NB), 256 thr.
// Each block processes TWO q-tiles {3-p, p} sequentially -> uniform 5
// chunks/block, 1024 blocks = one residency round (4/CU), zero imbalance
// (R9 measured: 85->77us despite ~28MB spill returning).
// Unswizzle: l = x + 2*(y+8*z); bh = (l&7)+8*(l>>4), p = (l>>3)&1 -> both
// blocks of a (b,h) share l%8 (same XCD under round-robin) for K/V L2 hits.
// Wave w owns q-cols [w*32, w*32+32). S^T = K Q^T via 16x16x32 (keys=M, q=N);
// C-layout: q = lane&15 (col), key = (lane>>4)*4+i (row). P^T stays in regs as
// 16x16x16 B-frags; O^T = V^T P^T with dk as M.
// Q/K arrive PRE-SCALED by sqrt(0.125*log2e) (gemm_kv z=0 epilogue), so QK^T
// emerges directly in the exp2 domain — no per-element scale pass (R7).
// All LDS staging regions (Q/K/V/epilogue scratch) are wave-private ranges
// of Ks/Vs, so the barrier structure is unchanged by the outer 2-tile loop.
// Each chunk = two 64-key halves with their own online-softmax update.
// Softmax: masked = -1e30, plain-subtract exp2; P->bf16 via cvt_pk (R6).
// Epilogue bounces O^T through wave-private LDS (XOR swizzle) for coalesced
// short8 stores. LDS 32KB.
// ---------------------------------------------------------------------------
__global__ __launch_bounds__(256, 2) void attn_k(
    const u16* __restrict__ kq, const u16* __restrict__ vT, u16* __restrict__ o)
{
  __shared__ alignas(16) u16 Ks[128 * 64];
  __shared__ alignas(16) u16 Vs[64 * 128];
  const int l = blockIdx.x + 2 * (blockIdx.y + 8 * blockIdx.z);
  const int bh = (l & 7) + 8 * (l >> 4);
  const int pr = (l >> 3) & 1;
  const int h = bh & 7, b = bh >> 3;
  const int lane = threadIdx.x & 63;
  const int w = threadIdx.x >> 6;
  const size_t kq_base = ((size_t)b * 512) * 512 + h * 64;

  for (int pi = 0; pi < 2; ++pi) {
    const int t = pi ? pr : 3 - pr;   // pr=0 -> {3,0}; pr=1 -> {2,1}: 5 chunks
    const int q0 = t * 128;

    // stage Q tile [128 x 64] into Ks (wave-private region), pull B-frags
#pragma unroll
    for (int i = 0; i < 4; ++i) {
      int tb = w * 4 + i;
      int r = tb * 8 + (lane >> 3);
      int ps = (lane & 7) ^ (r & 7);
      gl2l16(kq + kq_base + (size_t)(q0 + r) * 512 + ps * 8, Ks + (tb * 64 + lane) * 8);
    }
    __syncthreads();
    short8 qf[2][2];
#pragma unroll
    for (int nt = 0; nt < 2; ++nt)
#pragma unroll
      for (int ks = 0; ks < 2; ++ks) {
        int q = w * 32 + nt * 16 + (lane & 15);
        int ch = ks * 4 + (lane >> 4);
        qf[nt][ks] = *(const short8*)(Ks + (q * 8 + (ch ^ (q & 7))) * 8);
      }

    f32x4 of[4][2];  // [dk-tile][q-tile]; col=q=lane&15, row=dk=(lane>>4)*4+i
    float m_st[2] = {-1e30f, -1e30f}, l_st[2] = {0.f, 0.f};  // exp2 domain
#pragma unroll
    for (int d = 0; d < 4; ++d)
#pragma unroll
      for (int nt = 0; nt < 2; ++nt)
#pragma unroll
        for (int i = 0; i < 4; ++i) of[d][nt][i] = 0.f;

    auto chunk = [&](int j, auto diagc) {
      constexpr bool DIAG = decltype(diagc)::value;
      // diagonal chunk: wave w needs keys < w*32+32 -> key-tiles mt < 2w+2
      const int MT = DIAG ? (2 * w + 2) : 8;
      const int k0 = j * 128;

      // two 64-key halves, each with its own online-softmax update: halves
      // the sc/pf live range -> fits the 128-reg target (R3/R5 spill fix).
#pragma unroll
      for (int hh = 0; hh < 2; ++hh) {
        if (!DIAG || MT > hh * 4) {
          const int MTl = DIAG ? ((MT - hh * 4 < 4) ? MT - hh * 4 : 4) : 4;

          // S^T = K Q^T (this half's 4 key-tiles) — already exp2-scaled
          f32x4 sc[4][2];
          __builtin_amdgcn_s_setprio(1);
#pragma unroll
          for (int mt = 0; mt < 4; ++mt)
            if (!DIAG || mt < MTl) {
#pragma unroll
              for (int nt = 0; nt < 2; ++nt)
#pragma unroll
                for (int i = 0; i < 4; ++i) sc[mt][nt][i] = 0.f;
#pragma unroll
              for (int ks = 0; ks < 2; ++ks) {
                int key = (hh * 4 + mt) * 16 + (lane & 15);
                int ch = ks * 4 + (lane >> 4);
                short8 kf = *(const short8*)(Ks + (key * 8 + (ch ^ (key & 7))) * 8);
                sc[mt][0] = MFMA16(kf, qf[0][ks], sc[mt][0]);
                sc[mt][1] = MFMA16(kf, qf[1][ks], sc[mt][1]);
              }
            }
          __builtin_amdgcn_s_setprio(0);

          // strict causal mask (diag chunk only; no scale pass needed)
          if (DIAG) {
#pragma unroll
            for (int mt = 0; mt < 4; ++mt)
              if (mt < MTl) {
#pragma unroll
                for (int nt = 0; nt < 2; ++nt) {
                  int qg = q0 + w * 32 + nt * 16 + (lane & 15);
#pragma unroll
                  for (int i = 0; i < 4; ++i) {
                    int kg = k0 + (hh * 4 + mt) * 16 + (lane >> 4) * 4 + i;
                    if (kg >= qg) sc[mt][nt][i] = -1e30f;
                  }
                }
              }
          }

          // online softmax (exp2 domain): per-lane scalar state (q=lane&15)
          short4v pf[4][2];
#pragma unroll
          for (int nt = 0; nt < 2; ++nt) {
            float mx = -1e30f;
#pragma unroll
            for (int mt = 0; mt < 4; ++mt)
              if (!DIAG || mt < MTl) {
#pragma unroll
                for (int i = 0; i < 4; ++i) mx = fmaxf(mx, sc[mt][nt][i]);
              }
            mx = fmaxf(mx, __shfl_xor(mx, 16));
            mx = fmaxf(mx, __shfl_xor(mx, 32));
            float mo = m_st[nt];
            float mn = fmaxf(mo, mx);
            float al = exp2f(mo - mn);
            float rs = 0.f;
#pragma unroll
            for (int mt = 0; mt < 4; ++mt)
              if (!DIAG || mt < MTl) {
#pragma unroll
                for (int i = 0; i < 4; ++i) {
                  float pv = exp2f(sc[mt][nt][i] - mn);
                  sc[mt][nt][i] = pv;
                  rs += pv;
                }
              }
            rs += __shfl_xor(rs, 16);
            rs += __shfl_xor(rs, 32);
            m_st[nt] = mn;
            l_st[nt] = l_st[nt] * al + rs;
#pragma unroll
            for (int d = 0; d < 4; ++d)
#pragma unroll
              for (int i = 0; i < 4; ++i) of[d][nt][i] *= al;
            // pack P^T to bf16 16x16x16 B-frags via cvt_pk
#pragma unroll
            for (int mt = 0; mt < 4; ++mt)
              if (!DIAG || mt < MTl) {
                union { unsigned u[2]; short4v s; } cv;
                cv.u[0] = cvt_pk_bf16(sc[mt][nt][0], sc[mt][nt][1]);
                cv.u[1] = cvt_pk_bf16(sc[mt][nt][2], sc[mt][nt][3]);
                pf[mt][nt] = cv.s;
              }
          }

          // O^T += V^T P^T  (A = V^T frag: m=dk, k=key; 16x16x16)
          __builtin_amdgcn_s_setprio(1);
#pragma unroll
          for (int mt = 0; mt < 4; ++mt)
            if (!DIAG || mt < MTl) {
              int key4 = (hh * 4 + mt) * 16 + (lane >> 4) * 4;
#pragma unroll
              for (int d = 0; d < 4; ++d) {
                int dk = d * 16 + (lane & 15);
                short4v vf = *(const short4v*)(
                    Vs + (dk * 16 + ((key4 >> 3) ^ (dk & 15))) * 8 + (key4 & 7));
                of[d][0] = MFMA16X16(vf, pf[mt][0], of[d][0]);
                of[d][1] = MFMA16X16(vf, pf[mt][1], of[d][1]);
              }
            }
          __builtin_amdgcn_s_setprio(0);
        }
      }
    };

    for (int j = 0; j <= t; ++j) {
      const int k0 = j * 128;
      __syncthreads();  // all waves done reading prior chunk's Ks/Vs
#pragma unroll
      for (int i = 0; i < 4; ++i) {  // K chunk [128 keys x 64]
        int tb = w * 4 + i;
        int r = tb * 8 + (lane >> 3);
        int ps = (lane & 7) ^ (r & 7);
        gl2l16(kq + kq_base + (size_t)(k0 + r) * 512 + ps * 8, Ks + (tb * 64 + lane) * 8);
      }
#pragma unroll
      for (int i = 0; i < 4; ++i) {  // V^T chunk [64 dk x 128 keys]
        int tb = w * 4 + i;
        int r = tb * 4 + (lane >> 4);
        int ps = (lane & 15) ^ (r & 15);
        gl2l16(vT + ((size_t)((b * 8 + h) * 64 + r)) * 512 + k0 + ps * 8, Vs + (tb * 64 + lane) * 8);
      }
      __syncthreads();
      if (j < t) {
        chunk(j, BoolC<false>{});
      } else {
        chunk(j, BoolC<true>{});
      }
    }

    // epilogue: O^T -> wave-private LDS (swizzled) -> coalesced stores
    __syncthreads();  // all waves done reading Ks/Vs
    u16* Ws = Ks + w * 2048;  // 32 q-rows x 64 dk per wave
#pragma unroll
    for (int nt = 0; nt < 2; ++nt) {
      int qrow = nt * 16 + (lane & 15);
      int qg = q0 + w * 32 + qrow;
      float li = l_st[nt];
      float inv = (qg > 0 && li > 0.f) ? (1.f / li) : 0.f;
      int sw = (qrow & 7) * 8;
#pragma unroll
      for (int d = 0; d < 4; ++d)
#pragma unroll
        for (int i = 0; i < 4; ++i) {
          int dk = d * 16 + (lane >> 4) * 4 + i;
          Ws[qrow * 64 + (dk ^ sw)] = f2bf(of[d][nt][i] * inv);
        }
    }
    // wave-private: no barrier needed (lgkmcnt ordering within wave)
#pragma unroll
    for (int p = 0; p < 4; ++p) {
      int qrow = p * 8 + (lane >> 3);
      int c = lane & 7;
      short8 vv = *(const short8*)(Ws + qrow * 64 + ((c ^ (qrow & 7)) * 8));
      int qg = q0 + w * 32 + qrow;
      *(short8*)(o + ((size_t)b * 512 + qg) * 512 + h * 64 + c * 8) = vv;
    }
  }
}

// ---------------------------------------------------------------------------
// LayerNorm(x + res); one wave per 512-col row; in-place safe.
// ---------------------------------------------------------------------------
__global__ __launch_bounds__(256) void ln_res(
    const u16* __restrict__ xin, const u16* __restrict__ res,
    const float* __restrict__ gam, const float* __restrict__ bet, u16* __restrict__ xout)
{
  const int row = blockIdx.x * 4 + (threadIdx.x >> 6);
  const int lane = threadIdx.x & 63;
  const size_t base = (size_t)row * 512 + lane * 8;
  short8 xv = *(const short8*)(xin + base);
  short8 rv = *(const short8*)(res + base);
  float v[8];
  float s = 0.f, s2 = 0.f;
#pragma unroll
  for (int i = 0; i < 8; ++i) {
    float a = bf2f((u16)xv[i]) + bf2f((u16)rv[i]);
    v[i] = a;
    s += a;
    s2 += a * a;
  }
#pragma unroll
  for (int d = 1; d < 64; d <<= 1) {
    s += __shfl_xor(s, d);
    s2 += __shfl_xor(s2, d);
  }
  float mean = s * (1.f / 512.f);
  float var = s2 * (1.f / 512.f) - mean * mean;
  float rstd = rsqrtf(var + 1e-5f);
  const int c = lane * 8;
  short8 ov;
#pragma unroll
  for (int i = 0; i < 8; ++i) {
    float ot = (v[i] - mean) * rstd * gam[c + i] + bet[c + i];
    ov[i] = (short)f2bf(ot);
  }
  *(short8*)(xout + base) = ov;
}

// ---------------------------------------------------------------------------
// concat [x, q_emb[q_data]] -> cat [rows,1024] bf16
// ---------------------------------------------------------------------------
__global__ __launch_bounds__(256) void concat2_k(
    const u16* __restrict__ x, const int* __restrict__ qd,
    const float* __restrict__ qemb, u16* __restrict__ cat)
{
  const int row = blockIdx.x * 4 + (threadIdx.x >> 6);
  const int lane = threadIdx.x & 63;
  *(short8*)(cat + (size_t)row * 1024 + lane * 8) =
      *(const short8*)(x + (size_t)row * 512 + lane * 8);
  const int idx = qd[row];
  const float* q = qemb + (size_t)idx * 512 + lane * 8;
  float4 q0 = *(const float4*)q, q1 = *(const float4*)(q + 4);
  float qv[8] = {q0.x, q0.y, q0.z, q0.w, q1.x, q1.y, q1.z, q1.w};
  short8 ov;
#pragma unroll
  for (int i = 0; i < 8; ++i) ov[i] = (short)f2bf(qv[i]);
  *(short8*)(cat + (size_t)row * 1024 + 512 + lane * 8) = ov;
}

// ---------------------------------------------------------------------------
extern "C" void kernel_launch(void* const* d_in, const int* in_sizes, int n_in,
                              void* d_out, int out_size, void* d_ws, size_t ws_size,
                              hipStream_t stream)
{
  const int* qd = (const int*)d_in[0];
  const int* tg = (const int*)d_in[1];
  const float* pe = (const float*)d_in[2];
  const float* qemb = (const float*)d_in[3];
  const float* qa = (const float*)d_in[4];
  const float* Wk = (const float*)d_in[5];
  const float* bk = (const float*)d_in[6];
  const float* Wv = (const float*)d_in[7];
  const float* bv = (const float*)d_in[8];
  const float* Wo = (const float*)d_in[9];
  const float* bo = (const float*)d_in[10];
  const float* g1 = (const float*)d_in[11];
  const float* be1 = (const float*)d_in[12];
  const float* W1 = (const float*)d_in[13];
  const float* b1 = (const float*)d_in[14];
  const float* W2 = (const float*)d_in[15];
  const float* b2 = (const float*)d_in[16];
  const float* g2 = (const float*)d_in[17];
  const float* be2 = (const float*)d_in[18];
  const float* Wo1 = (const float*)d_in[19];
  const float* bo1 = (const float*)d_in[20];
  const float* Wo2 = (const float*)d_in[21];
  const float* bo2 = (const float*)d_in[22];
  const float* Wo3 = (const float*)d_in[23];
  const float* bo3 = (const float*)d_in[24];
  float* out = (float*)d_out;

  const int BS = 64 * 512;  // 32768
  const float SQS = 0.42466089f;  // sqrt(0.125 * log2(e)) — QK pre-scale

  // batch-group chunking from ws_size (constant per process -> graph-safe)
  const size_t WU16 = 12266496ull;
  int NC = 1;
  {
    auto need = [&](int nc) -> size_t {
      size_t CMr = (size_t)BS / nc;
      size_t st = CMr < 8192 ? CMr : 8192;
      return 2ull * (WU16 + 2ull * BS * 512 + 3ull * CMr * 512 + st * 2048);
    };
    if (ws_size < need(1)) NC = 4;
    if (NC == 4 && ws_size < need(4)) NC = 8;
  }
  const int CM = BS / NC;
  const int MI = CM < 8192 ? CM : 8192;

  u16* p = (u16*)d_ws;
  u16* wkT = p;  p += 4 * 512 * 512;
  u16* wvT = p;  p += 4 * 512 * 512;
  u16* woT = p;  p += 4 * 512 * 512;
  u16* w1T = p;  p += 4 * 512 * 2048;
  u16* w2T = p;  p += 4 * 2048 * 512;
  u16* wo1T = p; p += 1024 * 512;
  u16* wo2T = p; p += 512 * 256;
  u16* wo3T = p; p += 300 * 256;
  u16* x_b = p;  p += (size_t)BS * 512;
  u16* y_b = p;  p += (size_t)BS * 512;
  u16* s_kq = p; p += (size_t)CM * 512;   // also head-cat first half
  u16* s_vT = p; p += (size_t)CM * 512;   // adjacent: cat = s_kq[CM x 1024]
  u16* s_o = p;  p += (size_t)CM * 512;
  u16* s_t = p;                            // MI x 2048 FFN / head scratch

  transpose_cvt<<<dim3(16, 16, 4), 256, 0, stream>>>(Wk, wkT, 512, 512);
  transpose_cvt<<<dim3(16, 16, 4), 256, 0, stream>>>(Wv, wvT, 512, 512);
  transpose_cvt<<<dim3(16, 16, 4), 256, 0, stream>>>(Wo, woT, 512, 512);
  transpose_cvt<<<dim3(64, 16, 4), 256, 0, stream>>>(W1, w1T, 512, 2048);
  transpose_cvt<<<dim3(16, 64, 4), 256, 0, stream>>>(W2, w2T, 2048, 512);
  transpose_cvt<<<dim3(16, 32, 1), 256, 0, stream>>>(Wo1, wo1T, 1024, 512);
  transpose_cvt<<<dim3(8, 16, 1), 256, 0, stream>>>(Wo2, wo2T, 512, 256);
  transpose_cvt<<<dim3(10, 8, 1), 256, 0, stream>>>(Wo3, wo3T, 256, 300);

  embed_k<<<BS / 4, 256, 0, stream>>>(qd, tg, pe, qemb, qa, x_b, y_b);

  for (int l = 0; l < 4; ++l) {
    const size_t lw = (size_t)l * 512 * 512;
    for (int cc = 0; cc < NC; ++cc) {
      const size_t R = (size_t)cc * CM;
      // fused q/k + v projections (kq_same=1); q/k pre-scaled for exp2 domain
      gemm_kv<<<dim3(4, CM / 128, 2), 256, 0, stream>>>(
          x_b + R * 512, wkT + lw, bk + l * 512, s_kq,
          y_b + R * 512, wvT + lw, bv + l * 512, s_vT, CM, 512, 512, SQS);
      attn_k<<<dim3(2, 8, CM / 512), 256, 0, stream>>>(s_kq, s_vT, s_o);
      gemm_bt<0, 0><<<dim3(4, CM / 128), 256, 0, stream>>>(
          s_o, woT + lw, bo + l * 512, s_kq, CM, 512, 512);
      ln_res<<<CM / 4, 256, 0, stream>>>(
          x_b + R * 512, s_kq, g1 + l * 512, be1 + l * 512, x_b + R * 512);
      for (int mc = 0; mc < CM; mc += MI) {
        gemm_bt<1, 0><<<dim3(16, MI / 128), 256, 0, stream>>>(
            x_b + (R + mc) * 512, w1T + (size_t)l * 512 * 2048, b1 + l * 2048,
            s_t, MI, 2048, 512);
        gemm_bt<0, 0><<<dim3(4, MI / 128), 256, 0, stream>>>(
            s_t, w2T + (size_t)l * 2048 * 512, b2 + l * 512,
            s_vT + (size_t)mc * 512, MI, 512, 2048);
      }
      ln_res<<<CM / 4, 256, 0, stream>>>(
          x_b + R * 512, s_vT, g2 + l * 512, be2 + l * 512, x_b + R * 512);
    }
  }

  for (int cc = 0; cc < NC; ++cc) {
    const size_t R = (size_t)cc * CM;
    concat2_k<<<CM / 4, 256, 0, stream>>>(x_b + R * 512, qd + R, qemb, s_kq);
    gemm_bt<1, 0><<<dim3(4, CM / 128), 256, 0, stream>>>(
        s_kq, wo1T, bo1, s_o, CM, 512, 1024);
    gemm_bt<1, 0><<<dim3(2, CM / 128), 256, 0, stream>>>(
        s_o, wo2T, bo2, s_t, CM, 256, 512);
    gemm_bt<0, 1><<<dim3(3, CM / 128), 256, 0, stream>>>(
        s_t, wo3T, bo3, out + R * 300, CM, 300, 256);
  }
}

// Round 11
// 2339.453 us; speedup vs baseline: 1.1294x; 1.0231x over previous
//
#include <hip/hip_runtime.h>

// simpleKT forward on gfx950: bf16 MFMA GEMMs + flash-style causal attention
// (transposed-scores formulation; P stays in registers; coalesced O epilogue;
//  XCD-aware block swizzle for K/V L2 locality).
// R11: R10 + "#pragma unroll 1" on attn_k's pi (q-tile pair) loop.
//  R10 postmortem: pairing cut attn dispatch 85->76us BUT reintroduced
//  ~27 regs of spill (WRITE 32.7->60MB; VGPR 120->128) — the compiler
//  UNROLLS the trip-count-2 pi loop, doubling live ranges past the 128-reg
//  target R8's single-tile body fit under. Forcing rolled execution keeps
//  pairing's schedule win (uniform 5 chunks/block, one residency round)
//  at R8's register footprint. Single-variable change for attribution.
// History: R0 2844 (spill-bound) -> R5 2491 (spill dead) -> R6 2371 (cvt_pk
//  + BK=64) -> R8 2349 (recombine) -> R9 2642 (resid fusion regr) ->
//  R10 2393 (pairing good, unroll-spill bad).
// B=64 S=512 D=512 H=8 DK=64 L=4 DFF=2048 NSK=300 FC1=512 FC2=256.
// ENVELOPE RULE: kernels use <=256 threads and <=32KB static LDS; no
// dynamic-LDS opt-in, no hipFuncSetAttribute.

typedef unsigned short u16;
typedef __attribute__((ext_vector_type(8))) short short8;   // 8 bf16 - 16x16x32 A/B frag
typedef __attribute__((ext_vector_type(4))) short short4v;  // 4 bf16 - 16x16x16 A/B frag
typedef __attribute__((ext_vector_type(4))) float f32x4;    // MFMA C/D frag

#define DEV __device__ __forceinline__

DEV float bf2f(u16 u) { return __uint_as_float(((unsigned int)u) << 16); }
DEV u16 f2bf(float f) {
  unsigned int u = __float_as_uint(f);
  u += 0x7FFFu + ((u >> 16) & 1u);
  return (u16)(u >> 16);
}

// v_cvt_pk_bf16_f32: low16 = bf16(lo), high16 = bf16(hi); RNE — bit-identical
// to f2bf for finite inputs.
DEV unsigned cvt_pk_bf16(float lo, float hi) {
  unsigned r;
  asm("v_cvt_pk_bf16_f32 %0, %1, %2" : "=v"(r) : "v"(lo), "v"(hi));
  return r;
}

template <bool V> struct BoolC { static constexpr bool value = V; };

DEV void gl2l16(const void* g, void* l) {
  __builtin_amdgcn_global_load_lds(
      (__attribute__((address_space(1))) void*)g,
      (__attribute__((address_space(3))) void*)l, 16, 0, 0);
}

#define MFMA16(a, b, c) __builtin_amdgcn_mfma_f32_16x16x32_bf16(a, b, c, 0, 0, 0)

// 16x16x16 bf16 MFMA (K=16: k = (lane>>4)*4+j — matches C-layout rows)
#if defined(__has_builtin)
#if __has_builtin(__builtin_amdgcn_mfma_f32_16x16x16bf16_1k)
#define MFMA16X16(a, b, c) __builtin_amdgcn_mfma_f32_16x16x16bf16_1k(a, b, c, 0, 0, 0)
#elif __has_builtin(__builtin_amdgcn_mfma_f32_16x16x16_bf16)
#define MFMA16X16(a, b, c) __builtin_amdgcn_mfma_f32_16x16x16_bf16(a, b, c, 0, 0, 0)
#endif
#endif
#ifndef MFMA16X16
DEV f32x4 mfma_16x16x16_bf16_asm(short4v a, short4v b, f32x4 c) {
  f32x4 d;
  asm("v_mfma_f32_16x16x16_bf16 %0, %1, %2, %3\n\ts_nop 7\n\ts_nop 3"
      : "=&v"(d) : "v"(a), "v"(b), "v"(c));
  return d;
}
#define MFMA16X16(a, b, c) mfma_16x16x16_bf16_asm(a, b, c)
#endif

// ---------------------------------------------------------------------------
// Weight convert+transpose: fp32 [K,N] (batched over z) -> bf16 [N,K]
// ---------------------------------------------------------------------------
__global__ __launch_bounds__(256) void transpose_cvt(
    const float* __restrict__ src, u16* __restrict__ dst, int K, int N)
{
  src += (size_t)blockIdx.z * K * N;
  dst += (size_t)blockIdx.z * K * N;
  __shared__ alignas(16) float tile[32][33];
  const int tx = threadIdx.x & 31, ty = threadIdx.x >> 5;
  const int n0 = blockIdx.x * 32, k0 = blockIdx.y * 32;
#pragma unroll
  for (int i = 0; i < 4; ++i) {
    int k = k0 + ty + i * 8, n = n0 + tx;
    if (k < K && n < N) tile[ty + i * 8][tx] = src[(size_t)k * N + n];
  }
  __syncthreads();
#pragma unroll
  for (int i = 0; i < 4; ++i) {
    int n = n0 + ty + i * 8, k = k0 + tx;
    if (n < N && k < K) dst[(size_t)n * K + k] = f2bf(tile[tx][ty + i * 8]);
  }
}

// ---------------------------------------------------------------------------
// Embedding: x = q_emb[q_data] + pe[s]; y = qa_emb[target] + q_emb[q_data] + pe[s]
// ---------------------------------------------------------------------------
__global__ __launch_bounds__(256) void embed_k(
    const int* __restrict__ qd, const int* __restrict__ tg,
    const float* __restrict__ pe, const float* __restrict__ qe, const float* __restrict__ qa,
    u16* __restrict__ x_b, u16* __restrict__ y_b)
{
  const int row = blockIdx.x * 4 + (threadIdx.x >> 6);
  const int lane = threadIdx.x & 63;
  const int s = row & 511;
  const int idx = qd[row];
  const int tt = tg[row];
  const int c = lane * 8;
  const float* q = qe + (size_t)idx * 512 + c;
  const float* p = pe + (size_t)s * 512 + c;
  const float* a = qa + (size_t)tt * 512 + c;
  float4 q0 = *(const float4*)q, q1 = *(const float4*)(q + 4);
  float4 p0 = *(const float4*)p, p1 = *(const float4*)(p + 4);
  float4 a0 = *(const float4*)a, a1 = *(const float4*)(a + 4);
  float qv[8] = {q0.x, q0.y, q0.z, q0.w, q1.x, q1.y, q1.z, q1.w};
  float pv[8] = {p0.x, p0.y, p0.z, p0.w, p1.x, p1.y, p1.z, p1.w};
  float av[8] = {a0.x, a0.y, a0.z, a0.w, a1.x, a1.y, a1.z, a1.w};
  short8 ox, oy;
#pragma unroll
  for (int i = 0; i < 8; ++i) {
    ox[i] = (short)f2bf(qv[i] + pv[i]);
    oy[i] = (short)f2bf(qv[i] + pv[i] + av[i]);
  }
  size_t base = (size_t)row * 512 + c;
  *(short8*)(x_b + base) = ox;
  *(short8*)(y_b + base) = oy;
}

// ---------------------------------------------------------------------------
// bf16 GEMM core: C[M,N] = act((A[M,K] @ Bt[N,K]^T + bias) * oscale)
// 128x128 tile, BK=64, 256 thr. Staging: 16 sub-tiles of (8 rows x 64 cols),
// wave w owns tb = w*4+i; slot swizzle ps = (lane&7)^(r&7) with r&7 == lane>>3
// (uniform across tb). Per K-step: 8 gl2l16, one barrier pair, 2x16 MFMA.
// OUTM: 0 = bf16 row-major, 1 = f32 row-major, 2 = bf16 scatter vT[b,h,dk,s].
// ---------------------------------------------------------------------------
template <int ACT, int OUTM>
DEV void gemm_core(u16* As, u16* Bs,
                   const u16* __restrict__ A, const u16* __restrict__ Bt,
                   const float* __restrict__ bias, void* __restrict__ Cv,
                   int M, int N, int K, int bx, int by, float oscale)
{
  const int lane = threadIdx.x & 63;
  const int w = threadIdx.x >> 6;
  const int wm = w >> 1, wn = w & 1;
  const int m0 = by * 128, n0 = bx * 128;

  // staging addresses: rows rs_+8i (i<4), slot ps_ (8 u16 = 16B)
  const int rs_ = w * 32 + (lane >> 3);
  const int ps_ = (lane & 7) ^ (lane >> 3);   // r&7 == lane>>3 for all tb
  const u16* pa = A + (size_t)(m0 + rs_) * K + ps_ * 8;
  const u16* pb[4];
#pragma unroll
  for (int i = 0; i < 4; ++i) {
    int rb = n0 + rs_ + i * 8;
    rb = (rb < N) ? rb : (N - 1);
    pb[i] = Bt + (size_t)rb * K + ps_ * 8;
  }
  u16* la = As + (w * 4 * 64 + lane) * 8;
  u16* lb = Bs + (w * 4 * 64 + lane) * 8;

  f32x4 acc[4][4];
#pragma unroll
  for (int a_ = 0; a_ < 4; ++a_)
#pragma unroll
    for (int b_ = 0; b_ < 4; ++b_)
#pragma unroll
      for (int i = 0; i < 4; ++i) acc[a_][b_][i] = 0.f;

  for (int k0 = 0; k0 < K; k0 += 64) {
#pragma unroll
    for (int i = 0; i < 4; ++i) gl2l16(pa + (size_t)i * 8 * K, la + i * 64 * 8);
#pragma unroll
    for (int i = 0; i < 4; ++i) gl2l16(pb[i], lb + i * 64 * 8);
    pa += 64;
#pragma unroll
    for (int i = 0; i < 4; ++i) pb[i] += 64;
    __syncthreads();
#pragma unroll
    for (int ks = 0; ks < 2; ++ks) {
      short8 af[4], bf[4];
#pragma unroll
      for (int i = 0; i < 4; ++i) {
        int r = wm * 64 + i * 16 + (lane & 15);
        af[i] = *(const short8*)(As + (r * 8 + ((ks * 4 + (lane >> 4)) ^ (r & 7))) * 8);
        int r2 = wn * 64 + i * 16 + (lane & 15);
        bf[i] = *(const short8*)(Bs + (r2 * 8 + ((ks * 4 + (lane >> 4)) ^ (r2 & 7))) * 8);
      }
#pragma unroll
      for (int mt = 0; mt < 4; ++mt)
#pragma unroll
        for (int nt = 0; nt < 4; ++nt)
          acc[mt][nt] = MFMA16(af[mt], bf[nt], acc[mt][nt]);
    }
    __syncthreads();
  }

  const int row0 = m0 + wm * 64, col0 = n0 + wn * 64;
#pragma unroll
  for (int mt = 0; mt < 4; ++mt) {
#pragma unroll
    for (int nt = 0; nt < 4; ++nt) {
      int c = col0 + nt * 16 + (lane & 15);
      int r = row0 + mt * 16 + (lane >> 4) * 4;
      if (c < N) {
        float bz = bias[c];
#pragma unroll
        for (int i = 0; i < 4; ++i) {
          float v = (acc[mt][nt][i] + bz) * oscale;
          if (ACT == 1) v = fmaxf(v, 0.f);
          int m = r + i;
          if (OUTM == 0) {
            ((u16*)Cv)[(size_t)m * N + c] = f2bf(v);
          } else if (OUTM == 1) {
            ((float*)Cv)[(size_t)m * N + c] = v;
          } else {  // vT[b][h][dk][s]: m=(b,s) local, c=(h,dk)
            size_t idx = ((((size_t)(m >> 9)) * 8 + (c >> 6)) * 64 + (c & 63)) * 512 + (m & 511);
            ((u16*)Cv)[idx] = f2bf(v);
          }
        }
      }
    }
  }
}

template <int ACT, int OUTM>
__global__ __launch_bounds__(256) void gemm_bt(
    const u16* __restrict__ A, const u16* __restrict__ Bt,
    const float* __restrict__ bias, void* __restrict__ Cv,
    int M, int N, int K)
{
  __shared__ alignas(16) u16 As[128 * 64];
  __shared__ alignas(16) u16 Bs[128 * 64];
  gemm_core<ACT, OUTM>(As, Bs, A, Bt, bias, Cv, M, N, K, blockIdx.x, blockIdx.y, 1.f);
}

// fused K/V projection: z=0 -> x@Wk (scaled by os0) -> s_kq (OUTM 0);
//                       z=1 -> y@Wv -> vT (OUTM 2)
__global__ __launch_bounds__(256) void gemm_kv(
    const u16* __restrict__ A0, const u16* __restrict__ Bt0,
    const float* __restrict__ b0, void* __restrict__ C0,
    const u16* __restrict__ A1, const u16* __restrict__ Bt1,
    const float* __restrict__ b1, void* __restrict__ C1,
    int M, int N, int K, float os0)
{
  __shared__ alignas(16) u16 As[128 * 64];
  __shared__ alignas(16) u16 Bs[128 * 64];
  if (blockIdx.z == 0)
    gemm_core<0, 0>(As, Bs, A0, Bt0, b0, C0, M, N, K, blockIdx.x, blockIdx.y, os0);
  else
    gemm_core<0, 2>(As, Bs, A1, Bt1, b1, C1, M, N, K, blockIdx.x, blockIdx.y, 1.f);
}

// ---------------------------------------------------------------------------
// Flash attention, transposed scores. grid (pair=2, h=8, b=NB), 256 thr.
// Each block processes TWO q-tiles {3-p, p} sequentially -> uniform 5
// chunks/block, 1024 blocks = one residency round (4/CU), zero imbalance.
// R11: "#pragma unroll 1" on the pi loop — R10's compiler-unrolled pair
// doubled live ranges and spilled ~27 regs (WRITE 60MB vs 32.7MB). Rolled
// execution keeps the schedule win at R8's ~120-reg footprint.
// Unswizzle: l = x + 2*(y+8*z); bh = (l&7)+8*(l>>4), p = (l>>3)&1 -> both
// blocks of a (b,h) share l%8 (same XCD under round-robin) for K/V L2 hits.
// Wave w owns q-cols [w*32, w*32+32). S^T = K Q^T via 16x16x32 (keys=M, q=N);
// C-layout: q = lane&15 (col), key = (lane>>4)*4+i (row). P^T stays in regs as
// 16x16x16 B-frags; O^T = V^T P^T with dk as M.
// Q/K arrive PRE-SCALED by sqrt(0.125*log2e) (gemm_kv z=0 epilogue), so QK^T
// emerges directly in the exp2 domain — no per-element scale pass (R7).
// All LDS staging regions are wave-private, so the barrier structure is
// unchanged by the outer 2-tile loop. Each chunk = two 64-key halves with
// their own online-softmax update. Softmax: masked = -1e30, plain-subtract
// exp2; P->bf16 via cvt_pk (R6). Epilogue bounces O^T through wave-private
// LDS (XOR swizzle) for coalesced short8 stores. LDS 32KB.
// ---------------------------------------------------------------------------
__global__ __launch_bounds__(256, 2) void attn_k(
    const u16* __restrict__ kq, const u16* __restrict__ vT, u16* __restrict__ o)
{
  __shared__ alignas(16) u16 Ks[128 * 64];
  __shared__ alignas(16) u16 Vs[64 * 128];
  const int l = blockIdx.x + 2 * (blockIdx.y + 8 * blockIdx.z);
  const int bh = (l & 7) + 8 * (l >> 4);
  const int pr = (l >> 3) & 1;
  const int h = bh & 7, b = bh >> 3;
  const int lane = threadIdx.x & 63;
  const int w = threadIdx.x >> 6;
  const size_t kq_base = ((size_t)b * 512) * 512 + h * 64;

#pragma unroll 1
  for (int pi = 0; pi < 2; ++pi) {
    const int t = pi ? pr : 3 - pr;   // pr=0 -> {3,0}; pr=1 -> {2,1}: 5 chunks
    const int q0 = t * 128;

    // stage Q tile [128 x 64] into Ks (wave-private region), pull B-frags
#pragma unroll
    for (int i = 0; i < 4; ++i) {
      int tb = w * 4 + i;
      int r = tb * 8 + (lane >> 3);
      int ps = (lane & 7) ^ (r & 7);
      gl2l16(kq + kq_base + (size_t)(q0 + r) * 512 + ps * 8, Ks + (tb * 64 + lane) * 8);
    }
    __syncthreads();
    short8 qf[2][2];
#pragma unroll
    for (int nt = 0; nt < 2; ++nt)
#pragma unroll
      for (int ks = 0; ks < 2; ++ks) {
        int q = w * 32 + nt * 16 + (lane & 15);
        int ch = ks * 4 + (lane >> 4);
        qf[nt][ks] = *(const short8*)(Ks + (q * 8 + (ch ^ (q & 7))) * 8);
      }

    f32x4 of[4][2];  // [dk-tile][q-tile]; col=q=lane&15, row=dk=(lane>>4)*4+i
    float m_st[2] = {-1e30f, -1e30f}, l_st[2] = {0.f, 0.f};  // exp2 domain
#pragma unroll
    for (int d = 0; d < 4; ++d)
#pragma unroll
      for (int nt = 0; nt < 2; ++nt)
#pragma unroll
        for (int i = 0; i < 4; ++i) of[d][nt][i] = 0.f;

    auto chunk = [&](int j, auto diagc) {
      constexpr bool DIAG = decltype(diagc)::value;
      // diagonal chunk: wave w needs keys < w*32+32 -> key-tiles mt < 2w+2
      const int MT = DIAG ? (2 * w + 2) : 8;
      const int k0 = j * 128;

      // two 64-key halves, each with its own online-softmax update: halves
      // the sc/pf live range -> fits the 128-reg target (R3/R5 spill fix).
#pragma unroll
      for (int hh = 0; hh < 2; ++hh) {
        if (!DIAG || MT > hh * 4) {
          const int MTl = DIAG ? ((MT - hh * 4 < 4) ? MT - hh * 4 : 4) : 4;

          // S^T = K Q^T (this half's 4 key-tiles) — already exp2-scaled
          f32x4 sc[4][2];
          __builtin_amdgcn_s_setprio(1);
#pragma unroll
          for (int mt = 0; mt < 4; ++mt)
            if (!DIAG || mt < MTl) {
#pragma unroll
              for (int nt = 0; nt < 2; ++nt)
#pragma unroll
                for (int i = 0; i < 4; ++i) sc[mt][nt][i] = 0.f;
#pragma unroll
              for (int ks = 0; ks < 2; ++ks) {
                int key = (hh * 4 + mt) * 16 + (lane & 15);
                int ch = ks * 4 + (lane >> 4);
                short8 kf = *(const short8*)(Ks + (key * 8 + (ch ^ (key & 7))) * 8);
                sc[mt][0] = MFMA16(kf, qf[0][ks], sc[mt][0]);
                sc[mt][1] = MFMA16(kf, qf[1][ks], sc[mt][1]);
              }
            }
          __builtin_amdgcn_s_setprio(0);

          // strict causal mask (diag chunk only; no scale pass needed)
          if (DIAG) {
#pragma unroll
            for (int mt = 0; mt < 4; ++mt)
              if (mt < MTl) {
#pragma unroll
                for (int nt = 0; nt < 2; ++nt) {
                  int qg = q0 + w * 32 + nt * 16 + (lane & 15);
#pragma unroll
                  for (int i = 0; i < 4; ++i) {
                    int kg = k0 + (hh * 4 + mt) * 16 + (lane >> 4) * 4 + i;
                    if (kg >= qg) sc[mt][nt][i] = -1e30f;
                  }
                }
              }
          }

          // online softmax (exp2 domain): per-lane scalar state (q=lane&15)
          short4v pf[4][2];
#pragma unroll
          for (int nt = 0; nt < 2; ++nt) {
            float mx = -1e30f;
#pragma unroll
            for (int mt = 0; mt < 4; ++mt)
              if (!DIAG || mt < MTl) {
#pragma unroll
                for (int i = 0; i < 4; ++i) mx = fmaxf(mx, sc[mt][nt][i]);
              }
            mx = fmaxf(mx, __shfl_xor(mx, 16));
            mx = fmaxf(mx, __shfl_xor(mx, 32));
            float mo = m_st[nt];
            float mn = fmaxf(mo, mx);
            float al = exp2f(mo - mn);
            float rs = 0.f;
#pragma unroll
            for (int mt = 0; mt < 4; ++mt)
              if (!DIAG || mt < MTl) {
#pragma unroll
                for (int i = 0; i < 4; ++i) {
                  float pv = exp2f(sc[mt][nt][i] - mn);
                  sc[mt][nt][i] = pv;
                  rs += pv;
                }
              }
            rs += __shfl_xor(rs, 16);
            rs += __shfl_xor(rs, 32);
            m_st[nt] = mn;
            l_st[nt] = l_st[nt] * al + rs;
#pragma unroll
            for (int d = 0; d < 4; ++d)
#pragma unroll
              for (int i = 0; i < 4; ++i) of[d][nt][i] *= al;
            // pack P^T to bf16 16x16x16 B-frags via cvt_pk
#pragma unroll
            for (int mt = 0; mt < 4; ++mt)
              if (!DIAG || mt < MTl) {
                union { unsigned u[2]; short4v s; } cv;
                cv.u[0] = cvt_pk_bf16(sc[mt][nt][0], sc[mt][nt][1]);
                cv.u[1] = cvt_pk_bf16(sc[mt][nt][2], sc[mt][nt][3]);
                pf[mt][nt] = cv.s;
              }
          }

          // O^T += V^T P^T  (A = V^T frag: m=dk, k=key; 16x16x16)
          __builtin_amdgcn_s_setprio(1);
#pragma unroll
          for (int mt = 0; mt < 4; ++mt)
            if (!DIAG || mt < MTl) {
              int key4 = (hh * 4 + mt) * 16 + (lane >> 4) * 4;
#pragma unroll
              for (int d = 0; d < 4; ++d) {
                int dk = d * 16 + (lane & 15);
                short4v vf = *(const short4v*)(
                    Vs + (dk * 16 + ((key4 >> 3) ^ (dk & 15))) * 8 + (key4 & 7));
                of[d][0] = MFMA16X16(vf, pf[mt][0], of[d][0]);
                of[d][1] = MFMA16X16(vf, pf[mt][1], of[d][1]);
              }
            }
          __builtin_amdgcn_s_setprio(0);
        }
      }
    };

#pragma unroll 1
    for (int j = 0; j <= t; ++j) {
      const int k0 = j * 128;
      __syncthreads();  // all waves done reading prior chunk's Ks/Vs
#pragma unroll
      for (int i = 0; i < 4; ++i) {  // K chunk [128 keys x 64]
        int tb = w * 4 + i;
        int r = tb * 8 + (lane >> 3);
        int ps = (lane & 7) ^ (r & 7);
        gl2l16(kq + kq_base + (size_t)(k0 + r) * 512 + ps * 8, Ks + (tb * 64 + lane) * 8);
      }
#pragma unroll
      for (int i = 0; i < 4; ++i) {  // V^T chunk [64 dk x 128 keys]
        int tb = w * 4 + i;
        int r = tb * 4 + (lane >> 4);
        int ps = (lane & 15) ^ (r & 15);
        gl2l16(vT + ((size_t)((b * 8 + h) * 64 + r)) * 512 + k0 + ps * 8, Vs + (tb * 64 + lane) * 8);
      }
      __syncthreads();
      if (j < t) {
        chunk(j, BoolC<false>{});
      } else {
        chunk(j, BoolC<true>{});
      }
    }

    // epilogue: O^T -> wave-private LDS (swizzled) -> coalesced stores
    __syncthreads();  // all waves done reading Ks/Vs
    u16* Ws = Ks + w * 2048;  // 32 q-rows x 64 dk per wave
#pragma unroll
    for (int nt = 0; nt < 2; ++nt) {
      int qrow = nt * 16 + (lane & 15);
      int qg = q0 + w * 32 + qrow;
      float li = l_st[nt];
      float inv = (qg > 0 && li > 0.f) ? (1.f / li) : 0.f;
      int sw = (qrow & 7) * 8;
#pragma unroll
      for (int d = 0; d < 4; ++d)
#pragma unroll
        for (int i = 0; i < 4; ++i) {
          int dk = d * 16 + (lane >> 4) * 4 + i;
          Ws[qrow * 64 + (dk ^ sw)] = f2bf(of[d][nt][i] * inv);
        }
    }
    // wave-private: no barrier needed (lgkmcnt ordering within wave)
#pragma unroll
    for (int p = 0; p < 4; ++p) {
      int qrow = p * 8 + (lane >> 3);
      int c = lane & 7;
      short8 vv = *(const short8*)(Ws + qrow * 64 + ((c ^ (qrow & 7)) * 8));
      int qg = q0 + w * 32 + qrow;
      *(short8*)(o + ((size_t)b * 512 + qg) * 512 + h * 64 + c * 8) = vv;
    }
  }
}

// ---------------------------------------------------------------------------
// LayerNorm(x + res); one wave per 512-col row; in-place safe.
// ---------------------------------------------------------------------------
__global__ __launch_bounds__(256) void ln_res(
    const u16* __restrict__ xin, const u16* __restrict__ res,
    const float* __restrict__ gam, const float* __restrict__ bet, u16* __restrict__ xout)
{
  const int row = blockIdx.x * 4 + (threadIdx.x >> 6);
  const int lane = threadIdx.x & 63;
  const size_t base = (size_t)row * 512 + lane * 8;
  short8 xv = *(const short8*)(xin + base);
  short8 rv = *(const short8*)(res + base);
  float v[8];
  float s = 0.f, s2 = 0.f;
#pragma unroll
  for (int i = 0; i < 8; ++i) {
    float a = bf2f((u16)xv[i]) + bf2f((u16)rv[i]);
    v[i] = a;
    s += a;
    s2 += a * a;
  }
#pragma unroll
  for (int d = 1; d < 64; d <<= 1) {
    s += __shfl_xor(s, d);
    s2 += __shfl_xor(s2, d);
  }
  float mean = s * (1.f / 512.f);
  float var = s2 * (1.f / 512.f) - mean * mean;
  float rstd = rsqrtf(var + 1e-5f);
  const int c = lane * 8;
  short8 ov;
#pragma unroll
  for (int i = 0; i < 8; ++i) {
    float ot = (v[i] - mean) * rstd * gam[c + i] + bet[c + i];
    ov[i] = (short)f2bf(ot);
  }
  *(short8*)(xout + base) = ov;
}

// ---------------------------------------------------------------------------
// concat [x, q_emb[q_data]] -> cat [rows,1024] bf16
// ---------------------------------------------------------------------------
__global__ __launch_bounds__(256) void concat2_k(
    const u16* __restrict__ x, const int* __restrict__ qd,
    const float* __restrict__ qemb, u16* __restrict__ cat)
{
  const int row = blockIdx.x * 4 + (threadIdx.x >> 6);
  const int lane = threadIdx.x & 63;
  *(short8*)(cat + (size_t)row * 1024 + lane * 8) =
      *(const short8*)(x + (size_t)row * 512 + lane * 8);
  const int idx = qd[row];
  const float* q = qemb + (size_t)idx * 512 + lane * 8;
  float4 q0 = *(const float4*)q, q1 = *(const float4*)(q + 4);
  float qv[8] = {q0.x, q0.y, q0.z, q0.w, q1.x, q1.y, q1.z, q1.w};
  short8 ov;
#pragma unroll
  for (int i = 0; i < 8; ++i) ov[i] = (short)f2bf(qv[i]);
  *(short8*)(cat + (size_t)row * 1024 + 512 + lane * 8) = ov;
}

// ---------------------------------------------------------------------------
extern "C" void kernel_launch(void* const* d_in, const int* in_sizes, int n_in,
                              void* d_out, int out_size, void* d_ws, size_t ws_size,
                              hipStream_t stream)
{
  const int* qd = (const int*)d_in[0];
  const int* tg = (const int*)d_in[1];
  const float* pe = (const float*)d_in[2];
  const float* qemb = (const float*)d_in[3];
  const float* qa = (const float*)d_in[4];
  const float* Wk = (const float*)d_in[5];
  const float* bk = (const float*)d_in[6];
  const float* Wv = (const float*)d_in[7];
  const float* bv = (const float*)d_in[8];
  const float* Wo = (const float*)d_in[9];
  const float* bo = (const float*)d_in[10];
  const float* g1 = (const float*)d_in[11];
  const float* be1 = (const float*)d_in[12];
  const float* W1 = (const float*)d_in[13];
  const float* b1 = (const float*)d_in[14];
  const float* W2 = (const float*)d_in[15];
  const float* b2 = (const float*)d_in[16];
  const float* g2 = (const float*)d_in[17];
  const float* be2 = (const float*)d_in[18];
  const float* Wo1 = (const float*)d_in[19];
  const float* bo1 = (const float*)d_in[20];
  const float* Wo2 = (const float*)d_in[21];
  const float* bo2 = (const float*)d_in[22];
  const float* Wo3 = (const float*)d_in[23];
  const float* bo3 = (const float*)d_in[24];
  float* out = (float*)d_out;

  const int BS = 64 * 512;  // 32768
  const float SQS = 0.42466089f;  // sqrt(0.125 * log2(e)) — QK pre-scale

  // batch-group chunking from ws_size (constant per process -> graph-safe)
  const size_t WU16 = 12266496ull;
  int NC = 1;
  {
    auto need = [&](int nc) -> size_t {
      size_t CMr = (size_t)BS / nc;
      size_t st = CMr < 8192 ? CMr : 8192;
      return 2ull * (WU16 + 2ull * BS * 512 + 3ull * CMr * 512 + st * 2048);
    };
    if (ws_size < need(1)) NC = 4;
    if (NC == 4 && ws_size < need(4)) NC = 8;
  }
  const int CM = BS / NC;
  const int MI = CM < 8192 ? CM : 8192;

  u16* p = (u16*)d_ws;
  u16* wkT = p;  p += 4 * 512 * 512;
  u16* wvT = p;  p += 4 * 512 * 512;
  u16* woT = p;  p += 4 * 512 * 512;
  u16* w1T = p;  p += 4 * 512 * 2048;
  u16* w2T = p;  p += 4 * 2048 * 512;
  u16* wo1T = p; p += 1024 * 512;
  u16* wo2T = p; p += 512 * 256;
  u16* wo3T = p; p += 300 * 256;
  u16* x_b = p;  p += (size_t)BS * 512;
  u16* y_b = p;  p += (size_t)BS * 512;
  u16* s_kq = p; p += (size_t)CM * 512;   // also head-cat first half
  u16* s_vT = p; p += (size_t)CM * 512;   // adjacent: cat = s_kq[CM x 1024]
  u16* s_o = p;  p += (size_t)CM * 512;
  u16* s_t = p;                            // MI x 2048 FFN / head scratch

  transpose_cvt<<<dim3(16, 16, 4), 256, 0, stream>>>(Wk, wkT, 512, 512);
  transpose_cvt<<<dim3(16, 16, 4), 256, 0, stream>>>(Wv, wvT, 512, 512);
  transpose_cvt<<<dim3(16, 16, 4), 256, 0, stream>>>(Wo, woT, 512, 512);
  transpose_cvt<<<dim3(64, 16, 4), 256, 0, stream>>>(W1, w1T, 512, 2048);
  transpose_cvt<<<dim3(16, 64, 4), 256, 0, stream>>>(W2, w2T, 2048, 512);
  transpose_cvt<<<dim3(16, 32, 1), 256, 0, stream>>>(Wo1, wo1T, 1024, 512);
  transpose_cvt<<<dim3(8, 16, 1), 256, 0, stream>>>(Wo2, wo2T, 512, 256);
  transpose_cvt<<<dim3(10, 8, 1), 256, 0, stream>>>(Wo3, wo3T, 256, 300);

  embed_k<<<BS / 4, 256, 0, stream>>>(qd, tg, pe, qemb, qa, x_b, y_b);

  for (int l = 0; l < 4; ++l) {
    const size_t lw = (size_t)l * 512 * 512;
    for (int cc = 0; cc < NC; ++cc) {
      const size_t R = (size_t)cc * CM;
      // fused q/k + v projections (kq_same=1); q/k pre-scaled for exp2 domain
      gemm_kv<<<dim3(4, CM / 128, 2), 256, 0, stream>>>(
          x_b + R * 512, wkT + lw, bk + l * 512, s_kq,
          y_b + R * 512, wvT + lw, bv + l * 512, s_vT, CM, 512, 512, SQS);
      attn_k<<<dim3(2, 8, CM / 512), 256, 0, stream>>>(s_kq, s_vT, s_o);
      gemm_bt<0, 0><<<dim3(4, CM / 128), 256, 0, stream>>>(
          s_o, woT + lw, bo + l * 512, s_kq, CM, 512, 512);
      ln_res<<<CM / 4, 256, 0, stream>>>(
          x_b + R * 512, s_kq, g1 + l * 512, be1 + l * 512, x_b + R * 512);
      for (int mc = 0; mc < CM; mc += MI) {
        gemm_bt<1, 0><<<dim3(16, MI / 128), 256, 0, stream>>>(
            x_b + (R + mc) * 512, w1T + (size_t)l * 512 * 2048, b1 + l * 2048,
            s_t, MI, 2048, 512);
        gemm_bt<0, 0><<<dim3(4, MI / 128), 256, 0, stream>>>(
            s_t, w2T + (size_t)l * 2048 * 512, b2 + l * 512,
            s_vT + (size_t)mc * 512, MI, 512, 2048);
      }
      ln_res<<<CM / 4, 256, 0, stream>>>(
          x_b + R * 512, s_vT, g2 + l * 512, be2 + l * 512, x_b + R * 512);
    }
  }

  for (int cc = 0; cc < NC; ++cc) {
    const size_t R = (size_t)cc * CM;
    concat2_k<<<CM / 4, 256, 0, stream>>>(x_b + R * 512, qd + R, qemb, s_kq);
    gemm_bt<1, 0><<<dim3(4, CM / 128), 256, 0, stream>>>(
        s_kq, wo1T, bo1, s_o, CM, 512, 1024);
    gemm_bt<1, 0><<<dim3(2, CM / 128), 256, 0, stream>>>(
        s_o, wo2T, bo2, s_t, CM, 256, 512);
    gemm_bt<0, 1><<<dim3(3, CM / 128), 256, 0, stream>>>(
        s_t, wo3T, bo3, out + R * 300, CM, 300, 256);
  }
}

// Round 12
// 1994.588 us; speedup vs baseline: 1.3247x; 1.1729x over previous
//
#include <hip/hip_runtime.h>

// simpleKT forward on gfx950: bf16 MFMA GEMMs + flash-style causal attention
// (transposed-scores formulation; P stays in registers; coalesced O epilogue;
//  XCD-aware block swizzle for K/V L2 locality).
// R12: host-side only — grow MI (FFN chunk rows) beyond 8192 when workspace
//  allows. The FFN-down GEMM at MI=8192 launches 256 blocks = EXACTLY
//  1 block/CU: the single-buffer K-loop's vmcnt(0)+barrier drain has no
//  co-resident block to hide under (the cross-block overlap mechanism the
//  m97 structure depends on). MI=32768 -> 1024 blocks = 4/CU. Deterministic
//  per process (ws_size constant) -> graph-safe; falls back to 8192 if ws
//  is small. Kernels unchanged from R11.
// R11 postmortem: "#pragma unroll 1" did NOT remove the pairing spill
//  (WRITE still 60MB, VGPR 128) — spill is inherent to the paired body;
//  but paired total 2339 < R8's 2349, so pairing stays (net positive).
// History: R0 2844 (spill-bound) -> R5 2491 (spill dead) -> R6 2371 (cvt_pk
//  + BK=64) -> R8 2349 -> R9 2642 (resid fusion regr) -> R10 2393 (pair
//  unroll-spill) -> R11 2339 (rolled pair, best).
// B=64 S=512 D=512 H=8 DK=64 L=4 DFF=2048 NSK=300 FC1=512 FC2=256.
// ENVELOPE RULE: kernels use <=256 threads and <=32KB static LDS; no
// dynamic-LDS opt-in, no hipFuncSetAttribute.

typedef unsigned short u16;
typedef __attribute__((ext_vector_type(8))) short short8;   // 8 bf16 - 16x16x32 A/B frag
typedef __attribute__((ext_vector_type(4))) short short4v;  // 4 bf16 - 16x16x16 A/B frag
typedef __attribute__((ext_vector_type(4))) float f32x4;    // MFMA C/D frag

#define DEV __device__ __forceinline__

DEV float bf2f(u16 u) { return __uint_as_float(((unsigned int)u) << 16); }
DEV u16 f2bf(float f) {
  unsigned int u = __float_as_uint(f);
  u += 0x7FFFu + ((u >> 16) & 1u);
  return (u16)(u >> 16);
}

// v_cvt_pk_bf16_f32: low16 = bf16(lo), high16 = bf16(hi); RNE — bit-identical
// to f2bf for finite inputs.
DEV unsigned cvt_pk_bf16(float lo, float hi) {
  unsigned r;
  asm("v_cvt_pk_bf16_f32 %0, %1, %2" : "=v"(r) : "v"(lo), "v"(hi));
  return r;
}

template <bool V> struct BoolC { static constexpr bool value = V; };

DEV void gl2l16(const void* g, void* l) {
  __builtin_amdgcn_global_load_lds(
      (__attribute__((address_space(1))) void*)g,
      (__attribute__((address_space(3))) void*)l, 16, 0, 0);
}

#define MFMA16(a, b, c) __builtin_amdgcn_mfma_f32_16x16x32_bf16(a, b, c, 0, 0, 0)

// 16x16x16 bf16 MFMA (K=16: k = (lane>>4)*4+j — matches C-layout rows)
#if defined(__has_builtin)
#if __has_builtin(__builtin_amdgcn_mfma_f32_16x16x16bf16_1k)
#define MFMA16X16(a, b, c) __builtin_amdgcn_mfma_f32_16x16x16bf16_1k(a, b, c, 0, 0, 0)
#elif __has_builtin(__builtin_amdgcn_mfma_f32_16x16x16_bf16)
#define MFMA16X16(a, b, c) __builtin_amdgcn_mfma_f32_16x16x16_bf16(a, b, c, 0, 0, 0)
#endif
#endif
#ifndef MFMA16X16
DEV f32x4 mfma_16x16x16_bf16_asm(short4v a, short4v b, f32x4 c) {
  f32x4 d;
  asm("v_mfma_f32_16x16x16_bf16 %0, %1, %2, %3\n\ts_nop 7\n\ts_nop 3"
      : "=&v"(d) : "v"(a), "v"(b), "v"(c));
  return d;
}
#define MFMA16X16(a, b, c) mfma_16x16x16_bf16_asm(a, b, c)
#endif

// ---------------------------------------------------------------------------
// Weight convert+transpose: fp32 [K,N] (batched over z) -> bf16 [N,K]
// ---------------------------------------------------------------------------
__global__ __launch_bounds__(256) void transpose_cvt(
    const float* __restrict__ src, u16* __restrict__ dst, int K, int N)
{
  src += (size_t)blockIdx.z * K * N;
  dst += (size_t)blockIdx.z * K * N;
  __shared__ alignas(16) float tile[32][33];
  const int tx = threadIdx.x & 31, ty = threadIdx.x >> 5;
  const int n0 = blockIdx.x * 32, k0 = blockIdx.y * 32;
#pragma unroll
  for (int i = 0; i < 4; ++i) {
    int k = k0 + ty + i * 8, n = n0 + tx;
    if (k < K && n < N) tile[ty + i * 8][tx] = src[(size_t)k * N + n];
  }
  __syncthreads();
#pragma unroll
  for (int i = 0; i < 4; ++i) {
    int n = n0 + ty + i * 8, k = k0 + tx;
    if (n < N && k < K) dst[(size_t)n * K + k] = f2bf(tile[tx][ty + i * 8]);
  }
}

// ---------------------------------------------------------------------------
// Embedding: x = q_emb[q_data] + pe[s]; y = qa_emb[target] + q_emb[q_data] + pe[s]
// ---------------------------------------------------------------------------
__global__ __launch_bounds__(256) void embed_k(
    const int* __restrict__ qd, const int* __restrict__ tg,
    const float* __restrict__ pe, const float* __restrict__ qe, const float* __restrict__ qa,
    u16* __restrict__ x_b, u16* __restrict__ y_b)
{
  const int row = blockIdx.x * 4 + (threadIdx.x >> 6);
  const int lane = threadIdx.x & 63;
  const int s = row & 511;
  const int idx = qd[row];
  const int tt = tg[row];
  const int c = lane * 8;
  const float* q = qe + (size_t)idx * 512 + c;
  const float* p = pe + (size_t)s * 512 + c;
  const float* a = qa + (size_t)tt * 512 + c;
  float4 q0 = *(const float4*)q, q1 = *(const float4*)(q + 4);
  float4 p0 = *(const float4*)p, p1 = *(const float4*)(p + 4);
  float4 a0 = *(const float4*)a, a1 = *(const float4*)(a + 4);
  float qv[8] = {q0.x, q0.y, q0.z, q0.w, q1.x, q1.y, q1.z, q1.w};
  float pv[8] = {p0.x, p0.y, p0.z, p0.w, p1.x, p1.y, p1.z, p1.w};
  float av[8] = {a0.x, a0.y, a0.z, a0.w, a1.x, a1.y, a1.z, a1.w};
  short8 ox, oy;
#pragma unroll
  for (int i = 0; i < 8; ++i) {
    ox[i] = (short)f2bf(qv[i] + pv[i]);
    oy[i] = (short)f2bf(qv[i] + pv[i] + av[i]);
  }
  size_t base = (size_t)row * 512 + c;
  *(short8*)(x_b + base) = ox;
  *(short8*)(y_b + base) = oy;
}

// ---------------------------------------------------------------------------
// bf16 GEMM core: C[M,N] = act((A[M,K] @ Bt[N,K]^T + bias) * oscale)
// 128x128 tile, BK=64, 256 thr. Staging: 16 sub-tiles of (8 rows x 64 cols),
// wave w owns tb = w*4+i; slot swizzle ps = (lane&7)^(r&7) with r&7 == lane>>3
// (uniform across tb). Per K-step: 8 gl2l16, one barrier pair, 2x16 MFMA.
// OUTM: 0 = bf16 row-major, 1 = f32 row-major, 2 = bf16 scatter vT[b,h,dk,s].
// ---------------------------------------------------------------------------
template <int ACT, int OUTM>
DEV void gemm_core(u16* As, u16* Bs,
                   const u16* __restrict__ A, const u16* __restrict__ Bt,
                   const float* __restrict__ bias, void* __restrict__ Cv,
                   int M, int N, int K, int bx, int by, float oscale)
{
  const int lane = threadIdx.x & 63;
  const int w = threadIdx.x >> 6;
  const int wm = w >> 1, wn = w & 1;
  const int m0 = by * 128, n0 = bx * 128;

  // staging addresses: rows rs_+8i (i<4), slot ps_ (8 u16 = 16B)
  const int rs_ = w * 32 + (lane >> 3);
  const int ps_ = (lane & 7) ^ (lane >> 3);   // r&7 == lane>>3 for all tb
  const u16* pa = A + (size_t)(m0 + rs_) * K + ps_ * 8;
  const u16* pb[4];
#pragma unroll
  for (int i = 0; i < 4; ++i) {
    int rb = n0 + rs_ + i * 8;
    rb = (rb < N) ? rb : (N - 1);
    pb[i] = Bt + (size_t)rb * K + ps_ * 8;
  }
  u16* la = As + (w * 4 * 64 + lane) * 8;
  u16* lb = Bs + (w * 4 * 64 + lane) * 8;

  f32x4 acc[4][4];
#pragma unroll
  for (int a_ = 0; a_ < 4; ++a_)
#pragma unroll
    for (int b_ = 0; b_ < 4; ++b_)
#pragma unroll
      for (int i = 0; i < 4; ++i) acc[a_][b_][i] = 0.f;

  for (int k0 = 0; k0 < K; k0 += 64) {
#pragma unroll
    for (int i = 0; i < 4; ++i) gl2l16(pa + (size_t)i * 8 * K, la + i * 64 * 8);
#pragma unroll
    for (int i = 0; i < 4; ++i) gl2l16(pb[i], lb + i * 64 * 8);
    pa += 64;
#pragma unroll
    for (int i = 0; i < 4; ++i) pb[i] += 64;
    __syncthreads();
#pragma unroll
    for (int ks = 0; ks < 2; ++ks) {
      short8 af[4], bf[4];
#pragma unroll
      for (int i = 0; i < 4; ++i) {
        int r = wm * 64 + i * 16 + (lane & 15);
        af[i] = *(const short8*)(As + (r * 8 + ((ks * 4 + (lane >> 4)) ^ (r & 7))) * 8);
        int r2 = wn * 64 + i * 16 + (lane & 15);
        bf[i] = *(const short8*)(Bs + (r2 * 8 + ((ks * 4 + (lane >> 4)) ^ (r2 & 7))) * 8);
      }
#pragma unroll
      for (int mt = 0; mt < 4; ++mt)
#pragma unroll
        for (int nt = 0; nt < 4; ++nt)
          acc[mt][nt] = MFMA16(af[mt], bf[nt], acc[mt][nt]);
    }
    __syncthreads();
  }

  const int row0 = m0 + wm * 64, col0 = n0 + wn * 64;
#pragma unroll
  for (int mt = 0; mt < 4; ++mt) {
#pragma unroll
    for (int nt = 0; nt < 4; ++nt) {
      int c = col0 + nt * 16 + (lane & 15);
      int r = row0 + mt * 16 + (lane >> 4) * 4;
      if (c < N) {
        float bz = bias[c];
#pragma unroll
        for (int i = 0; i < 4; ++i) {
          float v = (acc[mt][nt][i] + bz) * oscale;
          if (ACT == 1) v = fmaxf(v, 0.f);
          int m = r + i;
          if (OUTM == 0) {
            ((u16*)Cv)[(size_t)m * N + c] = f2bf(v);
          } else if (OUTM == 1) {
            ((float*)Cv)[(size_t)m * N + c] = v;
          } else {  // vT[b][h][dk][s]: m=(b,s) local, c=(h,dk)
            size_t idx = ((((size_t)(m >> 9)) * 8 + (c >> 6)) * 64 + (c & 63)) * 512 + (m & 511);
            ((u16*)Cv)[idx] = f2bf(v);
          }
        }
      }
    }
  }
}

template <int ACT, int OUTM>
__global__ __launch_bounds__(256) void gemm_bt(
    const u16* __restrict__ A, const u16* __restrict__ Bt,
    const float* __restrict__ bias, void* __restrict__ Cv,
    int M, int N, int K)
{
  __shared__ alignas(16) u16 As[128 * 64];
  __shared__ alignas(16) u16 Bs[128 * 64];
  gemm_core<ACT, OUTM>(As, Bs, A, Bt, bias, Cv, M, N, K, blockIdx.x, blockIdx.y, 1.f);
}

// fused K/V projection: z=0 -> x@Wk (scaled by os0) -> s_kq (OUTM 0);
//                       z=1 -> y@Wv -> vT (OUTM 2)
__global__ __launch_bounds__(256) void gemm_kv(
    const u16* __restrict__ A0, const u16* __restrict__ Bt0,
    const float* __restrict__ b0, void* __restrict__ C0,
    const u16* __restrict__ A1, const u16* __restrict__ Bt1,
    const float* __restrict__ b1, void* __restrict__ C1,
    int M, int N, int K, float os0)
{
  __shared__ alignas(16) u16 As[128 * 64];
  __shared__ alignas(16) u16 Bs[128 * 64];
  if (blockIdx.z == 0)
    gemm_core<0, 0>(As, Bs, A0, Bt0, b0, C0, M, N, K, blockIdx.x, blockIdx.y, os0);
  else
    gemm_core<0, 2>(As, Bs, A1, Bt1, b1, C1, M, N, K, blockIdx.x, blockIdx.y, 1.f);
}

// ---------------------------------------------------------------------------
// Flash attention, transposed scores. grid (pair=2, h=8, b=NB), 256 thr.
// Each block processes TWO q-tiles {3-p, p} sequentially -> uniform 5
// chunks/block, 1024 blocks = one residency round (4/CU), zero imbalance.
// "#pragma unroll 1" on the pi loop (R11). Known tax: paired structure
// spills ~27 regs (WRITE 60MB vs 32.7 ideal) — net positive vs unpaired.
// Unswizzle: l = x + 2*(y+8*z); bh = (l&7)+8*(l>>4), p = (l>>3)&1 -> both
// blocks of a (b,h) share l%8 (same XCD under round-robin) for K/V L2 hits.
// Wave w owns q-cols [w*32, w*32+32). S^T = K Q^T via 16x16x32 (keys=M, q=N);
// C-layout: q = lane&15 (col), key = (lane>>4)*4+i (row). P^T stays in regs as
// 16x16x16 B-frags; O^T = V^T P^T with dk as M.
// Q/K arrive PRE-SCALED by sqrt(0.125*log2e) (gemm_kv z=0 epilogue), so QK^T
// emerges directly in the exp2 domain — no per-element scale pass (R7).
// All LDS staging regions are wave-private, so the barrier structure is
// unchanged by the outer 2-tile loop. Each chunk = two 64-key halves with
// their own online-softmax update. Softmax: masked = -1e30, plain-subtract
// exp2; P->bf16 via cvt_pk (R6). Epilogue bounces O^T through wave-private
// LDS (XOR swizzle) for coalesced short8 stores. LDS 32KB.
// ---------------------------------------------------------------------------
__global__ __launch_bounds__(256, 2) void attn_k(
    const u16* __restrict__ kq, const u16* __restrict__ vT, u16* __restrict__ o)
{
  __shared__ alignas(16) u16 Ks[128 * 64];
  __shared__ alignas(16) u16 Vs[64 * 128];
  const int l = blockIdx.x + 2 * (blockIdx.y + 8 * blockIdx.z);
  const int bh = (l & 7) + 8 * (l >> 4);
  const int pr = (l >> 3) & 1;
  const int h = bh & 7, b = bh >> 3;
  const int lane = threadIdx.x & 63;
  const int w = threadIdx.x >> 6;
  const size_t kq_base = ((size_t)b * 512) * 512 + h * 64;

#pragma unroll 1
  for (int pi = 0; pi < 2; ++pi) {
    const int t = pi ? pr : 3 - pr;   // pr=0 -> {3,0}; pr=1 -> {2,1}: 5 chunks
    const int q0 = t * 128;

    // stage Q tile [128 x 64] into Ks (wave-private region), pull B-frags
#pragma unroll
    for (int i = 0; i < 4; ++i) {
      int tb = w * 4 + i;
      int r = tb * 8 + (lane >> 3);
      int ps = (lane & 7) ^ (r & 7);
      gl2l16(kq + kq_base + (size_t)(q0 + r) * 512 + ps * 8, Ks + (tb * 64 + lane) * 8);
    }
    __syncthreads();
    short8 qf[2][2];
#pragma unroll
    for (int nt = 0; nt < 2; ++nt)
#pragma unroll
      for (int ks = 0; ks < 2; ++ks) {
        int q = w * 32 + nt * 16 + (lane & 15);
        int ch = ks * 4 + (lane >> 4);
        qf[nt][ks] = *(const short8*)(Ks + (q * 8 + (ch ^ (q & 7))) * 8);
      }

    f32x4 of[4][2];  // [dk-tile][q-tile]; col=q=lane&15, row=dk=(lane>>4)*4+i
    float m_st[2] = {-1e30f, -1e30f}, l_st[2] = {0.f, 0.f};  // exp2 domain
#pragma unroll
    for (int d = 0; d < 4; ++d)
#pragma unroll
      for (int nt = 0; nt < 2; ++nt)
#pragma unroll
        for (int i = 0; i < 4; ++i) of[d][nt][i] = 0.f;

    auto chunk = [&](int j, auto diagc) {
      constexpr bool DIAG = decltype(diagc)::value;
      // diagonal chunk: wave w needs keys < w*32+32 -> key-tiles mt < 2w+2
      const int MT = DIAG ? (2 * w + 2) : 8;
      const int k0 = j * 128;

      // two 64-key halves, each with its own online-softmax update: halves
      // the sc/pf live range -> fits the 128-reg target (R3/R5 spill fix).
#pragma unroll
      for (int hh = 0; hh < 2; ++hh) {
        if (!DIAG || MT > hh * 4) {
          const int MTl = DIAG ? ((MT - hh * 4 < 4) ? MT - hh * 4 : 4) : 4;

          // S^T = K Q^T (this half's 4 key-tiles) — already exp2-scaled
          f32x4 sc[4][2];
          __builtin_amdgcn_s_setprio(1);
#pragma unroll
          for (int mt = 0; mt < 4; ++mt)
            if (!DIAG || mt < MTl) {
#pragma unroll
              for (int nt = 0; nt < 2; ++nt)
#pragma unroll
                for (int i = 0; i < 4; ++i) sc[mt][nt][i] = 0.f;
#pragma unroll
              for (int ks = 0; ks < 2; ++ks) {
                int key = (hh * 4 + mt) * 16 + (lane & 15);
                int ch = ks * 4 + (lane >> 4);
                short8 kf = *(const short8*)(Ks + (key * 8 + (ch ^ (key & 7))) * 8);
                sc[mt][0] = MFMA16(kf, qf[0][ks], sc[mt][0]);
                sc[mt][1] = MFMA16(kf, qf[1][ks], sc[mt][1]);
              }
            }
          __builtin_amdgcn_s_setprio(0);

          // strict causal mask (diag chunk only; no scale pass needed)
          if (DIAG) {
#pragma unroll
            for (int mt = 0; mt < 4; ++mt)
              if (mt < MTl) {
#pragma unroll
                for (int nt = 0; nt < 2; ++nt) {
                  int qg = q0 + w * 32 + nt * 16 + (lane & 15);
#pragma unroll
                  for (int i = 0; i < 4; ++i) {
                    int kg = k0 + (hh * 4 + mt) * 16 + (lane >> 4) * 4 + i;
                    if (kg >= qg) sc[mt][nt][i] = -1e30f;
                  }
                }
              }
          }

          // online softmax (exp2 domain): per-lane scalar state (q=lane&15)
          short4v pf[4][2];
#pragma unroll
          for (int nt = 0; nt < 2; ++nt) {
            float mx = -1e30f;
#pragma unroll
            for (int mt = 0; mt < 4; ++mt)
              if (!DIAG || mt < MTl) {
#pragma unroll
                for (int i = 0; i < 4; ++i) mx = fmaxf(mx, sc[mt][nt][i]);
              }
            mx = fmaxf(mx, __shfl_xor(mx, 16));
            mx = fmaxf(mx, __shfl_xor(mx, 32));
            float mo = m_st[nt];
            float mn = fmaxf(mo, mx);
            float al = exp2f(mo - mn);
            float rs = 0.f;
#pragma unroll
            for (int mt = 0; mt < 4; ++mt)
              if (!DIAG || mt < MTl) {
#pragma unroll
                for (int i = 0; i < 4; ++i) {
                  float pv = exp2f(sc[mt][nt][i] - mn);
                  sc[mt][nt][i] = pv;
                  rs += pv;
                }
              }
            rs += __shfl_xor(rs, 16);
            rs += __shfl_xor(rs, 32);
            m_st[nt] = mn;
            l_st[nt] = l_st[nt] * al + rs;
#pragma unroll
            for (int d = 0; d < 4; ++d)
#pragma unroll
              for (int i = 0; i < 4; ++i) of[d][nt][i] *= al;
            // pack P^T to bf16 16x16x16 B-frags via cvt_pk
#pragma unroll
            for (int mt = 0; mt < 4; ++mt)
              if (!DIAG || mt < MTl) {
                union { unsigned u[2]; short4v s; } cv;
                cv.u[0] = cvt_pk_bf16(sc[mt][nt][0], sc[mt][nt][1]);
                cv.u[1] = cvt_pk_bf16(sc[mt][nt][2], sc[mt][nt][3]);
                pf[mt][nt] = cv.s;
              }
          }

          // O^T += V^T P^T  (A = V^T frag: m=dk, k=key; 16x16x16)
          __builtin_amdgcn_s_setprio(1);
#pragma unroll
          for (int mt = 0; mt < 4; ++mt)
            if (!DIAG || mt < MTl) {
              int key4 = (hh * 4 + mt) * 16 + (lane >> 4) * 4;
#pragma unroll
              for (int d = 0; d < 4; ++d) {
                int dk = d * 16 + (lane & 15);
                short4v vf = *(const short4v*)(
                    Vs + (dk * 16 + ((key4 >> 3) ^ (dk & 15))) * 8 + (key4 & 7));
                of[d][0] = MFMA16X16(vf, pf[mt][0], of[d][0]);
                of[d][1] = MFMA16X16(vf, pf[mt][1], of[d][1]);
              }
            }
          __builtin_amdgcn_s_setprio(0);
        }
      }
    };

#pragma unroll 1
    for (int j = 0; j <= t; ++j) {
      const int k0 = j * 128;
      __syncthreads();  // all waves done reading prior chunk's Ks/Vs
#pragma unroll
      for (int i = 0; i < 4; ++i) {  // K chunk [128 keys x 64]
        int tb = w * 4 + i;
        int r = tb * 8 + (lane >> 3);
        int ps = (lane & 7) ^ (r & 7);
        gl2l16(kq + kq_base + (size_t)(k0 + r) * 512 + ps * 8, Ks + (tb * 64 + lane) * 8);
      }
#pragma unroll
      for (int i = 0; i < 4; ++i) {  // V^T chunk [64 dk x 128 keys]
        int tb = w * 4 + i;
        int r = tb * 4 + (lane >> 4);
        int ps = (lane & 15) ^ (r & 15);
        gl2l16(vT + ((size_t)((b * 8 + h) * 64 + r)) * 512 + k0 + ps * 8, Vs + (tb * 64 + lane) * 8);
      }
      __syncthreads();
      if (j < t) {
        chunk(j, BoolC<false>{});
      } else {
        chunk(j, BoolC<true>{});
      }
    }

    // epilogue: O^T -> wave-private LDS (swizzled) -> coalesced stores
    __syncthreads();  // all waves done reading Ks/Vs
    u16* Ws = Ks + w * 2048;  // 32 q-rows x 64 dk per wave
#pragma unroll
    for (int nt = 0; nt < 2; ++nt) {
      int qrow = nt * 16 + (lane & 15);
      int qg = q0 + w * 32 + qrow;
      float li = l_st[nt];
      float inv = (qg > 0 && li > 0.f) ? (1.f / li) : 0.f;
      int sw = (qrow & 7) * 8;
#pragma unroll
      for (int d = 0; d < 4; ++d)
#pragma unroll
        for (int i = 0; i < 4; ++i) {
          int dk = d * 16 + (lane >> 4) * 4 + i;
          Ws[qrow * 64 + (dk ^ sw)] = f2bf(of[d][nt][i] * inv);
        }
    }
    // wave-private: no barrier needed (lgkmcnt ordering within wave)
#pragma unroll
    for (int p = 0; p < 4; ++p) {
      int qrow = p * 8 + (lane >> 3);
      int c = lane & 7;
      short8 vv = *(const short8*)(Ws + qrow * 64 + ((c ^ (qrow & 7)) * 8));
      int qg = q0 + w * 32 + qrow;
      *(short8*)(o + ((size_t)b * 512 + qg) * 512 + h * 64 + c * 8) = vv;
    }
  }
}

// ---------------------------------------------------------------------------
// LayerNorm(x + res); one wave per 512-col row; in-place safe.
// ---------------------------------------------------------------------------
__global__ __launch_bounds__(256) void ln_res(
    const u16* __restrict__ xin, const u16* __restrict__ res,
    const float* __restrict__ gam, const float* __restrict__ bet, u16* __restrict__ xout)
{
  const int row = blockIdx.x * 4 + (threadIdx.x >> 6);
  const int lane = threadIdx.x & 63;
  const size_t base = (size_t)row * 512 + lane * 8;
  short8 xv = *(const short8*)(xin + base);
  short8 rv = *(const short8*)(res + base);
  float v[8];
  float s = 0.f, s2 = 0.f;
#pragma unroll
  for (int i = 0; i < 8; ++i) {
    float a = bf2f((u16)xv[i]) + bf2f((u16)rv[i]);
    v[i] = a;
    s += a;
    s2 += a * a;
  }
#pragma unroll
  for (int d = 1; d < 64; d <<= 1) {
    s += __shfl_xor(s, d);
    s2 += __shfl_xor(s2, d);
  }
  float mean = s * (1.f / 512.f);
  float var = s2 * (1.f / 512.f) - mean * mean;
  float rstd = rsqrtf(var + 1e-5f);
  const int c = lane * 8;
  short8 ov;
#pragma unroll
  for (int i = 0; i < 8; ++i) {
    float ot = (v[i] - mean) * rstd * gam[c + i] + bet[c + i];
    ov[i] = (short)f2bf(ot);
  }
  *(short8*)(xout + base) = ov;
}

// ---------------------------------------------------------------------------
// concat [x, q_emb[q_data]] -> cat [rows,1024] bf16
// ---------------------------------------------------------------------------
__global__ __launch_bounds__(256) void concat2_k(
    const u16* __restrict__ x, const int* __restrict__ qd,
    const float* __restrict__ qemb, u16* __restrict__ cat)
{
  const int row = blockIdx.x * 4 + (threadIdx.x >> 6);
  const int lane = threadIdx.x & 63;
  *(short8*)(cat + (size_t)row * 1024 + lane * 8) =
      *(const short8*)(x + (size_t)row * 512 + lane * 8);
  const int idx = qd[row];
  const float* q = qemb + (size_t)idx * 512 + lane * 8;
  float4 q0 = *(const float4*)q, q1 = *(const float4*)(q + 4);
  float qv[8] = {q0.x, q0.y, q0.z, q0.w, q1.x, q1.y, q1.z, q1.w};
  short8 ov;
#pragma unroll
  for (int i = 0; i < 8; ++i) ov[i] = (short)f2bf(qv[i]);
  *(short8*)(cat + (size_t)row * 1024 + 512 + lane * 8) = ov;
}

// ---------------------------------------------------------------------------
extern "C" void kernel_launch(void* const* d_in, const int* in_sizes, int n_in,
                              void* d_out, int out_size, void* d_ws, size_t ws_size,
                              hipStream_t stream)
{
  const int* qd = (const int*)d_in[0];
  const int* tg = (const int*)d_in[1];
  const float* pe = (const float*)d_in[2];
  const float* qemb = (const float*)d_in[3];
  const float* qa = (const float*)d_in[4];
  const float* Wk = (const float*)d_in[5];
  const float* bk = (const float*)d_in[6];
  const float* Wv = (const float*)d_in[7];
  const float* bv = (const float*)d_in[8];
  const float* Wo = (const float*)d_in[9];
  const float* bo = (const float*)d_in[10];
  const float* g1 = (const float*)d_in[11];
  const float* be1 = (const float*)d_in[12];
  const float* W1 = (const float*)d_in[13];
  const float* b1 = (const float*)d_in[14];
  const float* W2 = (const float*)d_in[15];
  const float* b2 = (const float*)d_in[16];
  const float* g2 = (const float*)d_in[17];
  const float* be2 = (const float*)d_in[18];
  const float* Wo1 = (const float*)d_in[19];
  const float* bo1 = (const float*)d_in[20];
  const float* Wo2 = (const float*)d_in[21];
  const float* bo2 = (const float*)d_in[22];
  const float* Wo3 = (const float*)d_in[23];
  const float* bo3 = (const float*)d_in[24];
  float* out = (float*)d_out;

  const int BS = 64 * 512;  // 32768
  const float SQS = 0.42466089f;  // sqrt(0.125 * log2(e)) — QK pre-scale

  // batch-group chunking from ws_size (constant per process -> graph-safe)
  const size_t WU16 = 12266496ull;
  auto need2 = [&](int nc, size_t st) -> size_t {
    size_t CMr = (size_t)BS / nc;
    return 2ull * (WU16 + 2ull * BS * 512 + 3ull * CMr * 512 + st * 2048);
  };
  int NC = 1;
  if (ws_size < need2(1, 8192)) NC = 4;
  if (NC == 4 && ws_size < need2(4, 8192)) NC = 8;
  const int CM = BS / NC;
  int MI = CM < 8192 ? CM : 8192;
  // R12: grow the FFN chunk while workspace allows — MI=8192 gives the
  // FFN-down GEMM a 256-block grid (1 block/CU: barrier drain fully exposed,
  // no cross-block overlap). MI=CM -> 1024 blocks = 4/CU. Deterministic in
  // ws_size -> graph-safe; no-op if workspace is tight.
  while (MI < CM && ws_size >= need2(NC, (size_t)MI * 2)) MI *= 2;

  u16* p = (u16*)d_ws;
  u16* wkT = p;  p += 4 * 512 * 512;
  u16* wvT = p;  p += 4 * 512 * 512;
  u16* woT = p;  p += 4 * 512 * 512;
  u16* w1T = p;  p += 4 * 512 * 2048;
  u16* w2T = p;  p += 4 * 2048 * 512;
  u16* wo1T = p; p += 1024 * 512;
  u16* wo2T = p; p += 512 * 256;
  u16* wo3T = p; p += 300 * 256;
  u16* x_b = p;  p += (size_t)BS * 512;
  u16* y_b = p;  p += (size_t)BS * 512;
  u16* s_kq = p; p += (size_t)CM * 512;   // also head-cat first half
  u16* s_vT = p; p += (size_t)CM * 512;   // adjacent: cat = s_kq[CM x 1024]
  u16* s_o = p;  p += (size_t)CM * 512;
  u16* s_t = p;                            // MI x 2048 FFN / head scratch

  transpose_cvt<<<dim3(16, 16, 4), 256, 0, stream>>>(Wk, wkT, 512, 512);
  transpose_cvt<<<dim3(16, 16, 4), 256, 0, stream>>>(Wv, wvT, 512, 512);
  transpose_cvt<<<dim3(16, 16, 4), 256, 0, stream>>>(Wo, woT, 512, 512);
  transpose_cvt<<<dim3(64, 16, 4), 256, 0, stream>>>(W1, w1T, 512, 2048);
  transpose_cvt<<<dim3(16, 64, 4), 256, 0, stream>>>(W2, w2T, 2048, 512);
  transpose_cvt<<<dim3(16, 32, 1), 256, 0, stream>>>(Wo1, wo1T, 1024, 512);
  transpose_cvt<<<dim3(8, 16, 1), 256, 0, stream>>>(Wo2, wo2T, 512, 256);
  transpose_cvt<<<dim3(10, 8, 1), 256, 0, stream>>>(Wo3, wo3T, 256, 300);

  embed_k<<<BS / 4, 256, 0, stream>>>(qd, tg, pe, qemb, qa, x_b, y_b);

  for (int l = 0; l < 4; ++l) {
    const size_t lw = (size_t)l * 512 * 512;
    for (int cc = 0; cc < NC; ++cc) {
      const size_t R = (size_t)cc * CM;
      // fused q/k + v projections (kq_same=1); q/k pre-scaled for exp2 domain
      gemm_kv<<<dim3(4, CM / 128, 2), 256, 0, stream>>>(
          x_b + R * 512, wkT + lw, bk + l * 512, s_kq,
          y_b + R * 512, wvT + lw, bv + l * 512, s_vT, CM, 512, 512, SQS);
      attn_k<<<dim3(2, 8, CM / 512), 256, 0, stream>>>(s_kq, s_vT, s_o);
      gemm_bt<0, 0><<<dim3(4, CM / 128), 256, 0, stream>>>(
          s_o, woT + lw, bo + l * 512, s_kq, CM, 512, 512);
      ln_res<<<CM / 4, 256, 0, stream>>>(
          x_b + R * 512, s_kq, g1 + l * 512, be1 + l * 512, x_b + R * 512);
      for (int mc = 0; mc < CM; mc += MI) {
        gemm_bt<1, 0><<<dim3(16, MI / 128), 256, 0, stream>>>(
            x_b + (R + mc) * 512, w1T + (size_t)l * 512 * 2048, b1 + l * 2048,
            s_t, MI, 2048, 512);
        gemm_bt<0, 0><<<dim3(4, MI / 128), 256, 0, stream>>>(
            s_t, w2T + (size_t)l * 2048 * 512, b2 + l * 512,
            s_vT + (size_t)mc * 512, MI, 512, 2048);
      }
      ln_res<<<CM / 4, 256, 0, stream>>>(
          x_b + R * 512, s_vT, g2 + l * 512, be2 + l * 512, x_b + R * 512);
    }
  }

  for (int cc = 0; cc < NC; ++cc) {
    const size_t R = (size_t)cc * CM;
    concat2_k<<<CM / 4, 256, 0, stream>>>(x_b + R * 512, qd + R, qemb, s_kq);
    gemm_bt<1, 0><<<dim3(4, CM / 128), 256, 0, stream>>>(
        s_kq, wo1T, bo1, s_o, CM, 512, 1024);
    gemm_bt<1, 0><<<dim3(2, CM / 128), 256, 0, stream>>>(
        s_o, wo2T, bo2, s_t, CM, 256, 512);
    gemm_bt<0, 1><<<dim3(3, CM / 128), 256, 0, stream>>>(
        s_t, wo3T, bo3, out + R * 300, CM, 300, 256);
  }
}

// Round 13
// 1913.106 us; speedup vs baseline: 1.3811x; 1.0426x over previous
//
#include <hip/hip_runtime.h>

// simpleKT forward on gfx950: bf16 MFMA GEMMs + flash-style causal attention
// (transposed-scores formulation; P stays in registers; coalesced O epilogue;
//  XCD-aware block swizzle for K/V L2 locality).
// R13: attn_k softmax goes 64-key halves -> 32-key QUARTERS (sc[2][2]/
//  pf[2][2] = 24 regs vs 48). R11/R12 showed the paired body spills ~27
//  regs (FETCH 70MB/WRITE 60MB vs 33/32.7 ideal = 65MB scratch round-trip
//  per dispatch, in-loop). Quartering drops demand to ~106 < the 128-reg
//  allocator target -> spill gone even paired. Cost: 2 extra online-softmax
//  updates per 128-key chunk (~260 VALU ops; VALUBusy at 30% has headroom).
// R12 recap: MI grown to CM (FFN-down 1 block/CU -> 4/CU) = -345us. attn's
//  77->99us rise is uniform -22% across all counters = sustained-clock
//  throttle from denser GEMM schedule, not a cache effect.
// History: R0 2844 -> R5 2491 (spill dead) -> R6 2371 -> R8 2349 ->
//  R11 2339 (paired attn) -> R12 1994 (MI=CM).
// B=64 S=512 D=512 H=8 DK=64 L=4 DFF=2048 NSK=300 FC1=512 FC2=256.
// ENVELOPE RULE: kernels use <=256 threads and <=32KB static LDS; no
// dynamic-LDS opt-in, no hipFuncSetAttribute.

typedef unsigned short u16;
typedef __attribute__((ext_vector_type(8))) short short8;   // 8 bf16 - 16x16x32 A/B frag
typedef __attribute__((ext_vector_type(4))) short short4v;  // 4 bf16 - 16x16x16 A/B frag
typedef __attribute__((ext_vector_type(4))) float f32x4;    // MFMA C/D frag

#define DEV __device__ __forceinline__

DEV float bf2f(u16 u) { return __uint_as_float(((unsigned int)u) << 16); }
DEV u16 f2bf(float f) {
  unsigned int u = __float_as_uint(f);
  u += 0x7FFFu + ((u >> 16) & 1u);
  return (u16)(u >> 16);
}

// v_cvt_pk_bf16_f32: low16 = bf16(lo), high16 = bf16(hi); RNE — bit-identical
// to f2bf for finite inputs.
DEV unsigned cvt_pk_bf16(float lo, float hi) {
  unsigned r;
  asm("v_cvt_pk_bf16_f32 %0, %1, %2" : "=v"(r) : "v"(lo), "v"(hi));
  return r;
}

template <bool V> struct BoolC { static constexpr bool value = V; };

DEV void gl2l16(const void* g, void* l) {
  __builtin_amdgcn_global_load_lds(
      (__attribute__((address_space(1))) void*)g,
      (__attribute__((address_space(3))) void*)l, 16, 0, 0);
}

#define MFMA16(a, b, c) __builtin_amdgcn_mfma_f32_16x16x32_bf16(a, b, c, 0, 0, 0)

// 16x16x16 bf16 MFMA (K=16: k = (lane>>4)*4+j — matches C-layout rows)
#if defined(__has_builtin)
#if __has_builtin(__builtin_amdgcn_mfma_f32_16x16x16bf16_1k)
#define MFMA16X16(a, b, c) __builtin_amdgcn_mfma_f32_16x16x16bf16_1k(a, b, c, 0, 0, 0)
#elif __has_builtin(__builtin_amdgcn_mfma_f32_16x16x16_bf16)
#define MFMA16X16(a, b, c) __builtin_amdgcn_mfma_f32_16x16x16_bf16(a, b, c, 0, 0, 0)
#endif
#endif
#ifndef MFMA16X16
DEV f32x4 mfma_16x16x16_bf16_asm(short4v a, short4v b, f32x4 c) {
  f32x4 d;
  asm("v_mfma_f32_16x16x16_bf16 %0, %1, %2, %3\n\ts_nop 7\n\ts_nop 3"
      : "=&v"(d) : "v"(a), "v"(b), "v"(c));
  return d;
}
#define MFMA16X16(a, b, c) mfma_16x16x16_bf16_asm(a, b, c)
#endif

// ---------------------------------------------------------------------------
// Weight convert+transpose: fp32 [K,N] (batched over z) -> bf16 [N,K]
// ---------------------------------------------------------------------------
__global__ __launch_bounds__(256) void transpose_cvt(
    const float* __restrict__ src, u16* __restrict__ dst, int K, int N)
{
  src += (size_t)blockIdx.z * K * N;
  dst += (size_t)blockIdx.z * K * N;
  __shared__ alignas(16) float tile[32][33];
  const int tx = threadIdx.x & 31, ty = threadIdx.x >> 5;
  const int n0 = blockIdx.x * 32, k0 = blockIdx.y * 32;
#pragma unroll
  for (int i = 0; i < 4; ++i) {
    int k = k0 + ty + i * 8, n = n0 + tx;
    if (k < K && n < N) tile[ty + i * 8][tx] = src[(size_t)k * N + n];
  }
  __syncthreads();
#pragma unroll
  for (int i = 0; i < 4; ++i) {
    int n = n0 + ty + i * 8, k = k0 + tx;
    if (n < N && k < K) dst[(size_t)n * K + k] = f2bf(tile[tx][ty + i * 8]);
  }
}

// ---------------------------------------------------------------------------
// Embedding: x = q_emb[q_data] + pe[s]; y = qa_emb[target] + q_emb[q_data] + pe[s]
// ---------------------------------------------------------------------------
__global__ __launch_bounds__(256) void embed_k(
    const int* __restrict__ qd, const int* __restrict__ tg,
    const float* __restrict__ pe, const float* __restrict__ qe, const float* __restrict__ qa,
    u16* __restrict__ x_b, u16* __restrict__ y_b)
{
  const int row = blockIdx.x * 4 + (threadIdx.x >> 6);
  const int lane = threadIdx.x & 63;
  const int s = row & 511;
  const int idx = qd[row];
  const int tt = tg[row];
  const int c = lane * 8;
  const float* q = qe + (size_t)idx * 512 + c;
  const float* p = pe + (size_t)s * 512 + c;
  const float* a = qa + (size_t)tt * 512 + c;
  float4 q0 = *(const float4*)q, q1 = *(const float4*)(q + 4);
  float4 p0 = *(const float4*)p, p1 = *(const float4*)(p + 4);
  float4 a0 = *(const float4*)a, a1 = *(const float4*)(a + 4);
  float qv[8] = {q0.x, q0.y, q0.z, q0.w, q1.x, q1.y, q1.z, q1.w};
  float pv[8] = {p0.x, p0.y, p0.z, p0.w, p1.x, p1.y, p1.z, p1.w};
  float av[8] = {a0.x, a0.y, a0.z, a0.w, a1.x, a1.y, a1.z, a1.w};
  short8 ox, oy;
#pragma unroll
  for (int i = 0; i < 8; ++i) {
    ox[i] = (short)f2bf(qv[i] + pv[i]);
    oy[i] = (short)f2bf(qv[i] + pv[i] + av[i]);
  }
  size_t base = (size_t)row * 512 + c;
  *(short8*)(x_b + base) = ox;
  *(short8*)(y_b + base) = oy;
}

// ---------------------------------------------------------------------------
// bf16 GEMM core: C[M,N] = act((A[M,K] @ Bt[N,K]^T + bias) * oscale)
// 128x128 tile, BK=64, 256 thr. Staging: 16 sub-tiles of (8 rows x 64 cols),
// wave w owns tb = w*4+i; slot swizzle ps = (lane&7)^(r&7) with r&7 == lane>>3
// (uniform across tb). Per K-step: 8 gl2l16, one barrier pair, 2x16 MFMA.
// OUTM: 0 = bf16 row-major, 1 = f32 row-major, 2 = bf16 scatter vT[b,h,dk,s].
// ---------------------------------------------------------------------------
template <int ACT, int OUTM>
DEV void gemm_core(u16* As, u16* Bs,
                   const u16* __restrict__ A, const u16* __restrict__ Bt,
                   const float* __restrict__ bias, void* __restrict__ Cv,
                   int M, int N, int K, int bx, int by, float oscale)
{
  const int lane = threadIdx.x & 63;
  const int w = threadIdx.x >> 6;
  const int wm = w >> 1, wn = w & 1;
  const int m0 = by * 128, n0 = bx * 128;

  // staging addresses: rows rs_+8i (i<4), slot ps_ (8 u16 = 16B)
  const int rs_ = w * 32 + (lane >> 3);
  const int ps_ = (lane & 7) ^ (lane >> 3);   // r&7 == lane>>3 for all tb
  const u16* pa = A + (size_t)(m0 + rs_) * K + ps_ * 8;
  const u16* pb[4];
#pragma unroll
  for (int i = 0; i < 4; ++i) {
    int rb = n0 + rs_ + i * 8;
    rb = (rb < N) ? rb : (N - 1);
    pb[i] = Bt + (size_t)rb * K + ps_ * 8;
  }
  u16* la = As + (w * 4 * 64 + lane) * 8;
  u16* lb = Bs + (w * 4 * 64 + lane) * 8;

  f32x4 acc[4][4];
#pragma unroll
  for (int a_ = 0; a_ < 4; ++a_)
#pragma unroll
    for (int b_ = 0; b_ < 4; ++b_)
#pragma unroll
      for (int i = 0; i < 4; ++i) acc[a_][b_][i] = 0.f;

  for (int k0 = 0; k0 < K; k0 += 64) {
#pragma unroll
    for (int i = 0; i < 4; ++i) gl2l16(pa + (size_t)i * 8 * K, la + i * 64 * 8);
#pragma unroll
    for (int i = 0; i < 4; ++i) gl2l16(pb[i], lb + i * 64 * 8);
    pa += 64;
#pragma unroll
    for (int i = 0; i < 4; ++i) pb[i] += 64;
    __syncthreads();
#pragma unroll
    for (int ks = 0; ks < 2; ++ks) {
      short8 af[4], bf[4];
#pragma unroll
      for (int i = 0; i < 4; ++i) {
        int r = wm * 64 + i * 16 + (lane & 15);
        af[i] = *(const short8*)(As + (r * 8 + ((ks * 4 + (lane >> 4)) ^ (r & 7))) * 8);
        int r2 = wn * 64 + i * 16 + (lane & 15);
        bf[i] = *(const short8*)(Bs + (r2 * 8 + ((ks * 4 + (lane >> 4)) ^ (r2 & 7))) * 8);
      }
#pragma unroll
      for (int mt = 0; mt < 4; ++mt)
#pragma unroll
        for (int nt = 0; nt < 4; ++nt)
          acc[mt][nt] = MFMA16(af[mt], bf[nt], acc[mt][nt]);
    }
    __syncthreads();
  }

  const int row0 = m0 + wm * 64, col0 = n0 + wn * 64;
#pragma unroll
  for (int mt = 0; mt < 4; ++mt) {
#pragma unroll
    for (int nt = 0; nt < 4; ++nt) {
      int c = col0 + nt * 16 + (lane & 15);
      int r = row0 + mt * 16 + (lane >> 4) * 4;
      if (c < N) {
        float bz = bias[c];
#pragma unroll
        for (int i = 0; i < 4; ++i) {
          float v = (acc[mt][nt][i] + bz) * oscale;
          if (ACT == 1) v = fmaxf(v, 0.f);
          int m = r + i;
          if (OUTM == 0) {
            ((u16*)Cv)[(size_t)m * N + c] = f2bf(v);
          } else if (OUTM == 1) {
            ((float*)Cv)[(size_t)m * N + c] = v;
          } else {  // vT[b][h][dk][s]: m=(b,s) local, c=(h,dk)
            size_t idx = ((((size_t)(m >> 9)) * 8 + (c >> 6)) * 64 + (c & 63)) * 512 + (m & 511);
            ((u16*)Cv)[idx] = f2bf(v);
          }
        }
      }
    }
  }
}

template <int ACT, int OUTM>
__global__ __launch_bounds__(256) void gemm_bt(
    const u16* __restrict__ A, const u16* __restrict__ Bt,
    const float* __restrict__ bias, void* __restrict__ Cv,
    int M, int N, int K)
{
  __shared__ alignas(16) u16 As[128 * 64];
  __shared__ alignas(16) u16 Bs[128 * 64];
  gemm_core<ACT, OUTM>(As, Bs, A, Bt, bias, Cv, M, N, K, blockIdx.x, blockIdx.y, 1.f);
}

// fused K/V projection: z=0 -> x@Wk (scaled by os0) -> s_kq (OUTM 0);
//                       z=1 -> y@Wv -> vT (OUTM 2)
__global__ __launch_bounds__(256) void gemm_kv(
    const u16* __restrict__ A0, const u16* __restrict__ Bt0,
    const float* __restrict__ b0, void* __restrict__ C0,
    const u16* __restrict__ A1, const u16* __restrict__ Bt1,
    const float* __restrict__ b1, void* __restrict__ C1,
    int M, int N, int K, float os0)
{
  __shared__ alignas(16) u16 As[128 * 64];
  __shared__ alignas(16) u16 Bs[128 * 64];
  if (blockIdx.z == 0)
    gemm_core<0, 0>(As, Bs, A0, Bt0, b0, C0, M, N, K, blockIdx.x, blockIdx.y, os0);
  else
    gemm_core<0, 2>(As, Bs, A1, Bt1, b1, C1, M, N, K, blockIdx.x, blockIdx.y, 1.f);
}

// ---------------------------------------------------------------------------
// Flash attention, transposed scores. grid (pair=2, h=8, b=NB), 256 thr.
// Each block processes TWO q-tiles {3-p, p} sequentially -> uniform 5
// chunks/block, 1024 blocks = one residency round (4/CU), zero imbalance.
// "#pragma unroll 1" on the pi loop (R11).
// R13: online softmax over 32-key QUARTERS (sc[2][2]/pf[2][2]) — cuts the
// spill the paired body reintroduced (R11: FETCH 70/WRITE 60 MB vs 33/32.7
// ideal). Demand ~106 regs < 128 target -> scratch-free.
// Unswizzle: l = x + 2*(y+8*z); bh = (l&7)+8*(l>>4), p = (l>>3)&1 -> both
// blocks of a (b,h) share l%8 (same XCD under round-robin) for K/V L2 hits.
// Wave w owns q-cols [w*32, w*32+32). S^T = K Q^T via 16x16x32 (keys=M, q=N);
// C-layout: q = lane&15 (col), key = (lane>>4)*4+i (row). P^T stays in regs as
// 16x16x16 B-frags; O^T = V^T P^T with dk as M.
// Q/K arrive PRE-SCALED by sqrt(0.125*log2e) (gemm_kv z=0 epilogue), so QK^T
// emerges directly in the exp2 domain — no per-element scale pass (R7).
// Softmax: masked = -1e30, plain-subtract exp2; P->bf16 via cvt_pk (R6).
// Epilogue bounces O^T through wave-private LDS (XOR swizzle) for coalesced
// short8 stores. LDS 32KB.
// ---------------------------------------------------------------------------
__global__ __launch_bounds__(256, 2) void attn_k(
    const u16* __restrict__ kq, const u16* __restrict__ vT, u16* __restrict__ o)
{
  __shared__ alignas(16) u16 Ks[128 * 64];
  __shared__ alignas(16) u16 Vs[64 * 128];
  const int l = blockIdx.x + 2 * (blockIdx.y + 8 * blockIdx.z);
  const int bh = (l & 7) + 8 * (l >> 4);
  const int pr = (l >> 3) & 1;
  const int h = bh & 7, b = bh >> 3;
  const int lane = threadIdx.x & 63;
  const int w = threadIdx.x >> 6;
  const size_t kq_base = ((size_t)b * 512) * 512 + h * 64;

#pragma unroll 1
  for (int pi = 0; pi < 2; ++pi) {
    const int t = pi ? pr : 3 - pr;   // pr=0 -> {3,0}; pr=1 -> {2,1}: 5 chunks
    const int q0 = t * 128;

    // stage Q tile [128 x 64] into Ks (wave-private region), pull B-frags
#pragma unroll
    for (int i = 0; i < 4; ++i) {
      int tb = w * 4 + i;
      int r = tb * 8 + (lane >> 3);
      int ps = (lane & 7) ^ (r & 7);
      gl2l16(kq + kq_base + (size_t)(q0 + r) * 512 + ps * 8, Ks + (tb * 64 + lane) * 8);
    }
    __syncthreads();
    short8 qf[2][2];
#pragma unroll
    for (int nt = 0; nt < 2; ++nt)
#pragma unroll
      for (int ks = 0; ks < 2; ++ks) {
        int q = w * 32 + nt * 16 + (lane & 15);
        int ch = ks * 4 + (lane >> 4);
        qf[nt][ks] = *(const short8*)(Ks + (q * 8 + (ch ^ (q & 7))) * 8);
      }

    f32x4 of[4][2];  // [dk-tile][q-tile]; col=q=lane&15, row=dk=(lane>>4)*4+i
    float m_st[2] = {-1e30f, -1e30f}, l_st[2] = {0.f, 0.f};  // exp2 domain
#pragma unroll
    for (int d = 0; d < 4; ++d)
#pragma unroll
      for (int nt = 0; nt < 2; ++nt)
#pragma unroll
        for (int i = 0; i < 4; ++i) of[d][nt][i] = 0.f;

    auto chunk = [&](int j, auto diagc) {
      constexpr bool DIAG = decltype(diagc)::value;
      // diagonal chunk: wave w needs keys < w*32+32 -> key-tiles mt < 2w+2
      const int MT = DIAG ? (2 * w + 2) : 8;
      const int k0 = j * 128;

      // four 32-key quarters, each with its own online-softmax update:
      // sc/pf live range = 24 regs (was 48 at halves) -> paired body fits
      // the 128-reg target scratch-free (R13).
#pragma unroll
      for (int hh = 0; hh < 4; ++hh) {
        if (!DIAG || MT > hh * 2) {
          const int MTl = DIAG ? ((MT - hh * 2 < 2) ? MT - hh * 2 : 2) : 2;

          // S^T = K Q^T (this quarter's 2 key-tiles) — already exp2-scaled
          f32x4 sc[2][2];
          __builtin_amdgcn_s_setprio(1);
#pragma unroll
          for (int mt = 0; mt < 2; ++mt)
            if (!DIAG || mt < MTl) {
#pragma unroll
              for (int nt = 0; nt < 2; ++nt)
#pragma unroll
                for (int i = 0; i < 4; ++i) sc[mt][nt][i] = 0.f;
#pragma unroll
              for (int ks = 0; ks < 2; ++ks) {
                int key = (hh * 2 + mt) * 16 + (lane & 15);
                int ch = ks * 4 + (lane >> 4);
                short8 kf = *(const short8*)(Ks + (key * 8 + (ch ^ (key & 7))) * 8);
                sc[mt][0] = MFMA16(kf, qf[0][ks], sc[mt][0]);
                sc[mt][1] = MFMA16(kf, qf[1][ks], sc[mt][1]);
              }
            }
          __builtin_amdgcn_s_setprio(0);

          // strict causal mask (diag chunk only; no scale pass needed)
          if (DIAG) {
#pragma unroll
            for (int mt = 0; mt < 2; ++mt)
              if (mt < MTl) {
#pragma unroll
                for (int nt = 0; nt < 2; ++nt) {
                  int qg = q0 + w * 32 + nt * 16 + (lane & 15);
#pragma unroll
                  for (int i = 0; i < 4; ++i) {
                    int kg = k0 + (hh * 2 + mt) * 16 + (lane >> 4) * 4 + i;
                    if (kg >= qg) sc[mt][nt][i] = -1e30f;
                  }
                }
              }
          }

          // online softmax (exp2 domain): per-lane scalar state (q=lane&15)
          short4v pf[2][2];
#pragma unroll
          for (int nt = 0; nt < 2; ++nt) {
            float mx = -1e30f;
#pragma unroll
            for (int mt = 0; mt < 2; ++mt)
              if (!DIAG || mt < MTl) {
#pragma unroll
                for (int i = 0; i < 4; ++i) mx = fmaxf(mx, sc[mt][nt][i]);
              }
            mx = fmaxf(mx, __shfl_xor(mx, 16));
            mx = fmaxf(mx, __shfl_xor(mx, 32));
            float mo = m_st[nt];
            float mn = fmaxf(mo, mx);
            float al = exp2f(mo - mn);
            float rs = 0.f;
#pragma unroll
            for (int mt = 0; mt < 2; ++mt)
              if (!DIAG || mt < MTl) {
#pragma unroll
                for (int i = 0; i < 4; ++i) {
                  float pv = exp2f(sc[mt][nt][i] - mn);
                  sc[mt][nt][i] = pv;
                  rs += pv;
                }
              }
            rs += __shfl_xor(rs, 16);
            rs += __shfl_xor(rs, 32);
            m_st[nt] = mn;
            l_st[nt] = l_st[nt] * al + rs;
#pragma unroll
            for (int d = 0; d < 4; ++d)
#pragma unroll
              for (int i = 0; i < 4; ++i) of[d][nt][i] *= al;
            // pack P^T to bf16 16x16x16 B-frags via cvt_pk
#pragma unroll
            for (int mt = 0; mt < 2; ++mt)
              if (!DIAG || mt < MTl) {
                union { unsigned u[2]; short4v s; } cv;
                cv.u[0] = cvt_pk_bf16(sc[mt][nt][0], sc[mt][nt][1]);
                cv.u[1] = cvt_pk_bf16(sc[mt][nt][2], sc[mt][nt][3]);
                pf[mt][nt] = cv.s;
              }
          }

          // O^T += V^T P^T  (A = V^T frag: m=dk, k=key; 16x16x16)
          __builtin_amdgcn_s_setprio(1);
#pragma unroll
          for (int mt = 0; mt < 2; ++mt)
            if (!DIAG || mt < MTl) {
              int key4 = (hh * 2 + mt) * 16 + (lane >> 4) * 4;
#pragma unroll
              for (int d = 0; d < 4; ++d) {
                int dk = d * 16 + (lane & 15);
                short4v vf = *(const short4v*)(
                    Vs + (dk * 16 + ((key4 >> 3) ^ (dk & 15))) * 8 + (key4 & 7));
                of[d][0] = MFMA16X16(vf, pf[mt][0], of[d][0]);
                of[d][1] = MFMA16X16(vf, pf[mt][1], of[d][1]);
              }
            }
          __builtin_amdgcn_s_setprio(0);
        }
      }
    };

#pragma unroll 1
    for (int j = 0; j <= t; ++j) {
      const int k0 = j * 128;
      __syncthreads();  // all waves done reading prior chunk's Ks/Vs
#pragma unroll
      for (int i = 0; i < 4; ++i) {  // K chunk [128 keys x 64]
        int tb = w * 4 + i;
        int r = tb * 8 + (lane >> 3);
        int ps = (lane & 7) ^ (r & 7);
        gl2l16(kq + kq_base + (size_t)(k0 + r) * 512 + ps * 8, Ks + (tb * 64 + lane) * 8);
      }
#pragma unroll
      for (int i = 0; i < 4; ++i) {  // V^T chunk [64 dk x 128 keys]
        int tb = w * 4 + i;
        int r = tb * 4 + (lane >> 4);
        int ps = (lane & 15) ^ (r & 15);
        gl2l16(vT + ((size_t)((b * 8 + h) * 64 + r)) * 512 + k0 + ps * 8, Vs + (tb * 64 + lane) * 8);
      }
      __syncthreads();
      if (j < t) {
        chunk(j, BoolC<false>{});
      } else {
        chunk(j, BoolC<true>{});
      }
    }

    // epilogue: O^T -> wave-private LDS (swizzled) -> coalesced stores
    __syncthreads();  // all waves done reading Ks/Vs
    u16* Ws = Ks + w * 2048;  // 32 q-rows x 64 dk per wave
#pragma unroll
    for (int nt = 0; nt < 2; ++nt) {
      int qrow = nt * 16 + (lane & 15);
      int qg = q0 + w * 32 + qrow;
      float li = l_st[nt];
      float inv = (qg > 0 && li > 0.f) ? (1.f / li) : 0.f;
      int sw = (qrow & 7) * 8;
#pragma unroll
      for (int d = 0; d < 4; ++d)
#pragma unroll
        for (int i = 0; i < 4; ++i) {
          int dk = d * 16 + (lane >> 4) * 4 + i;
          Ws[qrow * 64 + (dk ^ sw)] = f2bf(of[d][nt][i] * inv);
        }
    }
    // wave-private: no barrier needed (lgkmcnt ordering within wave)
#pragma unroll
    for (int p = 0; p < 4; ++p) {
      int qrow = p * 8 + (lane >> 3);
      int c = lane & 7;
      short8 vv = *(const short8*)(Ws + qrow * 64 + ((c ^ (qrow & 7)) * 8));
      int qg = q0 + w * 32 + qrow;
      *(short8*)(o + ((size_t)b * 512 + qg) * 512 + h * 64 + c * 8) = vv;
    }
  }
}

// ---------------------------------------------------------------------------
// LayerNorm(x + res); one wave per 512-col row; in-place safe.
// ---------------------------------------------------------------------------
__global__ __launch_bounds__(256) void ln_res(
    const u16* __restrict__ xin, const u16* __restrict__ res,
    const float* __restrict__ gam, const float* __restrict__ bet, u16* __restrict__ xout)
{
  const int row = blockIdx.x * 4 + (threadIdx.x >> 6);
  const int lane = threadIdx.x & 63;
  const size_t base = (size_t)row * 512 + lane * 8;
  short8 xv = *(const short8*)(xin + base);
  short8 rv = *(const short8*)(res + base);
  float v[8];
  float s = 0.f, s2 = 0.f;
#pragma unroll
  for (int i = 0; i < 8; ++i) {
    float a = bf2f((u16)xv[i]) + bf2f((u16)rv[i]);
    v[i] = a;
    s += a;
    s2 += a * a;
  }
#pragma unroll
  for (int d = 1; d < 64; d <<= 1) {
    s += __shfl_xor(s, d);
    s2 += __shfl_xor(s2, d);
  }
  float mean = s * (1.f / 512.f);
  float var = s2 * (1.f / 512.f) - mean * mean;
  float rstd = rsqrtf(var + 1e-5f);
  const int c = lane * 8;
  short8 ov;
#pragma unroll
  for (int i = 0; i < 8; ++i) {
    float ot = (v[i] - mean) * rstd * gam[c + i] + bet[c + i];
    ov[i] = (short)f2bf(ot);
  }
  *(short8*)(xout + base) = ov;
}

// ---------------------------------------------------------------------------
// concat [x, q_emb[q_data]] -> cat [rows,1024] bf16
// ---------------------------------------------------------------------------
__global__ __launch_bounds__(256) void concat2_k(
    const u16* __restrict__ x, const int* __restrict__ qd,
    const float* __restrict__ qemb, u16* __restrict__ cat)
{
  const int row = blockIdx.x * 4 + (threadIdx.x >> 6);
  const int lane = threadIdx.x & 63;
  *(short8*)(cat + (size_t)row * 1024 + lane * 8) =
      *(const short8*)(x + (size_t)row * 512 + lane * 8);
  const int idx = qd[row];
  const float* q = qemb + (size_t)idx * 512 + lane * 8;
  float4 q0 = *(const float4*)q, q1 = *(const float4*)(q + 4);
  float qv[8] = {q0.x, q0.y, q0.z, q0.w, q1.x, q1.y, q1.z, q1.w};
  short8 ov;
#pragma unroll
  for (int i = 0; i < 8; ++i) ov[i] = (short)f2bf(qv[i]);
  *(short8*)(cat + (size_t)row * 1024 + 512 + lane * 8) = ov;
}

// ---------------------------------------------------------------------------
extern "C" void kernel_launch(void* const* d_in, const int* in_sizes, int n_in,
                              void* d_out, int out_size, void* d_ws, size_t ws_size,
                              hipStream_t stream)
{
  const int* qd = (const int*)d_in[0];
  const int* tg = (const int*)d_in[1];
  const float* pe = (const float*)d_in[2];
  const float* qemb = (const float*)d_in[3];
  const float* qa = (const float*)d_in[4];
  const float* Wk = (const float*)d_in[5];
  const float* bk = (const float*)d_in[6];
  const float* Wv = (const float*)d_in[7];
  const float* bv = (const float*)d_in[8];
  const float* Wo = (const float*)d_in[9];
  const float* bo = (const float*)d_in[10];
  const float* g1 = (const float*)d_in[11];
  const float* be1 = (const float*)d_in[12];
  const float* W1 = (const float*)d_in[13];
  const float* b1 = (const float*)d_in[14];
  const float* W2 = (const float*)d_in[15];
  const float* b2 = (const float*)d_in[16];
  const float* g2 = (const float*)d_in[17];
  const float* be2 = (const float*)d_in[18];
  const float* Wo1 = (const float*)d_in[19];
  const float* bo1 = (const float*)d_in[20];
  const float* Wo2 = (const float*)d_in[21];
  const float* bo2 = (const float*)d_in[22];
  const float* Wo3 = (const float*)d_in[23];
  const float* bo3 = (const float*)d_in[24];
  float* out = (float*)d_out;

  const int BS = 64 * 512;  // 32768
  const float SQS = 0.42466089f;  // sqrt(0.125 * log2(e)) — QK pre-scale

  // batch-group chunking from ws_size (constant per process -> graph-safe)
  const size_t WU16 = 12266496ull;
  auto need2 = [&](int nc, size_t st) -> size_t {
    size_t CMr = (size_t)BS / nc;
    return 2ull * (WU16 + 2ull * BS * 512 + 3ull * CMr * 512 + st * 2048);
  };
  int NC = 1;
  if (ws_size < need2(1, 8192)) NC = 4;
  if (NC == 4 && ws_size < need2(4, 8192)) NC = 8;
  const int CM = BS / NC;
  int MI = CM < 8192 ? CM : 8192;
  // R12: grow the FFN chunk while workspace allows — MI=8192 gives the
  // FFN-down GEMM a 256-block grid (1 block/CU: barrier drain fully exposed,
  // no cross-block overlap). MI=CM -> 1024 blocks = 4/CU. Deterministic in
  // ws_size -> graph-safe; no-op if workspace is tight.
  while (MI < CM && ws_size >= need2(NC, (size_t)MI * 2)) MI *= 2;

  u16* p = (u16*)d_ws;
  u16* wkT = p;  p += 4 * 512 * 512;
  u16* wvT = p;  p += 4 * 512 * 512;
  u16* woT = p;  p += 4 * 512 * 512;
  u16* w1T = p;  p += 4 * 512 * 2048;
  u16* w2T = p;  p += 4 * 2048 * 512;
  u16* wo1T = p; p += 1024 * 512;
  u16* wo2T = p; p += 512 * 256;
  u16* wo3T = p; p += 300 * 256;
  u16* x_b = p;  p += (size_t)BS * 512;
  u16* y_b = p;  p += (size_t)BS * 512;
  u16* s_kq = p; p += (size_t)CM * 512;   // also head-cat first half
  u16* s_vT = p; p += (size_t)CM * 512;   // adjacent: cat = s_kq[CM x 1024]
  u16* s_o = p;  p += (size_t)CM * 512;
  u16* s_t = p;                            // MI x 2048 FFN / head scratch

  transpose_cvt<<<dim3(16, 16, 4), 256, 0, stream>>>(Wk, wkT, 512, 512);
  transpose_cvt<<<dim3(16, 16, 4), 256, 0, stream>>>(Wv, wvT, 512, 512);
  transpose_cvt<<<dim3(16, 16, 4), 256, 0, stream>>>(Wo, woT, 512, 512);
  transpose_cvt<<<dim3(64, 16, 4), 256, 0, stream>>>(W1, w1T, 512, 2048);
  transpose_cvt<<<dim3(16, 64, 4), 256, 0, stream>>>(W2, w2T, 2048, 512);
  transpose_cvt<<<dim3(16, 32, 1), 256, 0, stream>>>(Wo1, wo1T, 1024, 512);
  transpose_cvt<<<dim3(8, 16, 1), 256, 0, stream>>>(Wo2, wo2T, 512, 256);
  transpose_cvt<<<dim3(10, 8, 1), 256, 0, stream>>>(Wo3, wo3T, 256, 300);

  embed_k<<<BS / 4, 256, 0, stream>>>(qd, tg, pe, qemb, qa, x_b, y_b);

  for (int l = 0; l < 4; ++l) {
    const size_t lw = (size_t)l * 512 * 512;
    for (int cc = 0; cc < NC; ++cc) {
      const size_t R = (size_t)cc * CM;
      // fused q/k + v projections (kq_same=1); q/k pre-scaled for exp2 domain
      gemm_kv<<<dim3(4, CM / 128, 2), 256, 0, stream>>>(
          x_b + R * 512, wkT + lw, bk + l * 512, s_kq,
          y_b + R * 512, wvT + lw, bv + l * 512, s_vT, CM, 512, 512, SQS);
      attn_k<<<dim3(2, 8, CM / 512), 256, 0, stream>>>(s_kq, s_vT, s_o);
      gemm_bt<0, 0><<<dim3(4, CM / 128), 256, 0, stream>>>(
          s_o, woT + lw, bo + l * 512, s_kq, CM, 512, 512);
      ln_res<<<CM / 4, 256, 0, stream>>>(
          x_b + R * 512, s_kq, g1 + l * 512, be1 + l * 512, x_b + R * 512);
      for (int mc = 0; mc < CM; mc += MI) {
        gemm_bt<1, 0><<<dim3(16, MI / 128), 256, 0, stream>>>(
            x_b + (R + mc) * 512, w1T + (size_t)l * 512 * 2048, b1 + l * 2048,
            s_t, MI, 2048, 512);
        gemm_bt<0, 0><<<dim3(4, MI / 128), 256, 0, stream>>>(
            s_t, w2T + (size_t)l * 2048 * 512, b2 + l * 512,
            s_vT + (size_t)mc * 512, MI, 512, 2048);
      }
      ln_res<<<CM / 4, 256, 0, stream>>>(
          x_b + R * 512, s_vT, g2 + l * 512, be2 + l * 512, x_b + R * 512);
    }
  }

  for (int cc = 0; cc < NC; ++cc) {
    const size_t R = (size_t)cc * CM;
    concat2_k<<<CM / 4, 256, 0, stream>>>(x_b + R * 512, qd + R, qemb, s_kq);
    gemm_bt<1, 0><<<dim3(4, CM / 128), 256, 0, stream>>>(
        s_kq, wo1T, bo1, s_o, CM, 512, 1024);
    gemm_bt<1, 0><<<dim3(2, CM / 128), 256, 0, stream>>>(
        s_o, wo2T, bo2, s_t, CM, 256, 512);
    gemm_bt<0, 1><<<dim3(3, CM / 128), 256, 0, stream>>>(
        s_t, wo3T, bo3, out + R * 300, CM, 300, 256);
  }
}

// Round 14
// 1766.251 us; speedup vs baseline: 1.4960x; 1.0831x over previous
//
#include <hip/hip_runtime.h>

// simpleKT forward on gfx950: bf16 MFMA GEMMs + flash-style causal attention
// (transposed-scores formulation; P stays in registers; coalesced O epilogue;
//  XCD-aware block swizzle for K/V L2 locality).
// R14: XCD-aware swizzle for GEMM grids (T1). gemm_kv PMC: FETCH 133MB vs
//  68MB unique inputs = 2x over-fetch. Cause: the 4 (FFN-up: 16) column-
//  blocks sharing one A-row-panel are CONSECUTIVE linear block ids ->
//  round-robin dispatch scatters them over 4 XCDs; per-XCD L2s re-fetch the
//  panel (L3 absorbs only half). Remap (bijective, gy%8==0): r=lid>>3,
//  bx'=r%gx, by'=(lid&7)+8*(r/gx) -> panel-sharing blocks all on one XCD.
// R13 recap: 32-key quarters killed the attn pairing spill; attn out of
//  top-5. History: R0 2844 -> R5 2491 -> R8 2349 -> R11 2339 -> R12 1994
//  (MI=CM) -> R13 1913.
// B=64 S=512 D=512 H=8 DK=64 L=4 DFF=2048 NSK=300 FC1=512 FC2=256.
// ENVELOPE RULE: kernels use <=256 threads and <=32KB static LDS; no
// dynamic-LDS opt-in, no hipFuncSetAttribute.

typedef unsigned short u16;
typedef __attribute__((ext_vector_type(8))) short short8;   // 8 bf16 - 16x16x32 A/B frag
typedef __attribute__((ext_vector_type(4))) short short4v;  // 4 bf16 - 16x16x16 A/B frag
typedef __attribute__((ext_vector_type(4))) float f32x4;    // MFMA C/D frag

#define DEV __device__ __forceinline__

DEV float bf2f(u16 u) { return __uint_as_float(((unsigned int)u) << 16); }
DEV u16 f2bf(float f) {
  unsigned int u = __float_as_uint(f);
  u += 0x7FFFu + ((u >> 16) & 1u);
  return (u16)(u >> 16);
}

// v_cvt_pk_bf16_f32: low16 = bf16(lo), high16 = bf16(hi); RNE — bit-identical
// to f2bf for finite inputs.
DEV unsigned cvt_pk_bf16(float lo, float hi) {
  unsigned r;
  asm("v_cvt_pk_bf16_f32 %0, %1, %2" : "=v"(r) : "v"(lo), "v"(hi));
  return r;
}

template <bool V> struct BoolC { static constexpr bool value = V; };

DEV void gl2l16(const void* g, void* l) {
  __builtin_amdgcn_global_load_lds(
      (__attribute__((address_space(1))) void*)g,
      (__attribute__((address_space(3))) void*)l, 16, 0, 0);
}

// XCD-aware grid swizzle (T1): blocks sharing an A-row-panel (same by, all
// bx) get equal lid%8 -> same XCD under round-robin dispatch -> the panel is
// fetched into ONE L2 and reused. Bijective when gy % 8 == 0.
DEV void xcd_swz(int gx, int gy, int& bx, int& by) {
  if ((gy & 7) == 0) {
    int lid = bx + gx * by;
    int r = lid >> 3;
    int q = r / gx;
    bx = r - q * gx;
    by = (lid & 7) + 8 * q;
  }
}

#define MFMA16(a, b, c) __builtin_amdgcn_mfma_f32_16x16x32_bf16(a, b, c, 0, 0, 0)

// 16x16x16 bf16 MFMA (K=16: k = (lane>>4)*4+j — matches C-layout rows)
#if defined(__has_builtin)
#if __has_builtin(__builtin_amdgcn_mfma_f32_16x16x16bf16_1k)
#define MFMA16X16(a, b, c) __builtin_amdgcn_mfma_f32_16x16x16bf16_1k(a, b, c, 0, 0, 0)
#elif __has_builtin(__builtin_amdgcn_mfma_f32_16x16x16_bf16)
#define MFMA16X16(a, b, c) __builtin_amdgcn_mfma_f32_16x16x16_bf16(a, b, c, 0, 0, 0)
#endif
#endif
#ifndef MFMA16X16
DEV f32x4 mfma_16x16x16_bf16_asm(short4v a, short4v b, f32x4 c) {
  f32x4 d;
  asm("v_mfma_f32_16x16x16_bf16 %0, %1, %2, %3\n\ts_nop 7\n\ts_nop 3"
      : "=&v"(d) : "v"(a), "v"(b), "v"(c));
  return d;
}
#define MFMA16X16(a, b, c) mfma_16x16x16_bf16_asm(a, b, c)
#endif

// ---------------------------------------------------------------------------
// Weight convert+transpose: fp32 [K,N] (batched over z) -> bf16 [N,K]
// ---------------------------------------------------------------------------
__global__ __launch_bounds__(256) void transpose_cvt(
    const float* __restrict__ src, u16* __restrict__ dst, int K, int N)
{
  src += (size_t)blockIdx.z * K * N;
  dst += (size_t)blockIdx.z * K * N;
  __shared__ alignas(16) float tile[32][33];
  const int tx = threadIdx.x & 31, ty = threadIdx.x >> 5;
  const int n0 = blockIdx.x * 32, k0 = blockIdx.y * 32;
#pragma unroll
  for (int i = 0; i < 4; ++i) {
    int k = k0 + ty + i * 8, n = n0 + tx;
    if (k < K && n < N) tile[ty + i * 8][tx] = src[(size_t)k * N + n];
  }
  __syncthreads();
#pragma unroll
  for (int i = 0; i < 4; ++i) {
    int n = n0 + ty + i * 8, k = k0 + tx;
    if (n < N && k < K) dst[(size_t)n * K + k] = f2bf(tile[tx][ty + i * 8]);
  }
}

// ---------------------------------------------------------------------------
// Embedding: x = q_emb[q_data] + pe[s]; y = qa_emb[target] + q_emb[q_data] + pe[s]
// ---------------------------------------------------------------------------
__global__ __launch_bounds__(256) void embed_k(
    const int* __restrict__ qd, const int* __restrict__ tg,
    const float* __restrict__ pe, const float* __restrict__ qe, const float* __restrict__ qa,
    u16* __restrict__ x_b, u16* __restrict__ y_b)
{
  const int row = blockIdx.x * 4 + (threadIdx.x >> 6);
  const int lane = threadIdx.x & 63;
  const int s = row & 511;
  const int idx = qd[row];
  const int tt = tg[row];
  const int c = lane * 8;
  const float* q = qe + (size_t)idx * 512 + c;
  const float* p = pe + (size_t)s * 512 + c;
  const float* a = qa + (size_t)tt * 512 + c;
  float4 q0 = *(const float4*)q, q1 = *(const float4*)(q + 4);
  float4 p0 = *(const float4*)p, p1 = *(const float4*)(p + 4);
  float4 a0 = *(const float4*)a, a1 = *(const float4*)(a + 4);
  float qv[8] = {q0.x, q0.y, q0.z, q0.w, q1.x, q1.y, q1.z, q1.w};
  float pv[8] = {p0.x, p0.y, p0.z, p0.w, p1.x, p1.y, p1.z, p1.w};
  float av[8] = {a0.x, a0.y, a0.z, a0.w, a1.x, a1.y, a1.z, a1.w};
  short8 ox, oy;
#pragma unroll
  for (int i = 0; i < 8; ++i) {
    ox[i] = (short)f2bf(qv[i] + pv[i]);
    oy[i] = (short)f2bf(qv[i] + pv[i] + av[i]);
  }
  size_t base = (size_t)row * 512 + c;
  *(short8*)(x_b + base) = ox;
  *(short8*)(y_b + base) = oy;
}

// ---------------------------------------------------------------------------
// bf16 GEMM core: C[M,N] = act((A[M,K] @ Bt[N,K]^T + bias) * oscale)
// 128x128 tile, BK=64, 256 thr. Staging: 16 sub-tiles of (8 rows x 64 cols),
// wave w owns tb = w*4+i; slot swizzle ps = (lane&7)^(r&7) with r&7 == lane>>3
// (uniform across tb). Per K-step: 8 gl2l16, one barrier pair, 2x16 MFMA.
// OUTM: 0 = bf16 row-major, 1 = f32 row-major, 2 = bf16 scatter vT[b,h,dk,s].
// ---------------------------------------------------------------------------
template <int ACT, int OUTM>
DEV void gemm_core(u16* As, u16* Bs,
                   const u16* __restrict__ A, const u16* __restrict__ Bt,
                   const float* __restrict__ bias, void* __restrict__ Cv,
                   int M, int N, int K, int bx, int by, float oscale)
{
  const int lane = threadIdx.x & 63;
  const int w = threadIdx.x >> 6;
  const int wm = w >> 1, wn = w & 1;
  const int m0 = by * 128, n0 = bx * 128;

  // staging addresses: rows rs_+8i (i<4), slot ps_ (8 u16 = 16B)
  const int rs_ = w * 32 + (lane >> 3);
  const int ps_ = (lane & 7) ^ (lane >> 3);   // r&7 == lane>>3 for all tb
  const u16* pa = A + (size_t)(m0 + rs_) * K + ps_ * 8;
  const u16* pb[4];
#pragma unroll
  for (int i = 0; i < 4; ++i) {
    int rb = n0 + rs_ + i * 8;
    rb = (rb < N) ? rb : (N - 1);
    pb[i] = Bt + (size_t)rb * K + ps_ * 8;
  }
  u16* la = As + (w * 4 * 64 + lane) * 8;
  u16* lb = Bs + (w * 4 * 64 + lane) * 8;

  f32x4 acc[4][4];
#pragma unroll
  for (int a_ = 0; a_ < 4; ++a_)
#pragma unroll
    for (int b_ = 0; b_ < 4; ++b_)
#pragma unroll
      for (int i = 0; i < 4; ++i) acc[a_][b_][i] = 0.f;

  for (int k0 = 0; k0 < K; k0 += 64) {
#pragma unroll
    for (int i = 0; i < 4; ++i) gl2l16(pa + (size_t)i * 8 * K, la + i * 64 * 8);
#pragma unroll
    for (int i = 0; i < 4; ++i) gl2l16(pb[i], lb + i * 64 * 8);
    pa += 64;
#pragma unroll
    for (int i = 0; i < 4; ++i) pb[i] += 64;
    __syncthreads();
#pragma unroll
    for (int ks = 0; ks < 2; ++ks) {
      short8 af[4], bf[4];
#pragma unroll
      for (int i = 0; i < 4; ++i) {
        int r = wm * 64 + i * 16 + (lane & 15);
        af[i] = *(const short8*)(As + (r * 8 + ((ks * 4 + (lane >> 4)) ^ (r & 7))) * 8);
        int r2 = wn * 64 + i * 16 + (lane & 15);
        bf[i] = *(const short8*)(Bs + (r2 * 8 + ((ks * 4 + (lane >> 4)) ^ (r2 & 7))) * 8);
      }
#pragma unroll
      for (int mt = 0; mt < 4; ++mt)
#pragma unroll
        for (int nt = 0; nt < 4; ++nt)
          acc[mt][nt] = MFMA16(af[mt], bf[nt], acc[mt][nt]);
    }
    __syncthreads();
  }

  const int row0 = m0 + wm * 64, col0 = n0 + wn * 64;
#pragma unroll
  for (int mt = 0; mt < 4; ++mt) {
#pragma unroll
    for (int nt = 0; nt < 4; ++nt) {
      int c = col0 + nt * 16 + (lane & 15);
      int r = row0 + mt * 16 + (lane >> 4) * 4;
      if (c < N) {
        float bz = bias[c];
#pragma unroll
        for (int i = 0; i < 4; ++i) {
          float v = (acc[mt][nt][i] + bz) * oscale;
          if (ACT == 1) v = fmaxf(v, 0.f);
          int m = r + i;
          if (OUTM == 0) {
            ((u16*)Cv)[(size_t)m * N + c] = f2bf(v);
          } else if (OUTM == 1) {
            ((float*)Cv)[(size_t)m * N + c] = v;
          } else {  // vT[b][h][dk][s]: m=(b,s) local, c=(h,dk)
            size_t idx = ((((size_t)(m >> 9)) * 8 + (c >> 6)) * 64 + (c & 63)) * 512 + (m & 511);
            ((u16*)Cv)[idx] = f2bf(v);
          }
        }
      }
    }
  }
}

template <int ACT, int OUTM>
__global__ __launch_bounds__(256) void gemm_bt(
    const u16* __restrict__ A, const u16* __restrict__ Bt,
    const float* __restrict__ bias, void* __restrict__ Cv,
    int M, int N, int K)
{
  __shared__ alignas(16) u16 As[128 * 64];
  __shared__ alignas(16) u16 Bs[128 * 64];
  int bx = blockIdx.x, by = blockIdx.y;
  xcd_swz(gridDim.x, gridDim.y, bx, by);
  gemm_core<ACT, OUTM>(As, Bs, A, Bt, bias, Cv, M, N, K, bx, by, 1.f);
}

// fused K/V projection: z=0 -> x@Wk (scaled by os0) -> s_kq (OUTM 0);
//                       z=1 -> y@Wv -> vT (OUTM 2)
__global__ __launch_bounds__(256) void gemm_kv(
    const u16* __restrict__ A0, const u16* __restrict__ Bt0,
    const float* __restrict__ b0, void* __restrict__ C0,
    const u16* __restrict__ A1, const u16* __restrict__ Bt1,
    const float* __restrict__ b1, void* __restrict__ C1,
    int M, int N, int K, float os0)
{
  __shared__ alignas(16) u16 As[128 * 64];
  __shared__ alignas(16) u16 Bs[128 * 64];
  int bx = blockIdx.x, by = blockIdx.y;
  xcd_swz(gridDim.x, gridDim.y, bx, by);
  if (blockIdx.z == 0)
    gemm_core<0, 0>(As, Bs, A0, Bt0, b0, C0, M, N, K, bx, by, os0);
  else
    gemm_core<0, 2>(As, Bs, A1, Bt1, b1, C1, M, N, K, bx, by, 1.f);
}

// ---------------------------------------------------------------------------
// Flash attention, transposed scores. grid (pair=2, h=8, b=NB), 256 thr.
// Each block processes TWO q-tiles {3-p, p} sequentially -> uniform 5
// chunks/block, 1024 blocks = one residency round (4/CU), zero imbalance.
// "#pragma unroll 1" on the pi loop (R11). Online softmax over 32-key
// QUARTERS (R13) -> paired body scratch-free.
// Unswizzle: l = x + 2*(y+8*z); bh = (l&7)+8*(l>>4), p = (l>>3)&1 -> both
// blocks of a (b,h) share l%8 (same XCD under round-robin) for K/V L2 hits.
// Wave w owns q-cols [w*32, w*32+32). S^T = K Q^T via 16x16x32 (keys=M, q=N);
// C-layout: q = lane&15 (col), key = (lane>>4)*4+i (row). P^T stays in regs as
// 16x16x16 B-frags; O^T = V^T P^T with dk as M.
// Q/K arrive PRE-SCALED by sqrt(0.125*log2e) (gemm_kv z=0 epilogue), so QK^T
// emerges directly in the exp2 domain — no per-element scale pass (R7).
// Softmax: masked = -1e30, plain-subtract exp2; P->bf16 via cvt_pk (R6).
// Epilogue bounces O^T through wave-private LDS (XOR swizzle) for coalesced
// short8 stores. LDS 32KB.
// ---------------------------------------------------------------------------
__global__ __launch_bounds__(256, 2) void attn_k(
    const u16* __restrict__ kq, const u16* __restrict__ vT, u16* __restrict__ o)
{
  __shared__ alignas(16) u16 Ks[128 * 64];
  __shared__ alignas(16) u16 Vs[64 * 128];
  const int l = blockIdx.x + 2 * (blockIdx.y + 8 * blockIdx.z);
  const int bh = (l & 7) + 8 * (l >> 4);
  const int pr = (l >> 3) & 1;
  const int h = bh & 7, b = bh >> 3;
  const int lane = threadIdx.x & 63;
  const int w = threadIdx.x >> 6;
  const size_t kq_base = ((size_t)b * 512) * 512 + h * 64;

#pragma unroll 1
  for (int pi = 0; pi < 2; ++pi) {
    const int t = pi ? pr : 3 - pr;   // pr=0 -> {3,0}; pr=1 -> {2,1}: 5 chunks
    const int q0 = t * 128;

    // stage Q tile [128 x 64] into Ks (wave-private region), pull B-frags
#pragma unroll
    for (int i = 0; i < 4; ++i) {
      int tb = w * 4 + i;
      int r = tb * 8 + (lane >> 3);
      int ps = (lane & 7) ^ (r & 7);
      gl2l16(kq + kq_base + (size_t)(q0 + r) * 512 + ps * 8, Ks + (tb * 64 + lane) * 8);
    }
    __syncthreads();
    short8 qf[2][2];
#pragma unroll
    for (int nt = 0; nt < 2; ++nt)
#pragma unroll
      for (int ks = 0; ks < 2; ++ks) {
        int q = w * 32 + nt * 16 + (lane & 15);
        int ch = ks * 4 + (lane >> 4);
        qf[nt][ks] = *(const short8*)(Ks + (q * 8 + (ch ^ (q & 7))) * 8);
      }

    f32x4 of[4][2];  // [dk-tile][q-tile]; col=q=lane&15, row=dk=(lane>>4)*4+i
    float m_st[2] = {-1e30f, -1e30f}, l_st[2] = {0.f, 0.f};  // exp2 domain
#pragma unroll
    for (int d = 0; d < 4; ++d)
#pragma unroll
      for (int nt = 0; nt < 2; ++nt)
#pragma unroll
        for (int i = 0; i < 4; ++i) of[d][nt][i] = 0.f;

    auto chunk = [&](int j, auto diagc) {
      constexpr bool DIAG = decltype(diagc)::value;
      // diagonal chunk: wave w needs keys < w*32+32 -> key-tiles mt < 2w+2
      const int MT = DIAG ? (2 * w + 2) : 8;
      const int k0 = j * 128;

      // four 32-key quarters, each with its own online-softmax update:
      // sc/pf live range = 24 regs -> paired body fits 128-reg target (R13).
#pragma unroll
      for (int hh = 0; hh < 4; ++hh) {
        if (!DIAG || MT > hh * 2) {
          const int MTl = DIAG ? ((MT - hh * 2 < 2) ? MT - hh * 2 : 2) : 2;

          // S^T = K Q^T (this quarter's 2 key-tiles) — already exp2-scaled
          f32x4 sc[2][2];
          __builtin_amdgcn_s_setprio(1);
#pragma unroll
          for (int mt = 0; mt < 2; ++mt)
            if (!DIAG || mt < MTl) {
#pragma unroll
              for (int nt = 0; nt < 2; ++nt)
#pragma unroll
                for (int i = 0; i < 4; ++i) sc[mt][nt][i] = 0.f;
#pragma unroll
              for (int ks = 0; ks < 2; ++ks) {
                int key = (hh * 2 + mt) * 16 + (lane & 15);
                int ch = ks * 4 + (lane >> 4);
                short8 kf = *(const short8*)(Ks + (key * 8 + (ch ^ (key & 7))) * 8);
                sc[mt][0] = MFMA16(kf, qf[0][ks], sc[mt][0]);
                sc[mt][1] = MFMA16(kf, qf[1][ks], sc[mt][1]);
              }
            }
          __builtin_amdgcn_s_setprio(0);

          // strict causal mask (diag chunk only; no scale pass needed)
          if (DIAG) {
#pragma unroll
            for (int mt = 0; mt < 2; ++mt)
              if (mt < MTl) {
#pragma unroll
                for (int nt = 0; nt < 2; ++nt) {
                  int qg = q0 + w * 32 + nt * 16 + (lane & 15);
#pragma unroll
                  for (int i = 0; i < 4; ++i) {
                    int kg = k0 + (hh * 2 + mt) * 16 + (lane >> 4) * 4 + i;
                    if (kg >= qg) sc[mt][nt][i] = -1e30f;
                  }
                }
              }
          }

          // online softmax (exp2 domain): per-lane scalar state (q=lane&15)
          short4v pf[2][2];
#pragma unroll
          for (int nt = 0; nt < 2; ++nt) {
            float mx = -1e30f;
#pragma unroll
            for (int mt = 0; mt < 2; ++mt)
              if (!DIAG || mt < MTl) {
#pragma unroll
                for (int i = 0; i < 4; ++i) mx = fmaxf(mx, sc[mt][nt][i]);
              }
            mx = fmaxf(mx, __shfl_xor(mx, 16));
            mx = fmaxf(mx, __shfl_xor(mx, 32));
            float mo = m_st[nt];
            float mn = fmaxf(mo, mx);
            float al = exp2f(mo - mn);
            float rs = 0.f;
#pragma unroll
            for (int mt = 0; mt < 2; ++mt)
              if (!DIAG || mt < MTl) {
#pragma unroll
                for (int i = 0; i < 4; ++i) {
                  float pv = exp2f(sc[mt][nt][i] - mn);
                  sc[mt][nt][i] = pv;
                  rs += pv;
                }
              }
            rs += __shfl_xor(rs, 16);
            rs += __shfl_xor(rs, 32);
            m_st[nt] = mn;
            l_st[nt] = l_st[nt] * al + rs;
#pragma unroll
            for (int d = 0; d < 4; ++d)
#pragma unroll
              for (int i = 0; i < 4; ++i) of[d][nt][i] *= al;
            // pack P^T to bf16 16x16x16 B-frags via cvt_pk
#pragma unroll
            for (int mt = 0; mt < 2; ++mt)
              if (!DIAG || mt < MTl) {
                union { unsigned u[2]; short4v s; } cv;
                cv.u[0] = cvt_pk_bf16(sc[mt][nt][0], sc[mt][nt][1]);
                cv.u[1] = cvt_pk_bf16(sc[mt][nt][2], sc[mt][nt][3]);
                pf[mt][nt] = cv.s;
              }
          }

          // O^T += V^T P^T  (A = V^T frag: m=dk, k=key; 16x16x16)
          __builtin_amdgcn_s_setprio(1);
#pragma unroll
          for (int mt = 0; mt < 2; ++mt)
            if (!DIAG || mt < MTl) {
              int key4 = (hh * 2 + mt) * 16 + (lane >> 4) * 4;
#pragma unroll
              for (int d = 0; d < 4; ++d) {
                int dk = d * 16 + (lane & 15);
                short4v vf = *(const short4v*)(
                    Vs + (dk * 16 + ((key4 >> 3) ^ (dk & 15))) * 8 + (key4 & 7));
                of[d][0] = MFMA16X16(vf, pf[mt][0], of[d][0]);
                of[d][1] = MFMA16X16(vf, pf[mt][1], of[d][1]);
              }
            }
          __builtin_amdgcn_s_setprio(0);
        }
      }
    };

#pragma unroll 1
    for (int j = 0; j <= t; ++j) {
      const int k0 = j * 128;
      __syncthreads();  // all waves done reading prior chunk's Ks/Vs
#pragma unroll
      for (int i = 0; i < 4; ++i) {  // K chunk [128 keys x 64]
        int tb = w * 4 + i;
        int r = tb * 8 + (lane >> 3);
        int ps = (lane & 7) ^ (r & 7);
        gl2l16(kq + kq_base + (size_t)(k0 + r) * 512 + ps * 8, Ks + (tb * 64 + lane) * 8);
      }
#pragma unroll
      for (int i = 0; i < 4; ++i) {  // V^T chunk [64 dk x 128 keys]
        int tb = w * 4 + i;
        int r = tb * 4 + (lane >> 4);
        int ps = (lane & 15) ^ (r & 15);
        gl2l16(vT + ((size_t)((b * 8 + h) * 64 + r)) * 512 + k0 + ps * 8, Vs + (tb * 64 + lane) * 8);
      }
      __syncthreads();
      if (j < t) {
        chunk(j, BoolC<false>{});
      } else {
        chunk(j, BoolC<true>{});
      }
    }

    // epilogue: O^T -> wave-private LDS (swizzled) -> coalesced stores
    __syncthreads();  // all waves done reading Ks/Vs
    u16* Ws = Ks + w * 2048;  // 32 q-rows x 64 dk per wave
#pragma unroll
    for (int nt = 0; nt < 2; ++nt) {
      int qrow = nt * 16 + (lane & 15);
      int qg = q0 + w * 32 + qrow;
      float li = l_st[nt];
      float inv = (qg > 0 && li > 0.f) ? (1.f / li) : 0.f;
      int sw = (qrow & 7) * 8;
#pragma unroll
      for (int d = 0; d < 4; ++d)
#pragma unroll
        for (int i = 0; i < 4; ++i) {
          int dk = d * 16 + (lane >> 4) * 4 + i;
          Ws[qrow * 64 + (dk ^ sw)] = f2bf(of[d][nt][i] * inv);
        }
    }
    // wave-private: no barrier needed (lgkmcnt ordering within wave)
#pragma unroll
    for (int p = 0; p < 4; ++p) {
      int qrow = p * 8 + (lane >> 3);
      int c = lane & 7;
      short8 vv = *(const short8*)(Ws + qrow * 64 + ((c ^ (qrow & 7)) * 8));
      int qg = q0 + w * 32 + qrow;
      *(short8*)(o + ((size_t)b * 512 + qg) * 512 + h * 64 + c * 8) = vv;
    }
  }
}

// ---------------------------------------------------------------------------
// LayerNorm(x + res); one wave per 512-col row; in-place safe.
// ---------------------------------------------------------------------------
__global__ __launch_bounds__(256) void ln_res(
    const u16* __restrict__ xin, const u16* __restrict__ res,
    const float* __restrict__ gam, const float* __restrict__ bet, u16* __restrict__ xout)
{
  const int row = blockIdx.x * 4 + (threadIdx.x >> 6);
  const int lane = threadIdx.x & 63;
  const size_t base = (size_t)row * 512 + lane * 8;
  short8 xv = *(const short8*)(xin + base);
  short8 rv = *(const short8*)(res + base);
  float v[8];
  float s = 0.f, s2 = 0.f;
#pragma unroll
  for (int i = 0; i < 8; ++i) {
    float a = bf2f((u16)xv[i]) + bf2f((u16)rv[i]);
    v[i] = a;
    s += a;
    s2 += a * a;
  }
#pragma unroll
  for (int d = 1; d < 64; d <<= 1) {
    s += __shfl_xor(s, d);
    s2 += __shfl_xor(s2, d);
  }
  float mean = s * (1.f / 512.f);
  float var = s2 * (1.f / 512.f) - mean * mean;
  float rstd = rsqrtf(var + 1e-5f);
  const int c = lane * 8;
  short8 ov;
#pragma unroll
  for (int i = 0; i < 8; ++i) {
    float ot = (v[i] - mean) * rstd * gam[c + i] + bet[c + i];
    ov[i] = (short)f2bf(ot);
  }
  *(short8*)(xout + base) = ov;
}

// ---------------------------------------------------------------------------
// concat [x, q_emb[q_data]] -> cat [rows,1024] bf16
// ---------------------------------------------------------------------------
__global__ __launch_bounds__(256) void concat2_k(
    const u16* __restrict__ x, const int* __restrict__ qd,
    const float* __restrict__ qemb, u16* __restrict__ cat)
{
  const int row = blockIdx.x * 4 + (threadIdx.x >> 6);
  const int lane = threadIdx.x & 63;
  *(short8*)(cat + (size_t)row * 1024 + lane * 8) =
      *(const short8*)(x + (size_t)row * 512 + lane * 8);
  const int idx = qd[row];
  const float* q = qemb + (size_t)idx * 512 + lane * 8;
  float4 q0 = *(const float4*)q, q1 = *(const float4*)(q + 4);
  float qv[8] = {q0.x, q0.y, q0.z, q0.w, q1.x, q1.y, q1.z, q1.w};
  short8 ov;
#pragma unroll
  for (int i = 0; i < 8; ++i) ov[i] = (short)f2bf(qv[i]);
  *(short8*)(cat + (size_t)row * 1024 + 512 + lane * 8) = ov;
}

// ---------------------------------------------------------------------------
extern "C" void kernel_launch(void* const* d_in, const int* in_sizes, int n_in,
                              void* d_out, int out_size, void* d_ws, size_t ws_size,
                              hipStream_t stream)
{
  const int* qd = (const int*)d_in[0];
  const int* tg = (const int*)d_in[1];
  const float* pe = (const float*)d_in[2];
  const float* qemb = (const float*)d_in[3];
  const float* qa = (const float*)d_in[4];
  const float* Wk = (const float*)d_in[5];
  const float* bk = (const float*)d_in[6];
  const float* Wv = (const float*)d_in[7];
  const float* bv = (const float*)d_in[8];
  const float* Wo = (const float*)d_in[9];
  const float* bo = (const float*)d_in[10];
  const float* g1 = (const float*)d_in[11];
  const float* be1 = (const float*)d_in[12];
  const float* W1 = (const float*)d_in[13];
  const float* b1 = (const float*)d_in[14];
  const float* W2 = (const float*)d_in[15];
  const float* b2 = (const float*)d_in[16];
  const float* g2 = (const float*)d_in[17];
  const float* be2 = (const float*)d_in[18];
  const float* Wo1 = (const float*)d_in[19];
  const float* bo1 = (const float*)d_in[20];
  const float* Wo2 = (const float*)d_in[21];
  const float* bo2 = (const float*)d_in[22];
  const float* Wo3 = (const float*)d_in[23];
  const float* bo3 = (const float*)d_in[24];
  float* out = (float*)d_out;

  const int BS = 64 * 512;  // 32768
  const float SQS = 0.42466089f;  // sqrt(0.125 * log2(e)) — QK pre-scale

  // batch-group chunking from ws_size (constant per process -> graph-safe)
  const size_t WU16 = 12266496ull;
  auto need2 = [&](int nc, size_t st) -> size_t {
    size_t CMr = (size_t)BS / nc;
    return 2ull * (WU16 + 2ull * BS * 512 + 3ull * CMr * 512 + st * 2048);
  };
  int NC = 1;
  if (ws_size < need2(1, 8192)) NC = 4;
  if (NC == 4 && ws_size < need2(4, 8192)) NC = 8;
  const int CM = BS / NC;
  int MI = CM < 8192 ? CM : 8192;
  // R12: grow the FFN chunk while workspace allows (MI=CM -> 4 blocks/CU on
  // the FFN-down). Deterministic in ws_size -> graph-safe.
  while (MI < CM && ws_size >= need2(NC, (size_t)MI * 2)) MI *= 2;

  u16* p = (u16*)d_ws;
  u16* wkT = p;  p += 4 * 512 * 512;
  u16* wvT = p;  p += 4 * 512 * 512;
  u16* woT = p;  p += 4 * 512 * 512;
  u16* w1T = p;  p += 4 * 512 * 2048;
  u16* w2T = p;  p += 4 * 2048 * 512;
  u16* wo1T = p; p += 1024 * 512;
  u16* wo2T = p; p += 512 * 256;
  u16* wo3T = p; p += 300 * 256;
  u16* x_b = p;  p += (size_t)BS * 512;
  u16* y_b = p;  p += (size_t)BS * 512;
  u16* s_kq = p; p += (size_t)CM * 512;   // also head-cat first half
  u16* s_vT = p; p += (size_t)CM * 512;   // adjacent: cat = s_kq[CM x 1024]
  u16* s_o = p;  p += (size_t)CM * 512;
  u16* s_t = p;                            // MI x 2048 FFN / head scratch

  transpose_cvt<<<dim3(16, 16, 4), 256, 0, stream>>>(Wk, wkT, 512, 512);
  transpose_cvt<<<dim3(16, 16, 4), 256, 0, stream>>>(Wv, wvT, 512, 512);
  transpose_cvt<<<dim3(16, 16, 4), 256, 0, stream>>>(Wo, woT, 512, 512);
  transpose_cvt<<<dim3(64, 16, 4), 256, 0, stream>>>(W1, w1T, 512, 2048);
  transpose_cvt<<<dim3(16, 64, 4), 256, 0, stream>>>(W2, w2T, 2048, 512);
  transpose_cvt<<<dim3(16, 32, 1), 256, 0, stream>>>(Wo1, wo1T, 1024, 512);
  transpose_cvt<<<dim3(8, 16, 1), 256, 0, stream>>>(Wo2, wo2T, 512, 256);
  transpose_cvt<<<dim3(10, 8, 1), 256, 0, stream>>>(Wo3, wo3T, 256, 300);

  embed_k<<<BS / 4, 256, 0, stream>>>(qd, tg, pe, qemb, qa, x_b, y_b);

  for (int l = 0; l < 4; ++l) {
    const size_t lw = (size_t)l * 512 * 512;
    for (int cc = 0; cc < NC; ++cc) {
      const size_t R = (size_t)cc * CM;
      // fused q/k + v projections (kq_same=1); q/k pre-scaled for exp2 domain
      gemm_kv<<<dim3(4, CM / 128, 2), 256, 0, stream>>>(
          x_b + R * 512, wkT + lw, bk + l * 512, s_kq,
          y_b + R * 512, wvT + lw, bv + l * 512, s_vT, CM, 512, 512, SQS);
      attn_k<<<dim3(2, 8, CM / 512), 256, 0, stream>>>(s_kq, s_vT, s_o);
      gemm_bt<0, 0><<<dim3(4, CM / 128), 256, 0, stream>>>(
          s_o, woT + lw, bo + l * 512, s_kq, CM, 512, 512);
      ln_res<<<CM / 4, 256, 0, stream>>>(
          x_b + R * 512, s_kq, g1 + l * 512, be1 + l * 512, x_b + R * 512);
      for (int mc = 0; mc < CM; mc += MI) {
        gemm_bt<1, 0><<<dim3(16, MI / 128), 256, 0, stream>>>(
            x_b + (R + mc) * 512, w1T + (size_t)l * 512 * 2048, b1 + l * 2048,
            s_t, MI, 2048, 512);
        gemm_bt<0, 0><<<dim3(4, MI / 128), 256, 0, stream>>>(
            s_t, w2T + (size_t)l * 2048 * 512, b2 + l * 512,
            s_vT + (size_t)mc * 512, MI, 512, 2048);
      }
      ln_res<<<CM / 4, 256, 0, stream>>>(
          x_b + R * 512, s_vT, g2 + l * 512, be2 + l * 512, x_b + R * 512);
    }
  }

  for (int cc = 0; cc < NC; ++cc) {
    const size_t R = (size_t)cc * CM;
    concat2_k<<<CM / 4, 256, 0, stream>>>(x_b + R * 512, qd + R, qemb, s_kq);
    gemm_bt<1, 0><<<dim3(4, CM / 128), 256, 0, stream>>>(
        s_kq, wo1T, bo1, s_o, CM, 512, 1024);
    gemm_bt<1, 0><<<dim3(2, CM / 128), 256, 0, stream>>>(
        s_o, wo2T, bo2, s_t, CM, 256, 512);
    gemm_bt<0, 1><<<dim3(3, CM / 128), 256, 0, stream>>>(
        s_t, wo3T, bo3, out + R * 300, CM, 300, 256);
  }
}

// Round 15
// 1675.240 us; speedup vs baseline: 1.5772x; 1.0543x over previous
//
#include <hip/hip_runtime.h>

// simpleKT forward on gfx950: bf16 MFMA GEMMs + flash-style causal attention
// (transposed-scores formulation; P stays in registers; coalesced O epilogue;
//  XCD-aware block swizzle for K/V L2 locality).
// R15: attn_k T13 defer-max + lazy reductions. attn is VALU-bound (46%
//  VALUBusy) and R13's quartering runs softmax bookkeeping 4x/chunk. Now:
//  per quarter, __ballot(per-lane max > m+8) gates the {cross-lane max
//  reduce, al=exp2, 32-elem of-rescale} — common path skips all three
//  (P bounded by 2^8, fine in f32/bf16; masked rows covered by the qg>0
//  guard + first-live-quarter ballot fire). l_st becomes a per-lane
//  partial, reduced once in the epilogue (drops 2 shfl per quarter/nt).
// R14 recap: GEMM XCD swizzle (panel-sharing blocks -> one XCD L2) killed
//  gemm_kv's 2x over-fetch. attn WRITE==32MB (scratch-free).
// History: R0 2844 -> R5 2491 -> R8 2349 -> R11 2339 -> R12 1994 ->
//  R13 1913 -> R14 1766.
// B=64 S=512 D=512 H=8 DK=64 L=4 DFF=2048 NSK=300 FC1=512 FC2=256.
// ENVELOPE RULE: kernels use <=256 threads and <=32KB static LDS; no
// dynamic-LDS opt-in, no hipFuncSetAttribute.

typedef unsigned short u16;
typedef __attribute__((ext_vector_type(8))) short short8;   // 8 bf16 - 16x16x32 A/B frag
typedef __attribute__((ext_vector_type(4))) short short4v;  // 4 bf16 - 16x16x16 A/B frag
typedef __attribute__((ext_vector_type(4))) float f32x4;    // MFMA C/D frag

#define DEV __device__ __forceinline__

DEV float bf2f(u16 u) { return __uint_as_float(((unsigned int)u) << 16); }
DEV u16 f2bf(float f) {
  unsigned int u = __float_as_uint(f);
  u += 0x7FFFu + ((u >> 16) & 1u);
  return (u16)(u >> 16);
}

// v_cvt_pk_bf16_f32: low16 = bf16(lo), high16 = bf16(hi); RNE — bit-identical
// to f2bf for finite inputs.
DEV unsigned cvt_pk_bf16(float lo, float hi) {
  unsigned r;
  asm("v_cvt_pk_bf16_f32 %0, %1, %2" : "=v"(r) : "v"(lo), "v"(hi));
  return r;
}

template <bool V> struct BoolC { static constexpr bool value = V; };

DEV void gl2l16(const void* g, void* l) {
  __builtin_amdgcn_global_load_lds(
      (__attribute__((address_space(1))) void*)g,
      (__attribute__((address_space(3))) void*)l, 16, 0, 0);
}

// XCD-aware grid swizzle (T1): blocks sharing an A-row-panel (same by, all
// bx) get equal lid%8 -> same XCD under round-robin dispatch -> the panel is
// fetched into ONE L2 and reused. Bijective when gy % 8 == 0.
DEV void xcd_swz(int gx, int gy, int& bx, int& by) {
  if ((gy & 7) == 0) {
    int lid = bx + gx * by;
    int r = lid >> 3;
    int q = r / gx;
    bx = r - q * gx;
    by = (lid & 7) + 8 * q;
  }
}

#define MFMA16(a, b, c) __builtin_amdgcn_mfma_f32_16x16x32_bf16(a, b, c, 0, 0, 0)

// 16x16x16 bf16 MFMA (K=16: k = (lane>>4)*4+j — matches C-layout rows)
#if defined(__has_builtin)
#if __has_builtin(__builtin_amdgcn_mfma_f32_16x16x16bf16_1k)
#define MFMA16X16(a, b, c) __builtin_amdgcn_mfma_f32_16x16x16bf16_1k(a, b, c, 0, 0, 0)
#elif __has_builtin(__builtin_amdgcn_mfma_f32_16x16x16_bf16)
#define MFMA16X16(a, b, c) __builtin_amdgcn_mfma_f32_16x16x16_bf16(a, b, c, 0, 0, 0)
#endif
#endif
#ifndef MFMA16X16
DEV f32x4 mfma_16x16x16_bf16_asm(short4v a, short4v b, f32x4 c) {
  f32x4 d;
  asm("v_mfma_f32_16x16x16_bf16 %0, %1, %2, %3\n\ts_nop 7\n\ts_nop 3"
      : "=&v"(d) : "v"(a), "v"(b), "v"(c));
  return d;
}
#define MFMA16X16(a, b, c) mfma_16x16x16_bf16_asm(a, b, c)
#endif

// ---------------------------------------------------------------------------
// Weight convert+transpose: fp32 [K,N] (batched over z) -> bf16 [N,K]
// ---------------------------------------------------------------------------
__global__ __launch_bounds__(256) void transpose_cvt(
    const float* __restrict__ src, u16* __restrict__ dst, int K, int N)
{
  src += (size_t)blockIdx.z * K * N;
  dst += (size_t)blockIdx.z * K * N;
  __shared__ alignas(16) float tile[32][33];
  const int tx = threadIdx.x & 31, ty = threadIdx.x >> 5;
  const int n0 = blockIdx.x * 32, k0 = blockIdx.y * 32;
#pragma unroll
  for (int i = 0; i < 4; ++i) {
    int k = k0 + ty + i * 8, n = n0 + tx;
    if (k < K && n < N) tile[ty + i * 8][tx] = src[(size_t)k * N + n];
  }
  __syncthreads();
#pragma unroll
  for (int i = 0; i < 4; ++i) {
    int n = n0 + ty + i * 8, k = k0 + tx;
    if (n < N && k < K) dst[(size_t)n * K + k] = f2bf(tile[tx][ty + i * 8]);
  }
}

// ---------------------------------------------------------------------------
// Embedding: x = q_emb[q_data] + pe[s]; y = qa_emb[target] + q_emb[q_data] + pe[s]
// ---------------------------------------------------------------------------
__global__ __launch_bounds__(256) void embed_k(
    const int* __restrict__ qd, const int* __restrict__ tg,
    const float* __restrict__ pe, const float* __restrict__ qe, const float* __restrict__ qa,
    u16* __restrict__ x_b, u16* __restrict__ y_b)
{
  const int row = blockIdx.x * 4 + (threadIdx.x >> 6);
  const int lane = threadIdx.x & 63;
  const int s = row & 511;
  const int idx = qd[row];
  const int tt = tg[row];
  const int c = lane * 8;
  const float* q = qe + (size_t)idx * 512 + c;
  const float* p = pe + (size_t)s * 512 + c;
  const float* a = qa + (size_t)tt * 512 + c;
  float4 q0 = *(const float4*)q, q1 = *(const float4*)(q + 4);
  float4 p0 = *(const float4*)p, p1 = *(const float4*)(p + 4);
  float4 a0 = *(const float4*)a, a1 = *(const float4*)(a + 4);
  float qv[8] = {q0.x, q0.y, q0.z, q0.w, q1.x, q1.y, q1.z, q1.w};
  float pv[8] = {p0.x, p0.y, p0.z, p0.w, p1.x, p1.y, p1.z, p1.w};
  float av[8] = {a0.x, a0.y, a0.z, a0.w, a1.x, a1.y, a1.z, a1.w};
  short8 ox, oy;
#pragma unroll
  for (int i = 0; i < 8; ++i) {
    ox[i] = (short)f2bf(qv[i] + pv[i]);
    oy[i] = (short)f2bf(qv[i] + pv[i] + av[i]);
  }
  size_t base = (size_t)row * 512 + c;
  *(short8*)(x_b + base) = ox;
  *(short8*)(y_b + base) = oy;
}

// ---------------------------------------------------------------------------
// bf16 GEMM core: C[M,N] = act((A[M,K] @ Bt[N,K]^T + bias) * oscale)
// 128x128 tile, BK=64, 256 thr. Staging: 16 sub-tiles of (8 rows x 64 cols),
// wave w owns tb = w*4+i; slot swizzle ps = (lane&7)^(r&7) with r&7 == lane>>3
// (uniform across tb). Per K-step: 8 gl2l16, one barrier pair, 2x16 MFMA.
// OUTM: 0 = bf16 row-major, 1 = f32 row-major, 2 = bf16 scatter vT[b,h,dk,s].
// ---------------------------------------------------------------------------
template <int ACT, int OUTM>
DEV void gemm_core(u16* As, u16* Bs,
                   const u16* __restrict__ A, const u16* __restrict__ Bt,
                   const float* __restrict__ bias, void* __restrict__ Cv,
                   int M, int N, int K, int bx, int by, float oscale)
{
  const int lane = threadIdx.x & 63;
  const int w = threadIdx.x >> 6;
  const int wm = w >> 1, wn = w & 1;
  const int m0 = by * 128, n0 = bx * 128;

  // staging addresses: rows rs_+8i (i<4), slot ps_ (8 u16 = 16B)
  const int rs_ = w * 32 + (lane >> 3);
  const int ps_ = (lane & 7) ^ (lane >> 3);   // r&7 == lane>>3 for all tb
  const u16* pa = A + (size_t)(m0 + rs_) * K + ps_ * 8;
  const u16* pb[4];
#pragma unroll
  for (int i = 0; i < 4; ++i) {
    int rb = n0 + rs_ + i * 8;
    rb = (rb < N) ? rb : (N - 1);
    pb[i] = Bt + (size_t)rb * K + ps_ * 8;
  }
  u16* la = As + (w * 4 * 64 + lane) * 8;
  u16* lb = Bs + (w * 4 * 64 + lane) * 8;

  f32x4 acc[4][4];
#pragma unroll
  for (int a_ = 0; a_ < 4; ++a_)
#pragma unroll
    for (int b_ = 0; b_ < 4; ++b_)
#pragma unroll
      for (int i = 0; i < 4; ++i) acc[a_][b_][i] = 0.f;

  for (int k0 = 0; k0 < K; k0 += 64) {
#pragma unroll
    for (int i = 0; i < 4; ++i) gl2l16(pa + (size_t)i * 8 * K, la + i * 64 * 8);
#pragma unroll
    for (int i = 0; i < 4; ++i) gl2l16(pb[i], lb + i * 64 * 8);
    pa += 64;
#pragma unroll
    for (int i = 0; i < 4; ++i) pb[i] += 64;
    __syncthreads();
#pragma unroll
    for (int ks = 0; ks < 2; ++ks) {
      short8 af[4], bf[4];
#pragma unroll
      for (int i = 0; i < 4; ++i) {
        int r = wm * 64 + i * 16 + (lane & 15);
        af[i] = *(const short8*)(As + (r * 8 + ((ks * 4 + (lane >> 4)) ^ (r & 7))) * 8);
        int r2 = wn * 64 + i * 16 + (lane & 15);
        bf[i] = *(const short8*)(Bs + (r2 * 8 + ((ks * 4 + (lane >> 4)) ^ (r2 & 7))) * 8);
      }
#pragma unroll
      for (int mt = 0; mt < 4; ++mt)
#pragma unroll
        for (int nt = 0; nt < 4; ++nt)
          acc[mt][nt] = MFMA16(af[mt], bf[nt], acc[mt][nt]);
    }
    __syncthreads();
  }

  const int row0 = m0 + wm * 64, col0 = n0 + wn * 64;
#pragma unroll
  for (int mt = 0; mt < 4; ++mt) {
#pragma unroll
    for (int nt = 0; nt < 4; ++nt) {
      int c = col0 + nt * 16 + (lane & 15);
      int r = row0 + mt * 16 + (lane >> 4) * 4;
      if (c < N) {
        float bz = bias[c];
#pragma unroll
        for (int i = 0; i < 4; ++i) {
          float v = (acc[mt][nt][i] + bz) * oscale;
          if (ACT == 1) v = fmaxf(v, 0.f);
          int m = r + i;
          if (OUTM == 0) {
            ((u16*)Cv)[(size_t)m * N + c] = f2bf(v);
          } else if (OUTM == 1) {
            ((float*)Cv)[(size_t)m * N + c] = v;
          } else {  // vT[b][h][dk][s]: m=(b,s) local, c=(h,dk)
            size_t idx = ((((size_t)(m >> 9)) * 8 + (c >> 6)) * 64 + (c & 63)) * 512 + (m & 511);
            ((u16*)Cv)[idx] = f2bf(v);
          }
        }
      }
    }
  }
}

template <int ACT, int OUTM>
__global__ __launch_bounds__(256) void gemm_bt(
    const u16* __restrict__ A, const u16* __restrict__ Bt,
    const float* __restrict__ bias, void* __restrict__ Cv,
    int M, int N, int K)
{
  __shared__ alignas(16) u16 As[128 * 64];
  __shared__ alignas(16) u16 Bs[128 * 64];
  int bx = blockIdx.x, by = blockIdx.y;
  xcd_swz(gridDim.x, gridDim.y, bx, by);
  gemm_core<ACT, OUTM>(As, Bs, A, Bt, bias, Cv, M, N, K, bx, by, 1.f);
}

// fused K/V projection: z=0 -> x@Wk (scaled by os0) -> s_kq (OUTM 0);
//                       z=1 -> y@Wv -> vT (OUTM 2)
__global__ __launch_bounds__(256) void gemm_kv(
    const u16* __restrict__ A0, const u16* __restrict__ Bt0,
    const float* __restrict__ b0, void* __restrict__ C0,
    const u16* __restrict__ A1, const u16* __restrict__ Bt1,
    const float* __restrict__ b1, void* __restrict__ C1,
    int M, int N, int K, float os0)
{
  __shared__ alignas(16) u16 As[128 * 64];
  __shared__ alignas(16) u16 Bs[128 * 64];
  int bx = blockIdx.x, by = blockIdx.y;
  xcd_swz(gridDim.x, gridDim.y, bx, by);
  if (blockIdx.z == 0)
    gemm_core<0, 0>(As, Bs, A0, Bt0, b0, C0, M, N, K, bx, by, os0);
  else
    gemm_core<0, 2>(As, Bs, A1, Bt1, b1, C1, M, N, K, bx, by, 1.f);
}

// ---------------------------------------------------------------------------
// Flash attention, transposed scores. grid (pair=2, h=8, b=NB), 256 thr.
// Each block processes TWO q-tiles {3-p, p} sequentially -> uniform 5
// chunks/block, one residency round. "#pragma unroll 1" on the pi loop.
// Online softmax over 32-key quarters (R13, scratch-free) with T13
// DEFER-MAX (R15): __ballot(lane_max > m+8) gates {cross-lane max reduce,
// al=exp2, of-rescale}; P bounded by 2^8 between rescales (f32 accum fine);
// l_st is a per-lane partial, reduced once in the epilogue.
// Unswizzle: l = x + 2*(y+8*z); bh = (l&7)+8*(l>>4), p = (l>>3)&1 -> both
// blocks of a (b,h) share l%8 (same XCD) for K/V L2 hits.
// Wave w owns q-cols [w*32, w*32+32). S^T = K Q^T via 16x16x32 (keys=M, q=N);
// C-layout: q = lane&15 (col), key = (lane>>4)*4+i (row). P^T stays in regs as
// 16x16x16 B-frags; O^T = V^T P^T with dk as M.
// Q/K arrive PRE-SCALED by sqrt(0.125*log2e) (gemm_kv z=0 epilogue) -> QK^T
// emerges in the exp2 domain. Masked = -1e30; fully-masked rows give P=1
// benignly (qg>0 guard); partially-masked rows fire the ballot on their
// first live quarter. Epilogue bounces O^T through wave-private LDS (XOR
// swizzle) for coalesced short8 stores. LDS 32KB.
// ---------------------------------------------------------------------------
__global__ __launch_bounds__(256, 2) void attn_k(
    const u16* __restrict__ kq, const u16* __restrict__ vT, u16* __restrict__ o)
{
  __shared__ alignas(16) u16 Ks[128 * 64];
  __shared__ alignas(16) u16 Vs[64 * 128];
  const int l = blockIdx.x + 2 * (blockIdx.y + 8 * blockIdx.z);
  const int bh = (l & 7) + 8 * (l >> 4);
  const int pr = (l >> 3) & 1;
  const int h = bh & 7, b = bh >> 3;
  const int lane = threadIdx.x & 63;
  const int w = threadIdx.x >> 6;
  const size_t kq_base = ((size_t)b * 512) * 512 + h * 64;

#pragma unroll 1
  for (int pi = 0; pi < 2; ++pi) {
    const int t = pi ? pr : 3 - pr;   // pr=0 -> {3,0}; pr=1 -> {2,1}: 5 chunks
    const int q0 = t * 128;

    // stage Q tile [128 x 64] into Ks (wave-private region), pull B-frags
#pragma unroll
    for (int i = 0; i < 4; ++i) {
      int tb = w * 4 + i;
      int r = tb * 8 + (lane >> 3);
      int ps = (lane & 7) ^ (r & 7);
      gl2l16(kq + kq_base + (size_t)(q0 + r) * 512 + ps * 8, Ks + (tb * 64 + lane) * 8);
    }
    __syncthreads();
    short8 qf[2][2];
#pragma unroll
    for (int nt = 0; nt < 2; ++nt)
#pragma unroll
      for (int ks = 0; ks < 2; ++ks) {
        int q = w * 32 + nt * 16 + (lane & 15);
        int ch = ks * 4 + (lane >> 4);
        qf[nt][ks] = *(const short8*)(Ks + (q * 8 + (ch ^ (q & 7))) * 8);
      }

    f32x4 of[4][2];  // [dk-tile][q-tile]; col=q=lane&15, row=dk=(lane>>4)*4+i
    float m_st[2] = {-1e30f, -1e30f}, l_st[2] = {0.f, 0.f};  // l = LANE PARTIAL
#pragma unroll
    for (int d = 0; d < 4; ++d)
#pragma unroll
      for (int nt = 0; nt < 2; ++nt)
#pragma unroll
        for (int i = 0; i < 4; ++i) of[d][nt][i] = 0.f;

    auto chunk = [&](int j, auto diagc) {
      constexpr bool DIAG = decltype(diagc)::value;
      // diagonal chunk: wave w needs keys < w*32+32 -> key-tiles mt < 2w+2
      const int MT = DIAG ? (2 * w + 2) : 8;
      const int k0 = j * 128;

      // four 32-key quarters; T13 defer-max per quarter (R15)
#pragma unroll
      for (int hh = 0; hh < 4; ++hh) {
        if (!DIAG || MT > hh * 2) {
          const int MTl = DIAG ? ((MT - hh * 2 < 2) ? MT - hh * 2 : 2) : 2;

          // S^T = K Q^T (this quarter's 2 key-tiles) — already exp2-scaled
          f32x4 sc[2][2];
          __builtin_amdgcn_s_setprio(1);
#pragma unroll
          for (int mt = 0; mt < 2; ++mt)
            if (!DIAG || mt < MTl) {
#pragma unroll
              for (int nt = 0; nt < 2; ++nt)
#pragma unroll
                for (int i = 0; i < 4; ++i) sc[mt][nt][i] = 0.f;
#pragma unroll
              for (int ks = 0; ks < 2; ++ks) {
                int key = (hh * 2 + mt) * 16 + (lane & 15);
                int ch = ks * 4 + (lane >> 4);
                short8 kf = *(const short8*)(Ks + (key * 8 + (ch ^ (key & 7))) * 8);
                sc[mt][0] = MFMA16(kf, qf[0][ks], sc[mt][0]);
                sc[mt][1] = MFMA16(kf, qf[1][ks], sc[mt][1]);
              }
            }
          __builtin_amdgcn_s_setprio(0);

          // strict causal mask (diag chunk only)
          if (DIAG) {
#pragma unroll
            for (int mt = 0; mt < 2; ++mt)
              if (mt < MTl) {
#pragma unroll
                for (int nt = 0; nt < 2; ++nt) {
                  int qg = q0 + w * 32 + nt * 16 + (lane & 15);
#pragma unroll
                  for (int i = 0; i < 4; ++i) {
                    int kg = k0 + (hh * 2 + mt) * 16 + (lane >> 4) * 4 + i;
                    if (kg >= qg) sc[mt][nt][i] = -1e30f;
                  }
                }
              }
          }

          // online softmax, T13 defer-max (exp2 domain; q = lane&15)
          short4v pf[2][2];
#pragma unroll
          for (int nt = 0; nt < 2; ++nt) {
            float mxl = -1e30f;  // per-LANE max (no cross-lane reduce yet)
#pragma unroll
            for (int mt = 0; mt < 2; ++mt)
              if (!DIAG || mt < MTl) {
#pragma unroll
                for (int i = 0; i < 4; ++i) mxl = fmaxf(mxl, sc[mt][nt][i]);
              }
            // wave-uniform gate: row max can exceed m+8 only if some lane does
            if (__ballot(mxl > m_st[nt] + 8.0f)) {
              float mx = fmaxf(mxl, __shfl_xor(mxl, 16));
              mx = fmaxf(mx, __shfl_xor(mx, 32));
              float mn = fmaxf(m_st[nt], mx);
              float al = exp2f(m_st[nt] - mn);
              m_st[nt] = mn;
              l_st[nt] *= al;
#pragma unroll
              for (int d = 0; d < 4; ++d)
#pragma unroll
                for (int i = 0; i < 4; ++i) of[d][nt][i] *= al;
            }
            float rs = 0.f;
#pragma unroll
            for (int mt = 0; mt < 2; ++mt)
              if (!DIAG || mt < MTl) {
#pragma unroll
                for (int i = 0; i < 4; ++i) {
                  float pv = exp2f(sc[mt][nt][i] - m_st[nt]);
                  sc[mt][nt][i] = pv;
                  rs += pv;
                }
              }
            l_st[nt] += rs;  // per-lane partial; reduced in epilogue
            // pack P^T to bf16 16x16x16 B-frags via cvt_pk
#pragma unroll
            for (int mt = 0; mt < 2; ++mt)
              if (!DIAG || mt < MTl) {
                union { unsigned u[2]; short4v s; } cv;
                cv.u[0] = cvt_pk_bf16(sc[mt][nt][0], sc[mt][nt][1]);
                cv.u[1] = cvt_pk_bf16(sc[mt][nt][2], sc[mt][nt][3]);
                pf[mt][nt] = cv.s;
              }
          }

          // O^T += V^T P^T  (A = V^T frag: m=dk, k=key; 16x16x16)
          __builtin_amdgcn_s_setprio(1);
#pragma unroll
          for (int mt = 0; mt < 2; ++mt)
            if (!DIAG || mt < MTl) {
              int key4 = (hh * 2 + mt) * 16 + (lane >> 4) * 4;
#pragma unroll
              for (int d = 0; d < 4; ++d) {
                int dk = d * 16 + (lane & 15);
                short4v vf = *(const short4v*)(
                    Vs + (dk * 16 + ((key4 >> 3) ^ (dk & 15))) * 8 + (key4 & 7));
                of[d][0] = MFMA16X16(vf, pf[mt][0], of[d][0]);
                of[d][1] = MFMA16X16(vf, pf[mt][1], of[d][1]);
              }
            }
          __builtin_amdgcn_s_setprio(0);
        }
      }
    };

#pragma unroll 1
    for (int j = 0; j <= t; ++j) {
      const int k0 = j * 128;
      __syncthreads();  // all waves done reading prior chunk's Ks/Vs
#pragma unroll
      for (int i = 0; i < 4; ++i) {  // K chunk [128 keys x 64]
        int tb = w * 4 + i;
        int r = tb * 8 + (lane >> 3);
        int ps = (lane & 7) ^ (r & 7);
        gl2l16(kq + kq_base + (size_t)(k0 + r) * 512 + ps * 8, Ks + (tb * 64 + lane) * 8);
      }
#pragma unroll
      for (int i = 0; i < 4; ++i) {  // V^T chunk [64 dk x 128 keys]
        int tb = w * 4 + i;
        int r = tb * 4 + (lane >> 4);
        int ps = (lane & 15) ^ (r & 15);
        gl2l16(vT + ((size_t)((b * 8 + h) * 64 + r)) * 512 + k0 + ps * 8, Vs + (tb * 64 + lane) * 8);
      }
      __syncthreads();
      if (j < t) {
        chunk(j, BoolC<false>{});
      } else {
        chunk(j, BoolC<true>{});
      }
    }

    // epilogue: reduce per-lane l partials, then O^T -> wave-private LDS
    // (swizzled) -> coalesced stores
    __syncthreads();  // all waves done reading Ks/Vs
    u16* Ws = Ks + w * 2048;  // 32 q-rows x 64 dk per wave
#pragma unroll
    for (int nt = 0; nt < 2; ++nt) {
      float li = l_st[nt];
      li += __shfl_xor(li, 16);
      li += __shfl_xor(li, 32);
      int qrow = nt * 16 + (lane & 15);
      int qg = q0 + w * 32 + qrow;
      float inv = (qg > 0 && li > 0.f) ? (1.f / li) : 0.f;
      int sw = (qrow & 7) * 8;
#pragma unroll
      for (int d = 0; d < 4; ++d)
#pragma unroll
        for (int i = 0; i < 4; ++i) {
          int dk = d * 16 + (lane >> 4) * 4 + i;
          Ws[qrow * 64 + (dk ^ sw)] = f2bf(of[d][nt][i] * inv);
        }
    }
    // wave-private: no barrier needed (lgkmcnt ordering within wave)
#pragma unroll
    for (int p = 0; p < 4; ++p) {
      int qrow = p * 8 + (lane >> 3);
      int c = lane & 7;
      short8 vv = *(const short8*)(Ws + qrow * 64 + ((c ^ (qrow & 7)) * 8));
      int qg = q0 + w * 32 + qrow;
      *(short8*)(o + ((size_t)b * 512 + qg) * 512 + h * 64 + c * 8) = vv;
    }
  }
}

// ---------------------------------------------------------------------------
// LayerNorm(x + res); one wave per 512-col row; in-place safe.
// ---------------------------------------------------------------------------
__global__ __launch_bounds__(256) void ln_res(
    const u16* __restrict__ xin, const u16* __restrict__ res,
    const float* __restrict__ gam, const float* __restrict__ bet, u16* __restrict__ xout)
{
  const int row = blockIdx.x * 4 + (threadIdx.x >> 6);
  const int lane = threadIdx.x & 63;
  const size_t base = (size_t)row * 512 + lane * 8;
  short8 xv = *(const short8*)(xin + base);
  short8 rv = *(const short8*)(res + base);
  float v[8];
  float s = 0.f, s2 = 0.f;
#pragma unroll
  for (int i = 0; i < 8; ++i) {
    float a = bf2f((u16)xv[i]) + bf2f((u16)rv[i]);
    v[i] = a;
    s += a;
    s2 += a * a;
  }
#pragma unroll
  for (int d = 1; d < 64; d <<= 1) {
    s += __shfl_xor(s, d);
    s2 += __shfl_xor(s2, d);
  }
  float mean = s * (1.f / 512.f);
  float var = s2 * (1.f / 512.f) - mean * mean;
  float rstd = rsqrtf(var + 1e-5f);
  const int c = lane * 8;
  short8 ov;
#pragma unroll
  for (int i = 0; i < 8; ++i) {
    float ot = (v[i] - mean) * rstd * gam[c + i] + bet[c + i];
    ov[i] = (short)f2bf(ot);
  }
  *(short8*)(xout + base) = ov;
}

// ---------------------------------------------------------------------------
// concat [x, q_emb[q_data]] -> cat [rows,1024] bf16
// ---------------------------------------------------------------------------
__global__ __launch_bounds__(256) void concat2_k(
    const u16* __restrict__ x, const int* __restrict__ qd,
    const float* __restrict__ qemb, u16* __restrict__ cat)
{
  const int row = blockIdx.x * 4 + (threadIdx.x >> 6);
  const int lane = threadIdx.x & 63;
  *(short8*)(cat + (size_t)row * 1024 + lane * 8) =
      *(const short8*)(x + (size_t)row * 512 + lane * 8);
  const int idx = qd[row];
  const float* q = qemb + (size_t)idx * 512 + lane * 8;
  float4 q0 = *(const float4*)q, q1 = *(const float4*)(q + 4);
  float qv[8] = {q0.x, q0.y, q0.z, q0.w, q1.x, q1.y, q1.z, q1.w};
  short8 ov;
#pragma unroll
  for (int i = 0; i < 8; ++i) ov[i] = (short)f2bf(qv[i]);
  *(short8*)(cat + (size_t)row * 1024 + 512 + lane * 8) = ov;
}

// ---------------------------------------------------------------------------
extern "C" void kernel_launch(void* const* d_in, const int* in_sizes, int n_in,
                              void* d_out, int out_size, void* d_ws, size_t ws_size,
                              hipStream_t stream)
{
  const int* qd = (const int*)d_in[0];
  const int* tg = (const int*)d_in[1];
  const float* pe = (const float*)d_in[2];
  const float* qemb = (const float*)d_in[3];
  const float* qa = (const float*)d_in[4];
  const float* Wk = (const float*)d_in[5];
  const float* bk = (const float*)d_in[6];
  const float* Wv = (const float*)d_in[7];
  const float* bv = (const float*)d_in[8];
  const float* Wo = (const float*)d_in[9];
  const float* bo = (const float*)d_in[10];
  const float* g1 = (const float*)d_in[11];
  const float* be1 = (const float*)d_in[12];
  const float* W1 = (const float*)d_in[13];
  const float* b1 = (const float*)d_in[14];
  const float* W2 = (const float*)d_in[15];
  const float* b2 = (const float*)d_in[16];
  const float* g2 = (const float*)d_in[17];
  const float* be2 = (const float*)d_in[18];
  const float* Wo1 = (const float*)d_in[19];
  const float* bo1 = (const float*)d_in[20];
  const float* Wo2 = (const float*)d_in[21];
  const float* bo2 = (const float*)d_in[22];
  const float* Wo3 = (const float*)d_in[23];
  const float* bo3 = (const float*)d_in[24];
  float* out = (float*)d_out;

  const int BS = 64 * 512;  // 32768
  const float SQS = 0.42466089f;  // sqrt(0.125 * log2(e)) — QK pre-scale

  // batch-group chunking from ws_size (constant per process -> graph-safe)
  const size_t WU16 = 12266496ull;
  auto need2 = [&](int nc, size_t st) -> size_t {
    size_t CMr = (size_t)BS / nc;
    return 2ull * (WU16 + 2ull * BS * 512 + 3ull * CMr * 512 + st * 2048);
  };
  int NC = 1;
  if (ws_size < need2(1, 8192)) NC = 4;
  if (NC == 4 && ws_size < need2(4, 8192)) NC = 8;
  const int CM = BS / NC;
  int MI = CM < 8192 ? CM : 8192;
  // R12: grow the FFN chunk while workspace allows (MI=CM -> 4 blocks/CU on
  // the FFN-down). Deterministic in ws_size -> graph-safe.
  while (MI < CM && ws_size >= need2(NC, (size_t)MI * 2)) MI *= 2;

  u16* p = (u16*)d_ws;
  u16* wkT = p;  p += 4 * 512 * 512;
  u16* wvT = p;  p += 4 * 512 * 512;
  u16* woT = p;  p += 4 * 512 * 512;
  u16* w1T = p;  p += 4 * 512 * 2048;
  u16* w2T = p;  p += 4 * 2048 * 512;
  u16* wo1T = p; p += 1024 * 512;
  u16* wo2T = p; p += 512 * 256;
  u16* wo3T = p; p += 300 * 256;
  u16* x_b = p;  p += (size_t)BS * 512;
  u16* y_b = p;  p += (size_t)BS * 512;
  u16* s_kq = p; p += (size_t)CM * 512;   // also head-cat first half
  u16* s_vT = p; p += (size_t)CM * 512;   // adjacent: cat = s_kq[CM x 1024]
  u16* s_o = p;  p += (size_t)CM * 512;
  u16* s_t = p;                            // MI x 2048 FFN / head scratch

  transpose_cvt<<<dim3(16, 16, 4), 256, 0, stream>>>(Wk, wkT, 512, 512);
  transpose_cvt<<<dim3(16, 16, 4), 256, 0, stream>>>(Wv, wvT, 512, 512);
  transpose_cvt<<<dim3(16, 16, 4), 256, 0, stream>>>(Wo, woT, 512, 512);
  transpose_cvt<<<dim3(64, 16, 4), 256, 0, stream>>>(W1, w1T, 512, 2048);
  transpose_cvt<<<dim3(16, 64, 4), 256, 0, stream>>>(W2, w2T, 2048, 512);
  transpose_cvt<<<dim3(16, 32, 1), 256, 0, stream>>>(Wo1, wo1T, 1024, 512);
  transpose_cvt<<<dim3(8, 16, 1), 256, 0, stream>>>(Wo2, wo2T, 512, 256);
  transpose_cvt<<<dim3(10, 8, 1), 256, 0, stream>>>(Wo3, wo3T, 256, 300);

  embed_k<<<BS / 4, 256, 0, stream>>>(qd, tg, pe, qemb, qa, x_b, y_b);

  for (int l = 0; l < 4; ++l) {
    const size_t lw = (size_t)l * 512 * 512;
    for (int cc = 0; cc < NC; ++cc) {
      const size_t R = (size_t)cc * CM;
      // fused q/k + v projections (kq_same=1); q/k pre-scaled for exp2 domain
      gemm_kv<<<dim3(4, CM / 128, 2), 256, 0, stream>>>(
          x_b + R * 512, wkT + lw, bk + l * 512, s_kq,
          y_b + R * 512, wvT + lw, bv + l * 512, s_vT, CM, 512, 512, SQS);
      attn_k<<<dim3(2, 8, CM / 512), 256, 0, stream>>>(s_kq, s_vT, s_o);
      gemm_bt<0, 0><<<dim3(4, CM / 128), 256, 0, stream>>>(
          s_o, woT + lw, bo + l * 512, s_kq, CM, 512, 512);
      ln_res<<<CM / 4, 256, 0, stream>>>(
          x_b + R * 512, s_kq, g1 + l * 512, be1 + l * 512, x_b + R * 512);
      for (int mc = 0; mc < CM; mc += MI) {
        gemm_bt<1, 0><<<dim3(16, MI / 128), 256, 0, stream>>>(
            x_b + (R + mc) * 512, w1T + (size_t)l * 512 * 2048, b1 + l * 2048,
            s_t, MI, 2048, 512);
        gemm_bt<0, 0><<<dim3(4, MI / 128), 256, 0, stream>>>(
            s_t, w2T + (size_t)l * 2048 * 512, b2 + l * 512,
            s_vT + (size_t)mc * 512, MI, 512, 2048);
      }
      ln_res<<<CM / 4, 256, 0, stream>>>(
          x_b + R * 512, s_vT, g2 + l * 512, be2 + l * 512, x_b + R * 512);
    }
  }

  for (int cc = 0; cc < NC; ++cc) {
    const size_t R = (size_t)cc * CM;
    concat2_k<<<CM / 4, 256, 0, stream>>>(x_b + R * 512, qd + R, qemb, s_kq);
    gemm_bt<1, 0><<<dim3(4, CM / 128), 256, 0, stream>>>(
        s_kq, wo1T, bo1, s_o, CM, 512, 1024);
    gemm_bt<1, 0><<<dim3(2, CM / 128), 256, 0, stream>>>(
        s_o, wo2T, bo2, s_t, CM, 256, 512);
    gemm_bt<0, 1><<<dim3(3, CM / 128), 256, 0, stream>>>(
        s_t, wo3T, bo3, out + R * 300, CM, 300, 256);
  }
}